// Round 3
// baseline (4281.643 us; speedup 1.0000x reference)
//
#include <hip/hip_runtime.h>
#include <math.h>

#define N_NODES 50000
#define N_EDGES 800000
#define HDIM 128

// ---------------------------------------------------------------------------
// Edge-index layout probe: reference creates int64 edge_index; harness contract
// says "integer -> const int*". Detect which layout is actually in the buffer:
// if the data is int64 (little-endian, values < 2^31), every odd 32-bit word
// of the first 4096 entries is 0. If int32, those words are random node ids.
// Deterministic: same input -> same flag every call.
// ---------------------------------------------------------------------------
__global__ void detect_mode_k(const int* __restrict__ ei, int* __restrict__ flag) {
    __shared__ int nz;
    if (threadIdx.x == 0) nz = 0;
    __syncthreads();
    for (int i = threadIdx.x; i < 4096; i += blockDim.x) {
        if (ei[2 * i + 1] != 0) atomicOr(&nz, 1);
    }
    __syncthreads();
    if (threadIdx.x == 0) *flag = (nz == 0) ? 1 : 0;  // 1 => int64 layout
}

__global__ void convert_idx_k(const int* __restrict__ ei, const int* __restrict__ flag,
                              int* __restrict__ src32, int* __restrict__ dst32, int ne) {
    int e = blockIdx.x * blockDim.x + threadIdx.x;
    if (e >= ne) return;
    if (*flag) {  // int64: low word at 2*k
        src32[e] = ei[2 * e];
        dst32[e] = ei[2 * (ne + e)];
    } else {      // int32
        src32[e] = ei[e];
        dst32[e] = ei[ne + e];
    }
}

// ---------------------------------------------------------------------------
// Degree / normalization (shared by all 3 GCN layers)
// ---------------------------------------------------------------------------
__global__ void deg_k(const int* __restrict__ dst, const float* __restrict__ ew,
                      float* __restrict__ deg, int ne) {
    int e = blockIdx.x * blockDim.x + threadIdx.x;
    if (e < ne) atomicAdd(&deg[dst[e]], ew[e]);
}

__global__ void dinv_k(const float* __restrict__ deg, float* __restrict__ dinv, int n) {
    int i = blockIdx.x * blockDim.x + threadIdx.x;
    if (i < n) dinv[i] = rsqrtf(deg[i] + 1.0f);  // deg+1 > 0 always
}

__global__ void norm_k(const int* __restrict__ src, const int* __restrict__ dst,
                       const float* __restrict__ ew, const float* __restrict__ dinv,
                       float* __restrict__ norm, int ne) {
    int e = blockIdx.x * blockDim.x + threadIdx.x;
    if (e < ne) norm[e] = dinv[src[e]] * ew[e] * dinv[dst[e]];
}

// ---------------------------------------------------------------------------
// GEMM: Y[r][c] = sum_k X[r][k] * W[k][c]   (K = H = 128)
// W (64 KB) staged in LDS once per block; 8 rows of X per iteration.
// Thread t: subrow = t/32 (0..7), colgroup = t%32 -> cols [4cg..4cg+3] (float4).
// ---------------------------------------------------------------------------
__global__ __launch_bounds__(256) void gemm128_k(const float* __restrict__ X,
                                                 const float* __restrict__ W,
                                                 float* __restrict__ Y, int nrows) {
    __shared__ float Wl[HDIM * HDIM];   // 64 KB
    __shared__ float xs[8][HDIM];       // 4 KB

    const float4* W4 = (const float4*)W;
    float4* Wl4 = (float4*)Wl;
    for (int i = threadIdx.x; i < HDIM * HDIM / 4; i += 256) Wl4[i] = W4[i];
    __syncthreads();

    const int cg = threadIdx.x & 31;    // column group
    const int sr = threadIdx.x >> 5;    // subrow 0..7

    for (int row0 = blockIdx.x * 8; row0 < nrows; row0 += gridDim.x * 8) {
        int r = row0 + sr;
        float4 v = make_float4(0.f, 0.f, 0.f, 0.f);
        if (r < nrows) v = ((const float4*)(X + (size_t)r * HDIM))[cg];
        ((float4*)xs[sr])[cg] = v;
        __syncthreads();

        float4 acc = make_float4(0.f, 0.f, 0.f, 0.f);
#pragma unroll 8
        for (int k = 0; k < HDIM; ++k) {
            float xv = xs[sr][k];
            float4 w = ((const float4*)(Wl + k * HDIM))[cg];
            acc.x += xv * w.x;
            acc.y += xv * w.y;
            acc.z += xv * w.z;
            acc.w += xv * w.w;
        }
        if (r < nrows) ((float4*)(Y + (size_t)r * HDIM))[cg] = acc;
        __syncthreads();
    }
}

// ---------------------------------------------------------------------------
// Edge scatter: AGG[dst] += XW[src] * norm.  32 threads per edge, float4 each.
// ---------------------------------------------------------------------------
__global__ void scatter_k(const int* __restrict__ src, const int* __restrict__ dst,
                          const float* __restrict__ norm, const float* __restrict__ XW,
                          float* __restrict__ AGG, int ne) {
    int t = blockIdx.x * blockDim.x + threadIdx.x;
    int e = t >> 5;
    int q = t & 31;
    if (e >= ne) return;
    int s = src[e], d = dst[e];
    float nm = norm[e];
    float4 v = ((const float4*)(XW + (size_t)s * HDIM))[q];
    float* ap = AGG + (size_t)d * HDIM + q * 4;
    atomicAdd(ap + 0, v.x * nm);
    atomicAdd(ap + 1, v.y * nm);
    atomicAdd(ap + 2, v.z * nm);
    atomicAdd(ap + 3, v.w * nm);
}

// ---------------------------------------------------------------------------
// Finalize: OUT = elu(AGG + XW*dinv^2 + b) [+ RES].  OUT may alias XW (same idx).
// ---------------------------------------------------------------------------
__device__ __forceinline__ float eluf(float v) { return v > 0.f ? v : expf(v) - 1.f; }

__global__ void finalize_k(const float* __restrict__ AGG, const float* XW,
                           const float* __restrict__ dinv, const float* __restrict__ bias,
                           const float* RES, float* OUT, int n) {
    int t = blockIdx.x * blockDim.x + threadIdx.x;
    int node = t >> 5;
    int q = t & 31;
    if (node >= n) return;
    float s = dinv[node];
    s = s * s;
    float4 a  = ((const float4*)(AGG + (size_t)node * HDIM))[q];
    float4 xv = ((const float4*)(XW  + (size_t)node * HDIM))[q];
    float4 bv = ((const float4*)bias)[q];
    float4 o;
    o.x = eluf(a.x + xv.x * s + bv.x);
    o.y = eluf(a.y + xv.y * s + bv.y);
    o.z = eluf(a.z + xv.z * s + bv.z);
    o.w = eluf(a.w + xv.w * s + bv.w);
    if (RES) {
        float4 rv = ((const float4*)(RES + (size_t)node * HDIM))[q];
        o.x += rv.x; o.y += rv.y; o.z += rv.z; o.w += rv.w;
    }
    ((float4*)(OUT + (size_t)node * HDIM))[q] = o;
}

// ---------------------------------------------------------------------------
// Head: out[n] = sigmoid(dot(H3[n], Wl) + bl).  One wave (64 lanes) per node.
// ---------------------------------------------------------------------------
__global__ __launch_bounds__(256) void head_k(const float* __restrict__ H3,
                                              const float* __restrict__ Wl,
                                              const float* __restrict__ bl,
                                              float* __restrict__ out, int n) {
    int wid = threadIdx.x >> 6;
    int lane = threadIdx.x & 63;
    int node = blockIdx.x * 4 + wid;
    if (node >= n) return;
    float2 h = ((const float2*)(H3 + (size_t)node * HDIM))[lane];
    float2 w = ((const float2*)Wl)[lane];
    float acc = h.x * w.x + h.y * w.y;
#pragma unroll
    for (int off = 32; off > 0; off >>= 1) acc += __shfl_down(acc, off);
    if (lane == 0) out[node] = 1.f / (1.f + expf(-(acc + bl[0])));
}

// ---------------------------------------------------------------------------
extern "C" void kernel_launch(void* const* d_in, const int* in_sizes, int n_in,
                              void* d_out, int out_size, void* d_ws, size_t ws_size,
                              hipStream_t stream) {
    const float* x  = (const float*)d_in[0];
    const int*   ei = (const int*)d_in[1];
    const float* ew = (const float*)d_in[2];
    const float* W1 = (const float*)d_in[3];
    const float* b1 = (const float*)d_in[4];
    const float* W2 = (const float*)d_in[5];
    const float* b2 = (const float*)d_in[6];
    const float* W3 = (const float*)d_in[7];
    const float* b3 = (const float*)d_in[8];
    const float* Wl = (const float*)d_in[9];
    const float* bl = (const float*)d_in[10];
    float* out = (float*)d_out;

    char* ws = (char*)d_ws;
    const size_t NHB = (size_t)N_NODES * HDIM * sizeof(float);  // 25.6 MB
    float* A    = (float*)(ws);
    float* B    = (float*)(ws + NHB);
    float* C    = (float*)(ws + 2 * NHB);
    float* deg  = (float*)(ws + 3 * NHB);
    float* dinv = deg + N_NODES;
    int*   src32 = (int*)(ws + 3 * NHB + 2 * sizeof(float) * N_NODES);
    int*   dst32 = src32 + N_EDGES;
    float* norm  = (float*)(dst32 + N_EDGES);
    int*   flag  = (int*)(norm + N_EDGES);

    const int TB = 256;
    const int egrid  = (N_EDGES + TB - 1) / TB;           // per-edge kernels
    const int ngrid  = (N_NODES + TB - 1) / TB;           // per-node kernels
    const int sgrid  = (N_EDGES * 32 + TB - 1) / TB;      // scatter (32 thr/edge)
    const int fgrid  = (N_NODES * 32 + TB - 1) / TB;      // finalize (32 thr/node)

    // --- graph preprocessing (once per call; identical every call) ---
    detect_mode_k<<<1, 256, 0, stream>>>(ei, flag);
    convert_idx_k<<<egrid, TB, 0, stream>>>(ei, flag, src32, dst32, N_EDGES);
    hipMemsetAsync(deg, 0, N_NODES * sizeof(float), stream);
    deg_k<<<egrid, TB, 0, stream>>>(dst32, ew, deg, N_EDGES);
    dinv_k<<<ngrid, TB, 0, stream>>>(deg, dinv, N_NODES);
    norm_k<<<egrid, TB, 0, stream>>>(src32, dst32, ew, dinv, norm, N_EDGES);

    // --- layer 1: h1 = elu(gcn(x, W1, b1)) -> A ---
    gemm128_k<<<1024, TB, 0, stream>>>(x, W1, A, N_NODES);
    hipMemsetAsync(B, 0, NHB, stream);
    scatter_k<<<sgrid, TB, 0, stream>>>(src32, dst32, norm, A, B, N_EDGES);
    finalize_k<<<fgrid, TB, 0, stream>>>(B, A, dinv, b1, nullptr, A, N_NODES);

    // --- layer 2: h2 = elu(gcn(h1, W2, b2)) + h1 -> B ---
    gemm128_k<<<1024, TB, 0, stream>>>(A, W2, B, N_NODES);
    hipMemsetAsync(C, 0, NHB, stream);
    scatter_k<<<sgrid, TB, 0, stream>>>(src32, dst32, norm, B, C, N_EDGES);
    finalize_k<<<fgrid, TB, 0, stream>>>(C, B, dinv, b2, A, B, N_NODES);

    // --- layer 3: h3 = elu(gcn(h2, W3, b3)) + h2 -> C ---
    gemm128_k<<<1024, TB, 0, stream>>>(B, W3, C, N_NODES);
    hipMemsetAsync(A, 0, NHB, stream);
    scatter_k<<<sgrid, TB, 0, stream>>>(src32, dst32, norm, C, A, N_EDGES);
    finalize_k<<<fgrid, TB, 0, stream>>>(A, C, dinv, b3, B, C, N_NODES);

    // --- head: out = sigmoid(h3 @ Wl + bl) ---
    head_k<<<(N_NODES + 3) / 4, TB, 0, stream>>>(C, Wl, bl, out, N_NODES);
}

// Round 8
// 627.973 us; speedup vs baseline: 6.8182x; 6.8182x over previous
//
#include <hip/hip_runtime.h>
#include <math.h>

#define N_NODES 50000
#define N_EDGES 800000
#define HDIM 128

// ---------------------------------------------------------------------------
// Edge-index layout probe (int64 vs int32 buffer layout). Deterministic.
// ---------------------------------------------------------------------------
__global__ void detect_mode_k(const int* __restrict__ ei, int* __restrict__ flag) {
    __shared__ int nz;
    if (threadIdx.x == 0) nz = 0;
    __syncthreads();
    for (int i = threadIdx.x; i < 4096; i += blockDim.x) {
        if (ei[2 * i + 1] != 0) atomicOr(&nz, 1);
    }
    __syncthreads();
    if (threadIdx.x == 0) *flag = (nz == 0) ? 1 : 0;  // 1 => int64 layout
}

__global__ void convert_idx_k(const int* __restrict__ ei, const int* __restrict__ flag,
                              int* __restrict__ src32, int* __restrict__ dst32, int ne) {
    int e = blockIdx.x * blockDim.x + threadIdx.x;
    if (e >= ne) return;
    if (*flag) {  // int64: low word at 2*k
        src32[e] = ei[2 * e];
        dst32[e] = ei[2 * (ne + e)];
    } else {      // int32
        src32[e] = ei[e];
        dst32[e] = ei[ne + e];
    }
}

// ---------------------------------------------------------------------------
// Degree / normalization (shared by all 3 GCN layers)
// ---------------------------------------------------------------------------
__global__ void deg_k(const int* __restrict__ dst, const float* __restrict__ ew,
                      float* __restrict__ deg, int ne) {
    int e = blockIdx.x * blockDim.x + threadIdx.x;
    if (e < ne) atomicAdd(&deg[dst[e]], ew[e]);
}

__global__ void dinv_k(const float* __restrict__ deg, float* __restrict__ dinv, int n) {
    int i = blockIdx.x * blockDim.x + threadIdx.x;
    if (i < n) dinv[i] = rsqrtf(deg[i] + 1.0f);
}

__global__ void norm_k(const int* __restrict__ src, const int* __restrict__ dst,
                       const float* __restrict__ ew, const float* __restrict__ dinv,
                       float* __restrict__ norm, int ne) {
    int e = blockIdx.x * blockDim.x + threadIdx.x;
    if (e < ne) norm[e] = dinv[src[e]] * ew[e] * dinv[dst[e]];
}

// ---------------------------------------------------------------------------
// CSR build: histogram by dst -> exclusive scan -> reorder (src, norm).
// ---------------------------------------------------------------------------
__global__ void hist_k(const int* __restrict__ dst, int* __restrict__ cnt, int ne) {
    int e = blockIdx.x * blockDim.x + threadIdx.x;
    if (e < ne) atomicAdd(&cnt[dst[e]], 1);
}

// single block, 1024 threads: exclusive scan of cnt[0..n) -> rowptr[0..n],
// plus a second copy into cursor[] for the reorder pass.
__global__ __launch_bounds__(1024) void scan_k(const int* __restrict__ cnt,
                                               int* __restrict__ rowptr,
                                               int* __restrict__ cursor, int n) {
    __shared__ int buf[1024];
    __shared__ int carry_s;
    if (threadIdx.x == 0) carry_s = 0;
    __syncthreads();
    for (int base = 0; base < n; base += 1024) {
        int i = base + threadIdx.x;
        int v = (i < n) ? cnt[i] : 0;
        buf[threadIdx.x] = v;
        __syncthreads();
#pragma unroll
        for (int off = 1; off < 1024; off <<= 1) {
            int t = (threadIdx.x >= off) ? buf[threadIdx.x - off] : 0;
            __syncthreads();
            buf[threadIdx.x] += t;
            __syncthreads();
        }
        int incl = buf[threadIdx.x];
        int base_c = carry_s;
        if (i < n) {
            int ex = base_c + incl - v;
            rowptr[i] = ex;
            cursor[i] = ex;
        }
        __syncthreads();
        if (threadIdx.x == 1023) carry_s = base_c + incl;
        __syncthreads();
    }
    if (threadIdx.x == 0) rowptr[n] = carry_s;
}

__global__ void reorder_k(const int* __restrict__ src, const int* __restrict__ dst,
                          const float* __restrict__ norm, int* __restrict__ cursor,
                          int* __restrict__ csr_src, float* __restrict__ csr_norm, int ne) {
    int e = blockIdx.x * blockDim.x + threadIdx.x;
    if (e >= ne) return;
    int slot = atomicAdd(&cursor[dst[e]], 1);
    csr_src[slot] = src[e];
    csr_norm[slot] = norm[e];
}

// ---------------------------------------------------------------------------
// GEMM: Y[r][c] = sum_k X[r][k] * W[k][c]   (K = H = 128), W staged in LDS.
// ---------------------------------------------------------------------------
__global__ __launch_bounds__(256) void gemm128_k(const float* __restrict__ X,
                                                 const float* __restrict__ W,
                                                 float* __restrict__ Y, int nrows) {
    __shared__ float Wl[HDIM * HDIM];   // 64 KB
    __shared__ float xs[8][HDIM];       // 4 KB

    const float4* W4 = (const float4*)W;
    float4* Wl4 = (float4*)Wl;
    for (int i = threadIdx.x; i < HDIM * HDIM / 4; i += 256) Wl4[i] = W4[i];
    __syncthreads();

    const int cg = threadIdx.x & 31;    // column group
    const int sr = threadIdx.x >> 5;    // subrow 0..7

    for (int row0 = blockIdx.x * 8; row0 < nrows; row0 += gridDim.x * 8) {
        int r = row0 + sr;
        float4 v = make_float4(0.f, 0.f, 0.f, 0.f);
        if (r < nrows) v = ((const float4*)(X + (size_t)r * HDIM))[cg];
        ((float4*)xs[sr])[cg] = v;
        __syncthreads();

        float4 acc = make_float4(0.f, 0.f, 0.f, 0.f);
#pragma unroll 8
        for (int k = 0; k < HDIM; ++k) {
            float xv = xs[sr][k];
            float4 w = ((const float4*)(Wl + k * HDIM))[cg];
            acc.x += xv * w.x;
            acc.y += xv * w.y;
            acc.z += xv * w.z;
            acc.w += xv * w.w;
        }
        if (r < nrows) ((float4*)(Y + (size_t)r * HDIM))[cg] = acc;
        __syncthreads();
    }
}

// ---------------------------------------------------------------------------
// Fused CSR gather + finalize. One wave (64 lanes) per node; lane holds 2 cols.
// OUT must NOT alias XW (other waves still read XW rows).
// OUT = elu(sum_e XW[src_e]*norm_e + XW[node]*dinv^2 + b) [+ RES]
// ---------------------------------------------------------------------------
__device__ __forceinline__ float eluf(float v) { return v > 0.f ? v : expf(v) - 1.f; }

__global__ __launch_bounds__(256) void gather_k(const int* __restrict__ rowptr,
                                                const int* __restrict__ csr_src,
                                                const float* __restrict__ csr_norm,
                                                const float* __restrict__ XW,
                                                const float* __restrict__ dinv,
                                                const float* __restrict__ bias,
                                                const float* RES, float* __restrict__ OUT,
                                                int n) {
    int wid = threadIdx.x >> 6;
    int lane = threadIdx.x & 63;
    int node = blockIdx.x * 4 + wid;
    if (node >= n) return;
    int s = rowptr[node];
    const int end = rowptr[node + 1];

    float2 acc0 = make_float2(0.f, 0.f);
    float2 acc1 = make_float2(0.f, 0.f);
    // 2-way unroll: two independent gather chains per iteration (MLP).
    for (; s + 1 < end; s += 2) {
        int s0 = csr_src[s], s1 = csr_src[s + 1];
        float n0 = csr_norm[s], n1 = csr_norm[s + 1];
        float2 v0 = ((const float2*)(XW + (size_t)s0 * HDIM))[lane];
        float2 v1 = ((const float2*)(XW + (size_t)s1 * HDIM))[lane];
        acc0.x += v0.x * n0; acc0.y += v0.y * n0;
        acc1.x += v1.x * n1; acc1.y += v1.y * n1;
    }
    if (s < end) {
        int s0 = csr_src[s];
        float n0 = csr_norm[s];
        float2 v0 = ((const float2*)(XW + (size_t)s0 * HDIM))[lane];
        acc0.x += v0.x * n0; acc0.y += v0.y * n0;
    }

    float di = dinv[node];
    di = di * di;
    float2 xv = ((const float2*)(XW + (size_t)node * HDIM))[lane];
    float2 bv = ((const float2*)bias)[lane];
    float2 o;
    o.x = eluf(acc0.x + acc1.x + xv.x * di + bv.x);
    o.y = eluf(acc0.y + acc1.y + xv.y * di + bv.y);
    if (RES) {
        float2 rv = ((const float2*)(RES + (size_t)node * HDIM))[lane];
        o.x += rv.x; o.y += rv.y;
    }
    ((float2*)(OUT + (size_t)node * HDIM))[lane] = o;
}

// ---------------------------------------------------------------------------
// Head: out[n] = sigmoid(dot(H3[n], Wl) + bl).  One wave per node.
// ---------------------------------------------------------------------------
__global__ __launch_bounds__(256) void head_k(const float* __restrict__ H3,
                                              const float* __restrict__ Wl,
                                              const float* __restrict__ bl,
                                              float* __restrict__ out, int n) {
    int wid = threadIdx.x >> 6;
    int lane = threadIdx.x & 63;
    int node = blockIdx.x * 4 + wid;
    if (node >= n) return;
    float2 h = ((const float2*)(H3 + (size_t)node * HDIM))[lane];
    float2 w = ((const float2*)Wl)[lane];
    float acc = h.x * w.x + h.y * w.y;
#pragma unroll
    for (int off = 32; off > 0; off >>= 1) acc += __shfl_down(acc, off);
    if (lane == 0) out[node] = 1.f / (1.f + expf(-(acc + bl[0])));
}

// ---------------------------------------------------------------------------
extern "C" void kernel_launch(void* const* d_in, const int* in_sizes, int n_in,
                              void* d_out, int out_size, void* d_ws, size_t ws_size,
                              hipStream_t stream) {
    const float* x  = (const float*)d_in[0];
    const int*   ei = (const int*)d_in[1];
    const float* ew = (const float*)d_in[2];
    const float* W1 = (const float*)d_in[3];
    const float* b1 = (const float*)d_in[4];
    const float* W2 = (const float*)d_in[5];
    const float* b2 = (const float*)d_in[6];
    const float* W3 = (const float*)d_in[7];
    const float* b3 = (const float*)d_in[8];
    const float* Wl = (const float*)d_in[9];
    const float* bl = (const float*)d_in[10];
    float* out = (float*)d_out;

    char* ws = (char*)d_ws;
    const size_t NHB = (size_t)N_NODES * HDIM * sizeof(float);  // 25.6 MB
    float* A    = (float*)(ws);                       // XW scratch
    float* B    = (float*)(ws + NHB);                 // h1 / h3
    float* C    = (float*)(ws + 2 * NHB);             // h2
    char*  p    = ws + 3 * NHB;
    float* deg     = (float*)p;            p += sizeof(float) * N_NODES;
    float* dinv    = (float*)p;            p += sizeof(float) * N_NODES;
    int*   src32   = (int*)p;              p += sizeof(int) * N_EDGES;
    int*   dst32   = (int*)p;              p += sizeof(int) * N_EDGES;
    float* norm    = (float*)p;            p += sizeof(float) * N_EDGES;
    int*   cnt     = (int*)p;              p += sizeof(int) * N_NODES;
    int*   rowptr  = (int*)p;              p += sizeof(int) * (N_NODES + 1);
    int*   cursor  = (int*)p;              p += sizeof(int) * N_NODES;
    int*   csr_src = (int*)p;              p += sizeof(int) * N_EDGES;
    float* csr_nrm = (float*)p;            p += sizeof(float) * N_EDGES;
    int*   flag    = (int*)p;

    const int TB = 256;
    const int egrid = (N_EDGES + TB - 1) / TB;
    const int ngrid = (N_NODES + TB - 1) / TB;
    const int ggrid = (N_NODES + 3) / 4;          // 4 nodes (waves) per block

    // --- graph preprocessing (identical every call) ---
    detect_mode_k<<<1, 256, 0, stream>>>(ei, flag);
    convert_idx_k<<<egrid, TB, 0, stream>>>(ei, flag, src32, dst32, N_EDGES);
    hipMemsetAsync(deg, 0, N_NODES * sizeof(float), stream);
    hipMemsetAsync(cnt, 0, N_NODES * sizeof(int), stream);
    deg_k<<<egrid, TB, 0, stream>>>(dst32, ew, deg, N_EDGES);
    dinv_k<<<ngrid, TB, 0, stream>>>(deg, dinv, N_NODES);
    norm_k<<<egrid, TB, 0, stream>>>(src32, dst32, ew, dinv, norm, N_EDGES);
    hist_k<<<egrid, TB, 0, stream>>>(dst32, cnt, N_EDGES);
    scan_k<<<1, 1024, 0, stream>>>(cnt, rowptr, cursor, N_NODES);
    reorder_k<<<egrid, TB, 0, stream>>>(src32, dst32, norm, cursor, csr_src, csr_nrm, N_EDGES);

    // --- layer 1: h1 = elu(gcn(x, W1, b1)) -> B ---
    gemm128_k<<<1024, TB, 0, stream>>>(x, W1, A, N_NODES);
    gather_k<<<ggrid, TB, 0, stream>>>(rowptr, csr_src, csr_nrm, A, dinv, b1, nullptr, B, N_NODES);

    // --- layer 2: h2 = elu(gcn(h1, W2, b2)) + h1 -> C ---
    gemm128_k<<<1024, TB, 0, stream>>>(B, W2, A, N_NODES);
    gather_k<<<ggrid, TB, 0, stream>>>(rowptr, csr_src, csr_nrm, A, dinv, b2, B, C, N_NODES);

    // --- layer 3: h3 = elu(gcn(h2, W3, b3)) + h2 -> B ---
    gemm128_k<<<1024, TB, 0, stream>>>(C, W3, A, N_NODES);
    gather_k<<<ggrid, TB, 0, stream>>>(rowptr, csr_src, csr_nrm, A, dinv, b3, C, B, N_NODES);

    // --- head: out = sigmoid(h3 @ Wl + bl) ---
    head_k<<<(N_NODES + 3) / 4, TB, 0, stream>>>(B, Wl, bl, out, N_NODES);
}

// Round 9
// 509.483 us; speedup vs baseline: 8.4039x; 1.2326x over previous
//
#include <hip/hip_runtime.h>
#include <math.h>

#define N_NODES 50000
#define N_EDGES 800000
#define HDIM 128
#define SCAN_B 512
#define SCAN_NB ((N_NODES + SCAN_B - 1) / SCAN_B)   // 98

// ---------------------------------------------------------------------------
// Edge-index layout probe (int64 vs int32 buffer layout). Deterministic.
// ---------------------------------------------------------------------------
__global__ void detect_mode_k(const int* __restrict__ ei, int* __restrict__ flag) {
    __shared__ int nz;
    if (threadIdx.x == 0) nz = 0;
    __syncthreads();
    for (int i = threadIdx.x; i < 4096; i += blockDim.x) {
        if (ei[2 * i + 1] != 0) atomicOr(&nz, 1);
    }
    __syncthreads();
    if (threadIdx.x == 0) *flag = (nz == 0) ? 1 : 0;  // 1 => int64 layout
}

__global__ void convert_idx_k(const int* __restrict__ ei, const int* __restrict__ flag,
                              int* __restrict__ src32, int* __restrict__ dst32, int ne) {
    int e = blockIdx.x * blockDim.x + threadIdx.x;
    if (e >= ne) return;
    if (*flag) {  // int64: low word at 2*k
        src32[e] = ei[2 * e];
        dst32[e] = ei[2 * (ne + e)];
    } else {      // int32
        src32[e] = ei[e];
        dst32[e] = ei[ne + e];
    }
}

// ---------------------------------------------------------------------------
// Fused degree (weighted) + histogram (count) in one edge pass.
// ---------------------------------------------------------------------------
__global__ void deghist_k(const int* __restrict__ dst, const float* __restrict__ ew,
                          float* __restrict__ deg, int* __restrict__ cnt, int ne) {
    int e = blockIdx.x * blockDim.x + threadIdx.x;
    if (e >= ne) return;
    int d = dst[e];
    atomicAdd(&deg[d], ew[e]);
    atomicAdd(&cnt[d], 1);
}

__global__ void dinv_k(const float* __restrict__ deg, float* __restrict__ dinv, int n) {
    int i = blockIdx.x * blockDim.x + threadIdx.x;
    if (i < n) dinv[i] = rsqrtf(deg[i] + 1.0f);
}

// ---------------------------------------------------------------------------
// Hierarchical exclusive scan of cnt[0..n) -> rowptr[0..n] (+ cursor copy).
// scan1: per-block inclusive scan (512 wide) + block sums
// scan2: one 128-thread block scans the 98 block sums -> block offsets, total
// scan3: apply offsets -> exclusive prefix
// ---------------------------------------------------------------------------
__global__ __launch_bounds__(SCAN_B) void scan1_k(const int* __restrict__ cnt,
                                                  int* __restrict__ incl,
                                                  int* __restrict__ bsum, int n) {
    __shared__ int buf[SCAN_B];
    int i = blockIdx.x * SCAN_B + threadIdx.x;
    int v = (i < n) ? cnt[i] : 0;
    buf[threadIdx.x] = v;
    __syncthreads();
#pragma unroll
    for (int off = 1; off < SCAN_B; off <<= 1) {
        int t = (threadIdx.x >= off) ? buf[threadIdx.x - off] : 0;
        __syncthreads();
        buf[threadIdx.x] += t;
        __syncthreads();
    }
    if (i < n) incl[i] = buf[threadIdx.x];
    if (threadIdx.x == SCAN_B - 1) bsum[blockIdx.x] = buf[threadIdx.x];
}

__global__ __launch_bounds__(128) void scan2_k(const int* __restrict__ bsum,
                                               int* __restrict__ boff,
                                               int* __restrict__ rowptr, int nb, int n) {
    __shared__ int buf[128];
    int t = threadIdx.x;
    int v = (t < nb) ? bsum[t] : 0;
    buf[t] = v;
    __syncthreads();
#pragma unroll
    for (int off = 1; off < 128; off <<= 1) {
        int s = (t >= off) ? buf[t - off] : 0;
        __syncthreads();
        buf[t] += s;
        __syncthreads();
    }
    if (t < nb) boff[t] = buf[t] - v;          // exclusive block offset
    if (t == nb - 1) rowptr[n] = buf[t];       // total edge count
}

__global__ __launch_bounds__(SCAN_B) void scan3_k(const int* __restrict__ cnt,
                                                  const int* __restrict__ incl,
                                                  const int* __restrict__ boff,
                                                  int* __restrict__ rowptr,
                                                  int* __restrict__ cursor, int n) {
    int i = blockIdx.x * SCAN_B + threadIdx.x;
    if (i >= n) return;
    int ex = boff[blockIdx.x] + incl[i] - cnt[i];
    rowptr[i] = ex;
    cursor[i] = ex;
}

// ---------------------------------------------------------------------------
// Reorder with fused norm computation: csr[slot] = (src, dinv[s]*ew*dinv[d]).
// ---------------------------------------------------------------------------
__global__ void reorder_k(const int* __restrict__ src, const int* __restrict__ dst,
                          const float* __restrict__ ew, const float* __restrict__ dinv,
                          int* __restrict__ cursor,
                          int* __restrict__ csr_src, float* __restrict__ csr_norm, int ne) {
    int e = blockIdx.x * blockDim.x + threadIdx.x;
    if (e >= ne) return;
    int s = src[e], d = dst[e];
    int slot = atomicAdd(&cursor[d], 1);
    csr_src[slot] = s;
    csr_norm[slot] = dinv[s] * ew[e] * dinv[d];
}

// ---------------------------------------------------------------------------
// GEMM: Y = X @ W  (K = H = 128), W in LDS, 16 rows/iter, 2 rows/thread.
// Thread t: cg = t&31 -> cols [4cg..4cg+3]; sr = t>>5 -> rows sr, sr+8.
// ---------------------------------------------------------------------------
__global__ __launch_bounds__(256) void gemm128_k(const float* __restrict__ X,
                                                 const float* __restrict__ W,
                                                 float* __restrict__ Y, int nrows) {
    __shared__ float Wl[HDIM * HDIM];   // 64 KB
    __shared__ float xs[16][HDIM];      // 8 KB

    const float4* W4 = (const float4*)W;
    float4* Wl4 = (float4*)Wl;
    for (int i = threadIdx.x; i < HDIM * HDIM / 4; i += 256) Wl4[i] = W4[i];
    __syncthreads();

    const int cg = threadIdx.x & 31;
    const int sr = threadIdx.x >> 5;

    for (int row0 = blockIdx.x * 16; row0 < nrows; row0 += gridDim.x * 16) {
        // stage 16 rows (512 float4, 2 per thread)
        for (int e = threadIdx.x; e < 512; e += 256) {
            int rr = e >> 5;
            int r = row0 + rr;
            float4 v = make_float4(0.f, 0.f, 0.f, 0.f);
            if (r < nrows) v = ((const float4*)(X + (size_t)r * HDIM))[e & 31];
            ((float4*)xs[rr])[e & 31] = v;
        }
        __syncthreads();

        float4 a0 = make_float4(0.f, 0.f, 0.f, 0.f);
        float4 a1 = make_float4(0.f, 0.f, 0.f, 0.f);
#pragma unroll 8
        for (int k = 0; k < HDIM; ++k) {
            float x0 = xs[sr][k];
            float x1 = xs[sr + 8][k];
            float4 w = ((const float4*)(Wl + k * HDIM))[cg];
            a0.x += x0 * w.x; a0.y += x0 * w.y; a0.z += x0 * w.z; a0.w += x0 * w.w;
            a1.x += x1 * w.x; a1.y += x1 * w.y; a1.z += x1 * w.z; a1.w += x1 * w.w;
        }
        int r0 = row0 + sr, r1 = row0 + sr + 8;
        if (r0 < nrows) ((float4*)(Y + (size_t)r0 * HDIM))[cg] = a0;
        if (r1 < nrows) ((float4*)(Y + (size_t)r1 * HDIM))[cg] = a1;
        __syncthreads();
    }
}

// ---------------------------------------------------------------------------
// Fused CSR gather + finalize. One wave per node; lane holds 2 cols (float2).
// OUT = elu(sum_e XW[src_e]*norm_e + XW[node]*dinv^2 + b) [+ RES]
// ---------------------------------------------------------------------------
__device__ __forceinline__ float eluf(float v) { return v > 0.f ? v : expf(v) - 1.f; }

__global__ __launch_bounds__(256) void gather_k(const int* __restrict__ rowptr,
                                                const int* __restrict__ csr_src,
                                                const float* __restrict__ csr_norm,
                                                const float* __restrict__ XW,
                                                const float* __restrict__ dinv,
                                                const float* __restrict__ bias,
                                                const float* RES, float* __restrict__ OUT,
                                                int n) {
    int wid = threadIdx.x >> 6;
    int lane = threadIdx.x & 63;
    int node = blockIdx.x * 4 + wid;
    if (node >= n) return;
    int s = rowptr[node];
    const int end = rowptr[node + 1];

    float2 acc0 = make_float2(0.f, 0.f);
    float2 acc1 = make_float2(0.f, 0.f);
    for (; s + 1 < end; s += 2) {
        int s0 = csr_src[s], s1 = csr_src[s + 1];
        float n0 = csr_norm[s], n1 = csr_norm[s + 1];
        float2 v0 = ((const float2*)(XW + (size_t)s0 * HDIM))[lane];
        float2 v1 = ((const float2*)(XW + (size_t)s1 * HDIM))[lane];
        acc0.x += v0.x * n0; acc0.y += v0.y * n0;
        acc1.x += v1.x * n1; acc1.y += v1.y * n1;
    }
    if (s < end) {
        int s0 = csr_src[s];
        float n0 = csr_norm[s];
        float2 v0 = ((const float2*)(XW + (size_t)s0 * HDIM))[lane];
        acc0.x += v0.x * n0; acc0.y += v0.y * n0;
    }

    float di = dinv[node];
    di = di * di;
    float2 xv = ((const float2*)(XW + (size_t)node * HDIM))[lane];
    float2 bv = ((const float2*)bias)[lane];
    float2 o;
    o.x = eluf(acc0.x + acc1.x + xv.x * di + bv.x);
    o.y = eluf(acc0.y + acc1.y + xv.y * di + bv.y);
    if (RES) {
        float2 rv = ((const float2*)(RES + (size_t)node * HDIM))[lane];
        o.x += rv.x; o.y += rv.y;
    }
    ((float2*)(OUT + (size_t)node * HDIM))[lane] = o;
}

// ---------------------------------------------------------------------------
// Head: out[n] = sigmoid(dot(H3[n], Wl) + bl).  One wave per node.
// ---------------------------------------------------------------------------
__global__ __launch_bounds__(256) void head_k(const float* __restrict__ H3,
                                              const float* __restrict__ Wl,
                                              const float* __restrict__ bl,
                                              float* __restrict__ out, int n) {
    int wid = threadIdx.x >> 6;
    int lane = threadIdx.x & 63;
    int node = blockIdx.x * 4 + wid;
    if (node >= n) return;
    float2 h = ((const float2*)(H3 + (size_t)node * HDIM))[lane];
    float2 w = ((const float2*)Wl)[lane];
    float acc = h.x * w.x + h.y * w.y;
#pragma unroll
    for (int off = 32; off > 0; off >>= 1) acc += __shfl_down(acc, off);
    if (lane == 0) out[node] = 1.f / (1.f + expf(-(acc + bl[0])));
}

// ---------------------------------------------------------------------------
extern "C" void kernel_launch(void* const* d_in, const int* in_sizes, int n_in,
                              void* d_out, int out_size, void* d_ws, size_t ws_size,
                              hipStream_t stream) {
    const float* x  = (const float*)d_in[0];
    const int*   ei = (const int*)d_in[1];
    const float* ew = (const float*)d_in[2];
    const float* W1 = (const float*)d_in[3];
    const float* b1 = (const float*)d_in[4];
    const float* W2 = (const float*)d_in[5];
    const float* b2 = (const float*)d_in[6];
    const float* W3 = (const float*)d_in[7];
    const float* b3 = (const float*)d_in[8];
    const float* Wl = (const float*)d_in[9];
    const float* bl = (const float*)d_in[10];
    float* out = (float*)d_out;

    char* ws = (char*)d_ws;
    const size_t NHB = (size_t)N_NODES * HDIM * sizeof(float);  // 25.6 MB
    float* A    = (float*)(ws);                       // XW scratch
    float* B    = (float*)(ws + NHB);                 // h1 / h3
    float* C    = (float*)(ws + 2 * NHB);             // h2
    char*  p    = ws + 3 * NHB;
    float* deg     = (float*)p;            p += sizeof(float) * N_NODES;
    float* dinv    = (float*)p;            p += sizeof(float) * N_NODES;
    int*   src32   = (int*)p;              p += sizeof(int) * N_EDGES;
    int*   dst32   = (int*)p;              p += sizeof(int) * N_EDGES;
    int*   cnt     = (int*)p;              p += sizeof(int) * N_NODES;
    int*   incl    = (int*)p;              p += sizeof(int) * N_NODES;
    int*   rowptr  = (int*)p;              p += sizeof(int) * (N_NODES + 1);
    int*   cursor  = (int*)p;              p += sizeof(int) * N_NODES;
    int*   csr_src = (int*)p;              p += sizeof(int) * N_EDGES;
    float* csr_nrm = (float*)p;            p += sizeof(float) * N_EDGES;
    int*   bsum    = (int*)p;              p += sizeof(int) * 128;
    int*   boff    = (int*)p;              p += sizeof(int) * 128;
    int*   flag    = (int*)p;

    const int TB = 256;
    const int egrid = (N_EDGES + TB - 1) / TB;
    const int ngrid = (N_NODES + TB - 1) / TB;
    const int ggrid = (N_NODES + 3) / 4;          // 4 nodes (waves) per block

    // --- graph preprocessing (identical every call) ---
    detect_mode_k<<<1, 256, 0, stream>>>(ei, flag);
    convert_idx_k<<<egrid, TB, 0, stream>>>(ei, flag, src32, dst32, N_EDGES);
    hipMemsetAsync(deg, 0, N_NODES * sizeof(float), stream);
    hipMemsetAsync(cnt, 0, N_NODES * sizeof(int), stream);
    deghist_k<<<egrid, TB, 0, stream>>>(dst32, ew, deg, cnt, N_EDGES);
    dinv_k<<<ngrid, TB, 0, stream>>>(deg, dinv, N_NODES);
    scan1_k<<<SCAN_NB, SCAN_B, 0, stream>>>(cnt, incl, bsum, N_NODES);
    scan2_k<<<1, 128, 0, stream>>>(bsum, boff, rowptr, SCAN_NB, N_NODES);
    scan3_k<<<SCAN_NB, SCAN_B, 0, stream>>>(cnt, incl, boff, rowptr, cursor, N_NODES);
    reorder_k<<<egrid, TB, 0, stream>>>(src32, dst32, ew, dinv, cursor, csr_src, csr_nrm, N_EDGES);

    // --- layer 1: h1 = elu(gcn(x, W1, b1)) -> B ---
    gemm128_k<<<1024, TB, 0, stream>>>(x, W1, A, N_NODES);
    gather_k<<<ggrid, TB, 0, stream>>>(rowptr, csr_src, csr_nrm, A, dinv, b1, nullptr, B, N_NODES);

    // --- layer 2: h2 = elu(gcn(h1, W2, b2)) + h1 -> C ---
    gemm128_k<<<1024, TB, 0, stream>>>(B, W2, A, N_NODES);
    gather_k<<<ggrid, TB, 0, stream>>>(rowptr, csr_src, csr_nrm, A, dinv, b2, B, C, N_NODES);

    // --- layer 3: h3 = elu(gcn(h2, W3, b3)) + h2 -> B ---
    gemm128_k<<<1024, TB, 0, stream>>>(C, W3, A, N_NODES);
    gather_k<<<ggrid, TB, 0, stream>>>(rowptr, csr_src, csr_nrm, A, dinv, b3, C, B, N_NODES);

    // --- head: out = sigmoid(h3 @ Wl + bl) ---
    head_k<<<(N_NODES + 3) / 4, TB, 0, stream>>>(B, Wl, bl, out, N_NODES);
}

// Round 11
// 412.701 us; speedup vs baseline: 10.3747x; 1.2345x over previous
//
#include <hip/hip_runtime.h>
#include <math.h>

#define N_NODES 50000
#define N_EDGES 800000
#define HDIM 128
#define SCAN_B 512
#define SCAN_NB ((N_NODES + SCAN_B - 1) / SCAN_B)   // 98

// bf16 helpers (manual RNE; bf16->f32 is a 16-bit shift)
__device__ __forceinline__ unsigned int f2bf(float f) {
    unsigned int u = __float_as_uint(f);
    return (u + 0x7fffu + ((u >> 16) & 1u)) >> 16;
}
__device__ __forceinline__ float bf_lo(unsigned int u) { return __uint_as_float(u << 16); }
__device__ __forceinline__ float bf_hi(unsigned int u) { return __uint_as_float(u & 0xffff0000u); }

// ---------------------------------------------------------------------------
// Edge-index layout probe (int64 vs int32 buffer layout). Deterministic.
// ---------------------------------------------------------------------------
__global__ void detect_mode_k(const int* __restrict__ ei, int* __restrict__ flag) {
    __shared__ int nz;
    if (threadIdx.x == 0) nz = 0;
    __syncthreads();
    for (int i = threadIdx.x; i < 4096; i += blockDim.x) {
        if (ei[2 * i + 1] != 0) atomicOr(&nz, 1);
    }
    __syncthreads();
    if (threadIdx.x == 0) *flag = (nz == 0) ? 1 : 0;  // 1 => int64 layout
}

__global__ void convert_idx_k(const int* __restrict__ ei, const int* __restrict__ flag,
                              int* __restrict__ src32, int* __restrict__ dst32, int ne) {
    int e = blockIdx.x * blockDim.x + threadIdx.x;
    if (e >= ne) return;
    if (*flag) {
        src32[e] = ei[2 * e];
        dst32[e] = ei[2 * (ne + e)];
    } else {
        src32[e] = ei[e];
        dst32[e] = ei[ne + e];
    }
}

// ---------------------------------------------------------------------------
// Fused degree (weighted) + histogram (count) in one edge pass.
// ---------------------------------------------------------------------------
__global__ void deghist_k(const int* __restrict__ dst, const float* __restrict__ ew,
                          float* __restrict__ deg, int* __restrict__ cnt, int ne) {
    int e = blockIdx.x * blockDim.x + threadIdx.x;
    if (e >= ne) return;
    int d = dst[e];
    atomicAdd(&deg[d], ew[e]);
    atomicAdd(&cnt[d], 1);
}

__global__ void dinv_k(const float* __restrict__ deg, float* __restrict__ dinv, int n) {
    int i = blockIdx.x * blockDim.x + threadIdx.x;
    if (i < n) dinv[i] = rsqrtf(deg[i] + 1.0f);
}

// ---------------------------------------------------------------------------
// Hierarchical exclusive scan of cnt[0..n) -> rowptr[0..n] (+ cursor copy).
// ---------------------------------------------------------------------------
__global__ __launch_bounds__(SCAN_B) void scan1_k(const int* __restrict__ cnt,
                                                  int* __restrict__ incl,
                                                  int* __restrict__ bsum, int n) {
    __shared__ int buf[SCAN_B];
    int i = blockIdx.x * SCAN_B + threadIdx.x;
    int v = (i < n) ? cnt[i] : 0;
    buf[threadIdx.x] = v;
    __syncthreads();
#pragma unroll
    for (int off = 1; off < SCAN_B; off <<= 1) {
        int t = (threadIdx.x >= off) ? buf[threadIdx.x - off] : 0;
        __syncthreads();
        buf[threadIdx.x] += t;
        __syncthreads();
    }
    if (i < n) incl[i] = buf[threadIdx.x];
    if (threadIdx.x == SCAN_B - 1) bsum[blockIdx.x] = buf[threadIdx.x];
}

__global__ __launch_bounds__(128) void scan2_k(const int* __restrict__ bsum,
                                               int* __restrict__ boff,
                                               int* __restrict__ rowptr, int nb, int n) {
    __shared__ int buf[128];
    int t = threadIdx.x;
    int v = (t < nb) ? bsum[t] : 0;
    buf[t] = v;
    __syncthreads();
#pragma unroll
    for (int off = 1; off < 128; off <<= 1) {
        int s = (t >= off) ? buf[t - off] : 0;
        __syncthreads();
        buf[t] += s;
        __syncthreads();
    }
    if (t < nb) boff[t] = buf[t] - v;
    if (t == nb - 1) rowptr[n] = buf[t];
}

__global__ __launch_bounds__(SCAN_B) void scan3_k(const int* __restrict__ cnt,
                                                  const int* __restrict__ incl,
                                                  const int* __restrict__ boff,
                                                  int* __restrict__ rowptr,
                                                  int* __restrict__ cursor, int n) {
    int i = blockIdx.x * SCAN_B + threadIdx.x;
    if (i >= n) return;
    int ex = boff[blockIdx.x] + incl[i] - cnt[i];
    rowptr[i] = ex;
    cursor[i] = ex;
}

// ---------------------------------------------------------------------------
// Reorder, fused norm, packed (src, norm) int2: one 8B scattered store/edge.
// ---------------------------------------------------------------------------
__global__ void reorder_k(const int* __restrict__ src, const int* __restrict__ dst,
                          const float* __restrict__ ew, const float* __restrict__ dinv,
                          int* __restrict__ cursor, int2* __restrict__ csr, int ne) {
    int e = blockIdx.x * blockDim.x + threadIdx.x;
    if (e >= ne) return;
    int s = src[e], d = dst[e];
    int slot = atomicAdd(&cursor[d], 1);
    csr[slot] = make_int2(s, __float_as_int(dinv[s] * ew[e] * dinv[d]));
}

// ---------------------------------------------------------------------------
// GEMM: Yb(bf16) = X(f32) @ W(f32).  W in LDS; 16 rows/iter, 2 rows/thread.
// Output packed bf16: cols 4cg..4cg+3 -> uint2 at uint-index 2cg.
// ---------------------------------------------------------------------------
__global__ __launch_bounds__(256) void gemm128_k(const float* __restrict__ X,
                                                 const float* __restrict__ W,
                                                 unsigned int* __restrict__ Yb, int nrows) {
    __shared__ float Wl[HDIM * HDIM];   // 64 KB
    __shared__ float xs[16][HDIM];      // 8 KB

    const float4* W4 = (const float4*)W;
    float4* Wl4 = (float4*)Wl;
    for (int i = threadIdx.x; i < HDIM * HDIM / 4; i += 256) Wl4[i] = W4[i];
    __syncthreads();

    const int cg = threadIdx.x & 31;
    const int sr = threadIdx.x >> 5;

    for (int row0 = blockIdx.x * 16; row0 < nrows; row0 += gridDim.x * 16) {
        for (int e = threadIdx.x; e < 512; e += 256) {
            int rr = e >> 5;
            int r = row0 + rr;
            float4 v = make_float4(0.f, 0.f, 0.f, 0.f);
            if (r < nrows) v = ((const float4*)(X + (size_t)r * HDIM))[e & 31];
            ((float4*)xs[rr])[e & 31] = v;
        }
        __syncthreads();

        float4 a0 = make_float4(0.f, 0.f, 0.f, 0.f);
        float4 a1 = make_float4(0.f, 0.f, 0.f, 0.f);
#pragma unroll 8
        for (int k = 0; k < HDIM; ++k) {
            float x0 = xs[sr][k];
            float x1 = xs[sr + 8][k];
            float4 w = ((const float4*)(Wl + k * HDIM))[cg];
            a0.x += x0 * w.x; a0.y += x0 * w.y; a0.z += x0 * w.z; a0.w += x0 * w.w;
            a1.x += x1 * w.x; a1.y += x1 * w.y; a1.z += x1 * w.z; a1.w += x1 * w.w;
        }
        int r0 = row0 + sr, r1 = row0 + sr + 8;
        // row stride in uints = HDIM/2 = 64
        if (r0 < nrows) {
            uint2 o;
            o.x = f2bf(a0.x) | (f2bf(a0.y) << 16);
            o.y = f2bf(a0.z) | (f2bf(a0.w) << 16);
            ((uint2*)(Yb + (size_t)r0 * (HDIM / 2)))[cg] = o;
        }
        if (r1 < nrows) {
            uint2 o;
            o.x = f2bf(a1.x) | (f2bf(a1.y) << 16);
            o.y = f2bf(a1.z) | (f2bf(a1.w) << 16);
            ((uint2*)(Yb + (size_t)r1 * (HDIM / 2)))[cg] = o;
        }
        __syncthreads();
    }
}

// ---------------------------------------------------------------------------
// Fused CSR gather + finalize; XW rows in bf16 (256B/row), 4-edge unroll.
// One wave per node; lane holds cols 2*lane, 2*lane+1 (one packed uint).
// OUT(f32) = elu(sum_e XW[src_e]*norm_e + XW[node]*dinv^2 + b) [+ RES]
// ---------------------------------------------------------------------------
__device__ __forceinline__ float eluf(float v) { return v > 0.f ? v : expf(v) - 1.f; }

__global__ __launch_bounds__(256) void gather_k(const int* __restrict__ rowptr,
                                                const int2* __restrict__ csr,
                                                const unsigned int* __restrict__ XWb,
                                                const float* __restrict__ dinv,
                                                const float* __restrict__ bias,
                                                const float* RES, float* __restrict__ OUT,
                                                int n) {
    int wid = threadIdx.x >> 6;
    int lane = threadIdx.x & 63;
    int node = blockIdx.x * 4 + wid;
    if (node >= n) return;
    int s = rowptr[node];
    const int end = rowptr[node + 1];

    float2 acc0 = make_float2(0.f, 0.f);
    float2 acc1 = make_float2(0.f, 0.f);

    for (; s + 3 < end; s += 4) {
        int2 e0 = csr[s], e1 = csr[s + 1], e2 = csr[s + 2], e3 = csr[s + 3];
        unsigned int u0 = (XWb + (size_t)e0.x * 64)[lane];
        unsigned int u1 = (XWb + (size_t)e1.x * 64)[lane];
        unsigned int u2 = (XWb + (size_t)e2.x * 64)[lane];
        unsigned int u3 = (XWb + (size_t)e3.x * 64)[lane];
        float n0 = __int_as_float(e0.y), n1 = __int_as_float(e1.y);
        float n2 = __int_as_float(e2.y), n3 = __int_as_float(e3.y);
        acc0.x += bf_lo(u0) * n0; acc0.y += bf_hi(u0) * n0;
        acc1.x += bf_lo(u1) * n1; acc1.y += bf_hi(u1) * n1;
        acc0.x += bf_lo(u2) * n2; acc0.y += bf_hi(u2) * n2;
        acc1.x += bf_lo(u3) * n3; acc1.y += bf_hi(u3) * n3;
    }
    for (; s < end; ++s) {
        int2 e0 = csr[s];
        unsigned int u0 = (XWb + (size_t)e0.x * 64)[lane];
        float n0 = __int_as_float(e0.y);
        acc0.x += bf_lo(u0) * n0; acc0.y += bf_hi(u0) * n0;
    }

    float di = dinv[node];
    di = di * di;
    unsigned int us = (XWb + (size_t)node * 64)[lane];
    float2 bv = ((const float2*)bias)[lane];
    float2 o;
    o.x = eluf(acc0.x + acc1.x + bf_lo(us) * di + bv.x);
    o.y = eluf(acc0.y + acc1.y + bf_hi(us) * di + bv.y);
    if (RES) {
        float2 rv = ((const float2*)(RES + (size_t)node * HDIM))[lane];
        o.x += rv.x; o.y += rv.y;
    }
    ((float2*)(OUT + (size_t)node * HDIM))[lane] = o;
}

// ---------------------------------------------------------------------------
// Head: out[n] = sigmoid(dot(H3[n], Wl) + bl).  One wave per node.
// ---------------------------------------------------------------------------
__global__ __launch_bounds__(256) void head_k(const float* __restrict__ H3,
                                              const float* __restrict__ Wl,
                                              const float* __restrict__ bl,
                                              float* __restrict__ out, int n) {
    int wid = threadIdx.x >> 6;
    int lane = threadIdx.x & 63;
    int node = blockIdx.x * 4 + wid;
    if (node >= n) return;
    float2 h = ((const float2*)(H3 + (size_t)node * HDIM))[lane];
    float2 w = ((const float2*)Wl)[lane];
    float acc = h.x * w.x + h.y * w.y;
#pragma unroll
    for (int off = 32; off > 0; off >>= 1) acc += __shfl_down(acc, off);
    if (lane == 0) out[node] = 1.f / (1.f + expf(-(acc + bl[0])));
}

// ---------------------------------------------------------------------------
extern "C" void kernel_launch(void* const* d_in, const int* in_sizes, int n_in,
                              void* d_out, int out_size, void* d_ws, size_t ws_size,
                              hipStream_t stream) {
    const float* x  = (const float*)d_in[0];
    const int*   ei = (const int*)d_in[1];
    const float* ew = (const float*)d_in[2];
    const float* W1 = (const float*)d_in[3];
    const float* b1 = (const float*)d_in[4];
    const float* W2 = (const float*)d_in[5];
    const float* b2 = (const float*)d_in[6];
    const float* W3 = (const float*)d_in[7];
    const float* b3 = (const float*)d_in[8];
    const float* Wl = (const float*)d_in[9];
    const float* bl = (const float*)d_in[10];
    float* out = (float*)d_out;

    char* ws = (char*)d_ws;
    const size_t NHB = (size_t)N_NODES * HDIM * sizeof(float);  // 25.6 MB
    unsigned int* A = (unsigned int*)(ws);            // XW in bf16 (12.8 MB used)
    float* B    = (float*)(ws + NHB);                 // h1 / h3 (f32)
    float* C    = (float*)(ws + 2 * NHB);             // h2 (f32)
    char*  p    = ws + 3 * NHB;
    float* deg     = (float*)p;            p += sizeof(float) * N_NODES;
    float* dinv    = (float*)p;            p += sizeof(float) * N_NODES;
    int*   src32   = (int*)p;              p += sizeof(int) * N_EDGES;
    int*   dst32   = (int*)p;              p += sizeof(int) * N_EDGES;
    int*   cnt     = (int*)p;              p += sizeof(int) * N_NODES;
    int*   incl    = (int*)p;              p += sizeof(int) * N_NODES;
    int*   rowptr  = (int*)p;              p += sizeof(int) * (N_NODES + 1);
    int*   cursor  = (int*)p;              p += sizeof(int) * N_NODES;
    int2*  csr     = (int2*)p;             p += sizeof(int2) * N_EDGES;
    int*   bsum    = (int*)p;              p += sizeof(int) * 128;
    int*   boff    = (int*)p;              p += sizeof(int) * 128;
    int*   flag    = (int*)p;

    const int TB = 256;
    const int egrid = (N_EDGES + TB - 1) / TB;
    const int ngrid = (N_NODES + TB - 1) / TB;
    const int ggrid = (N_NODES + 3) / 4;

    // --- graph preprocessing (identical every call) ---
    detect_mode_k<<<1, 256, 0, stream>>>(ei, flag);
    convert_idx_k<<<egrid, TB, 0, stream>>>(ei, flag, src32, dst32, N_EDGES);
    hipMemsetAsync(deg, 0, N_NODES * sizeof(float), stream);
    hipMemsetAsync(cnt, 0, N_NODES * sizeof(int), stream);
    deghist_k<<<egrid, TB, 0, stream>>>(dst32, ew, deg, cnt, N_EDGES);
    dinv_k<<<ngrid, TB, 0, stream>>>(deg, dinv, N_NODES);
    scan1_k<<<SCAN_NB, SCAN_B, 0, stream>>>(cnt, incl, bsum, N_NODES);
    scan2_k<<<1, 128, 0, stream>>>(bsum, boff, rowptr, SCAN_NB, N_NODES);
    scan3_k<<<SCAN_NB, SCAN_B, 0, stream>>>(cnt, incl, boff, rowptr, cursor, N_NODES);
    reorder_k<<<egrid, TB, 0, stream>>>(src32, dst32, ew, dinv, cursor, csr, N_EDGES);

    // --- layer 1: h1 = elu(gcn(x, W1, b1)) -> B ---
    gemm128_k<<<1024, TB, 0, stream>>>(x, W1, A, N_NODES);
    gather_k<<<ggrid, TB, 0, stream>>>(rowptr, csr, A, dinv, b1, nullptr, B, N_NODES);

    // --- layer 2: h2 = elu(gcn(h1, W2, b2)) + h1 -> C ---
    gemm128_k<<<1024, TB, 0, stream>>>(B, W2, A, N_NODES);
    gather_k<<<ggrid, TB, 0, stream>>>(rowptr, csr, A, dinv, b2, B, C, N_NODES);

    // --- layer 3: h3 = elu(gcn(h2, W3, b3)) + h2 -> B ---
    gemm128_k<<<1024, TB, 0, stream>>>(C, W3, A, N_NODES);
    gather_k<<<ggrid, TB, 0, stream>>>(rowptr, csr, A, dinv, b3, C, B, N_NODES);

    // --- head: out = sigmoid(h3 @ Wl + bl) ---
    head_k<<<(N_NODES + 3) / 4, TB, 0, stream>>>(B, Wl, bl, out, N_NODES);
}

// Round 12
// 303.246 us; speedup vs baseline: 14.1194x; 1.3609x over previous
//
#include <hip/hip_runtime.h>
#include <math.h>

#define N_NODES 50000
#define N_EDGES 800000
#define HDIM 128
#define SCAN_B 512
#define SCAN_NB ((N_NODES + SCAN_B - 1) / SCAN_B)   // 98

typedef __attribute__((ext_vector_type(8))) short short8;
typedef __attribute__((ext_vector_type(4))) float f32x4;

// bf16 helpers (manual RNE; bf16->f32 is a 16-bit shift)
__device__ __forceinline__ unsigned int f2bf(float f) {
    unsigned int u = __float_as_uint(f);
    return (u + 0x7fffu + ((u >> 16) & 1u)) >> 16;
}
__device__ __forceinline__ float bf_lo(unsigned int u) { return __uint_as_float(u << 16); }
__device__ __forceinline__ float bf_hi(unsigned int u) { return __uint_as_float(u & 0xffff0000u); }

// ---------------------------------------------------------------------------
// Edge-index layout probe (int64 vs int32 buffer layout). Deterministic.
// ---------------------------------------------------------------------------
__global__ void detect_mode_k(const int* __restrict__ ei, int* __restrict__ flag) {
    __shared__ int nz;
    if (threadIdx.x == 0) nz = 0;
    __syncthreads();
    for (int i = threadIdx.x; i < 4096; i += blockDim.x) {
        if (ei[2 * i + 1] != 0) atomicOr(&nz, 1);
    }
    __syncthreads();
    if (threadIdx.x == 0) *flag = (nz == 0) ? 1 : 0;  // 1 => int64 layout
}

__global__ void convert_idx_k(const int* __restrict__ ei, const int* __restrict__ flag,
                              int* __restrict__ src32, int* __restrict__ dst32, int ne) {
    int e = blockIdx.x * blockDim.x + threadIdx.x;
    if (e >= ne) return;
    if (*flag) {
        src32[e] = ei[2 * e];
        dst32[e] = ei[2 * (ne + e)];
    } else {
        src32[e] = ei[e];
        dst32[e] = ei[ne + e];
    }
}

// ---------------------------------------------------------------------------
// Packed degree+count: ONE 64-bit atomic per edge.
// high 32 = count, low 32 = sum(ew * 2^24) fixed-point (ew in [0,1), deg<256).
// ---------------------------------------------------------------------------
__global__ void deghist_k(const int* __restrict__ dst, const float* __restrict__ ew,
                          unsigned long long* __restrict__ pcnt, int ne) {
    int e = blockIdx.x * blockDim.x + threadIdx.x;
    if (e >= ne) return;
    unsigned int q = __float2uint_rn(ew[e] * 16777216.0f);
    atomicAdd(&pcnt[dst[e]], (1ULL << 32) | (unsigned long long)q);
}

__global__ void unpack_k(const unsigned long long* __restrict__ pcnt,
                         float* __restrict__ dinv, int* __restrict__ cnt, int n) {
    int i = blockIdx.x * blockDim.x + threadIdx.x;
    if (i >= n) return;
    unsigned long long v = pcnt[i];
    cnt[i] = (int)(v >> 32);
    float deg = (float)(unsigned int)(v & 0xffffffffULL) * (1.0f / 16777216.0f);
    dinv[i] = rsqrtf(deg + 1.0f);
}

// ---------------------------------------------------------------------------
// Hierarchical exclusive scan of cnt[0..n) -> rowptr[0..n] (+ cursor copy).
// ---------------------------------------------------------------------------
__global__ __launch_bounds__(SCAN_B) void scan1_k(const int* __restrict__ cnt,
                                                  int* __restrict__ incl,
                                                  int* __restrict__ bsum, int n) {
    __shared__ int buf[SCAN_B];
    int i = blockIdx.x * SCAN_B + threadIdx.x;
    int v = (i < n) ? cnt[i] : 0;
    buf[threadIdx.x] = v;
    __syncthreads();
#pragma unroll
    for (int off = 1; off < SCAN_B; off <<= 1) {
        int t = (threadIdx.x >= off) ? buf[threadIdx.x - off] : 0;
        __syncthreads();
        buf[threadIdx.x] += t;
        __syncthreads();
    }
    if (i < n) incl[i] = buf[threadIdx.x];
    if (threadIdx.x == SCAN_B - 1) bsum[blockIdx.x] = buf[threadIdx.x];
}

__global__ __launch_bounds__(128) void scan2_k(const int* __restrict__ bsum,
                                               int* __restrict__ boff,
                                               int* __restrict__ rowptr, int nb, int n) {
    __shared__ int buf[128];
    int t = threadIdx.x;
    int v = (t < nb) ? bsum[t] : 0;
    buf[t] = v;
    __syncthreads();
#pragma unroll
    for (int off = 1; off < 128; off <<= 1) {
        int s = (t >= off) ? buf[t - off] : 0;
        __syncthreads();
        buf[t] += s;
        __syncthreads();
    }
    if (t < nb) boff[t] = buf[t] - v;
    if (t == nb - 1) rowptr[n] = buf[t];
}

__global__ __launch_bounds__(SCAN_B) void scan3_k(const int* __restrict__ cnt,
                                                  const int* __restrict__ incl,
                                                  const int* __restrict__ boff,
                                                  int* __restrict__ rowptr,
                                                  int* __restrict__ cursor, int n) {
    int i = blockIdx.x * SCAN_B + threadIdx.x;
    if (i >= n) return;
    int ex = boff[blockIdx.x] + incl[i] - cnt[i];
    rowptr[i] = ex;
    cursor[i] = ex;
}

// ---------------------------------------------------------------------------
// Reorder, fused norm, packed (src, norm) int2: one 8B scattered store/edge.
// ---------------------------------------------------------------------------
__global__ void reorder_k(const int* __restrict__ src, const int* __restrict__ dst,
                          const float* __restrict__ ew, const float* __restrict__ dinv,
                          int* __restrict__ cursor, int2* __restrict__ csr, int ne) {
    int e = blockIdx.x * blockDim.x + threadIdx.x;
    if (e >= ne) return;
    int s = src[e], d = dst[e];
    int slot = atomicAdd(&cursor[d], 1);
    csr[slot] = make_int2(s, __float_as_int(dinv[s] * ew[e] * dinv[d]));
}

// ---------------------------------------------------------------------------
// W (f32 [k][c] row-major) -> Wt (bf16 [c][k] row-major). One block.
// ---------------------------------------------------------------------------
__global__ __launch_bounds__(256) void wtrans_k(const float* __restrict__ W,
                                                unsigned short* __restrict__ Wt) {
    for (int idx = threadIdx.x; idx < HDIM * HDIM; idx += 256) {
        int c = idx >> 7, k = idx & 127;
        Wt[idx] = (unsigned short)f2bf(W[k * HDIM + c]);
    }
}

// ---------------------------------------------------------------------------
// MFMA GEMM: Yb(bf16) = X(f32) @ W via Wt(bf16, transposed).
// Block: 256 thr = 4 waves; tile 16 rows x 128 cols; wave w -> cols 32w..32w+31.
// v_mfma_f32_16x16x32_bf16: A/B frag lane l elem i -> [l&15][(l>>4)*8+i];
// D: col=l&15, row=(l>>4)*4+reg  [m89-verified layout].
// ---------------------------------------------------------------------------
__global__ __launch_bounds__(256) void mfma_gemm_k(const float* __restrict__ X,
                                                   const unsigned short* __restrict__ Wt,
                                                   unsigned short* __restrict__ Y16,
                                                   int nrows) {
    __shared__ unsigned short WtL[HDIM][136];  // 34.8 KB (+8 pad: 2-way banks only)
    __shared__ unsigned short At[16][136];     // 4.4 KB

    // stage Wt (bf16, row-major [c][k]) into LDS, 16B chunks
    for (int idx = threadIdx.x; idx < HDIM * 16; idx += 256) {
        int row = idx >> 4, q = idx & 15;
        *(uint4*)&WtL[row][q * 8] = *(const uint4*)&Wt[row * HDIM + q * 8];
    }
    __syncthreads();

    const int lane = threadIdx.x & 63;
    const int wave = threadIdx.x >> 6;
    const int col0 = wave * 32 + (lane & 15);
    const int koff = (lane >> 4) * 8;
    const int rsub = (lane >> 4) * 4;

    for (int row0 = blockIdx.x * 16; row0 < nrows; row0 += gridDim.x * 16) {
        // stage 16 rows of X as bf16: thread t -> row t>>4, 8 cols at (t&15)*8
        {
            int r = threadIdx.x >> 4;
            int c8 = (threadIdx.x & 15) * 8;
            float4 v0 = make_float4(0.f, 0.f, 0.f, 0.f), v1 = v0;
            if (row0 + r < nrows) {
                const float4* xp = (const float4*)(X + (size_t)(row0 + r) * HDIM + c8);
                v0 = xp[0]; v1 = xp[1];
            }
            unsigned short tmp[8];
            tmp[0] = f2bf(v0.x); tmp[1] = f2bf(v0.y); tmp[2] = f2bf(v0.z); tmp[3] = f2bf(v0.w);
            tmp[4] = f2bf(v1.x); tmp[5] = f2bf(v1.y); tmp[6] = f2bf(v1.z); tmp[7] = f2bf(v1.w);
            *(short8*)&At[r][c8] = *(short8*)tmp;
        }
        __syncthreads();

        f32x4 acc0 = {0.f, 0.f, 0.f, 0.f};
        f32x4 acc1 = {0.f, 0.f, 0.f, 0.f};
#pragma unroll
        for (int kb = 0; kb < 4; ++kb) {
            short8 a  = *(const short8*)&At[lane & 15][kb * 32 + koff];
            short8 b0 = *(const short8*)&WtL[col0][kb * 32 + koff];
            short8 b1 = *(const short8*)&WtL[col0 + 16][kb * 32 + koff];
            acc0 = __builtin_amdgcn_mfma_f32_16x16x32_bf16(a, b0, acc0, 0, 0, 0);
            acc1 = __builtin_amdgcn_mfma_f32_16x16x32_bf16(a, b1, acc1, 0, 0, 0);
        }
#pragma unroll
        for (int r = 0; r < 4; ++r) {
            int row = row0 + rsub + r;
            if (row < nrows) {
                Y16[(size_t)row * HDIM + col0]      = (unsigned short)f2bf(acc0[r]);
                Y16[(size_t)row * HDIM + col0 + 16] = (unsigned short)f2bf(acc1[r]);
            }
        }
        __syncthreads();
    }
}

// ---------------------------------------------------------------------------
// Fused CSR gather + finalize; XW rows in bf16 (256B/row), 4-edge unroll.
// OUT(f32) = elu(sum_e XW[src_e]*norm_e + XW[node]*dinv^2 + b) [+ RES]
// ---------------------------------------------------------------------------
__device__ __forceinline__ float eluf(float v) { return v > 0.f ? v : expf(v) - 1.f; }

__global__ __launch_bounds__(256) void gather_k(const int* __restrict__ rowptr,
                                                const int2* __restrict__ csr,
                                                const unsigned int* __restrict__ XWb,
                                                const float* __restrict__ dinv,
                                                const float* __restrict__ bias,
                                                const float* RES, float* __restrict__ OUT,
                                                int n) {
    int wid = threadIdx.x >> 6;
    int lane = threadIdx.x & 63;
    int node = blockIdx.x * 4 + wid;
    if (node >= n) return;
    int s = rowptr[node];
    const int end = rowptr[node + 1];

    float2 acc0 = make_float2(0.f, 0.f);
    float2 acc1 = make_float2(0.f, 0.f);

    for (; s + 3 < end; s += 4) {
        int2 e0 = csr[s], e1 = csr[s + 1], e2 = csr[s + 2], e3 = csr[s + 3];
        unsigned int u0 = (XWb + (size_t)e0.x * 64)[lane];
        unsigned int u1 = (XWb + (size_t)e1.x * 64)[lane];
        unsigned int u2 = (XWb + (size_t)e2.x * 64)[lane];
        unsigned int u3 = (XWb + (size_t)e3.x * 64)[lane];
        float n0 = __int_as_float(e0.y), n1 = __int_as_float(e1.y);
        float n2 = __int_as_float(e2.y), n3 = __int_as_float(e3.y);
        acc0.x += bf_lo(u0) * n0; acc0.y += bf_hi(u0) * n0;
        acc1.x += bf_lo(u1) * n1; acc1.y += bf_hi(u1) * n1;
        acc0.x += bf_lo(u2) * n2; acc0.y += bf_hi(u2) * n2;
        acc1.x += bf_lo(u3) * n3; acc1.y += bf_hi(u3) * n3;
    }
    for (; s < end; ++s) {
        int2 e0 = csr[s];
        unsigned int u0 = (XWb + (size_t)e0.x * 64)[lane];
        float n0 = __int_as_float(e0.y);
        acc0.x += bf_lo(u0) * n0; acc0.y += bf_hi(u0) * n0;
    }

    float di = dinv[node];
    di = di * di;
    unsigned int us = (XWb + (size_t)node * 64)[lane];
    float2 bv = ((const float2*)bias)[lane];
    float2 o;
    o.x = eluf(acc0.x + acc1.x + bf_lo(us) * di + bv.x);
    o.y = eluf(acc0.y + acc1.y + bf_hi(us) * di + bv.y);
    if (RES) {
        float2 rv = ((const float2*)(RES + (size_t)node * HDIM))[lane];
        o.x += rv.x; o.y += rv.y;
    }
    ((float2*)(OUT + (size_t)node * HDIM))[lane] = o;
}

// ---------------------------------------------------------------------------
// Head: out[n] = sigmoid(dot(H3[n], Wl) + bl).  One wave per node.
// ---------------------------------------------------------------------------
__global__ __launch_bounds__(256) void head_k(const float* __restrict__ H3,
                                              const float* __restrict__ Wl,
                                              const float* __restrict__ bl,
                                              float* __restrict__ out, int n) {
    int wid = threadIdx.x >> 6;
    int lane = threadIdx.x & 63;
    int node = blockIdx.x * 4 + wid;
    if (node >= n) return;
    float2 h = ((const float2*)(H3 + (size_t)node * HDIM))[lane];
    float2 w = ((const float2*)Wl)[lane];
    float acc = h.x * w.x + h.y * w.y;
#pragma unroll
    for (int off = 32; off > 0; off >>= 1) acc += __shfl_down(acc, off);
    if (lane == 0) out[node] = 1.f / (1.f + expf(-(acc + bl[0])));
}

// ---------------------------------------------------------------------------
extern "C" void kernel_launch(void* const* d_in, const int* in_sizes, int n_in,
                              void* d_out, int out_size, void* d_ws, size_t ws_size,
                              hipStream_t stream) {
    const float* x  = (const float*)d_in[0];
    const int*   ei = (const int*)d_in[1];
    const float* ew = (const float*)d_in[2];
    const float* W1 = (const float*)d_in[3];
    const float* b1 = (const float*)d_in[4];
    const float* W2 = (const float*)d_in[5];
    const float* b2 = (const float*)d_in[6];
    const float* W3 = (const float*)d_in[7];
    const float* b3 = (const float*)d_in[8];
    const float* Wl = (const float*)d_in[9];
    const float* bl = (const float*)d_in[10];
    float* out = (float*)d_out;

    char* ws = (char*)d_ws;
    const size_t NHB = (size_t)N_NODES * HDIM * sizeof(float);  // 25.6 MB
    unsigned int* A = (unsigned int*)(ws);            // XW in bf16 (12.8 MB used)
    float* B    = (float*)(ws + NHB);                 // h1 / h3 (f32)
    float* C    = (float*)(ws + 2 * NHB);             // h2 (f32)
    char*  p    = ws + 3 * NHB;
    unsigned long long* pcnt = (unsigned long long*)p; p += sizeof(unsigned long long) * N_NODES;
    float* dinv    = (float*)p;            p += sizeof(float) * N_NODES;
    int*   src32   = (int*)p;              p += sizeof(int) * N_EDGES;
    int*   dst32   = (int*)p;              p += sizeof(int) * N_EDGES;
    int*   cnt     = (int*)p;              p += sizeof(int) * N_NODES;
    int*   incl    = (int*)p;              p += sizeof(int) * N_NODES;
    int*   rowptr  = (int*)p;              p += sizeof(int) * (N_NODES + 2);  // +2 keeps 8B align
    int*   cursor  = (int*)p;              p += sizeof(int) * N_NODES;
    int2*  csr     = (int2*)p;             p += sizeof(int2) * N_EDGES;
    unsigned short* Wt1 = (unsigned short*)p; p += sizeof(unsigned short) * HDIM * HDIM;
    unsigned short* Wt2 = (unsigned short*)p; p += sizeof(unsigned short) * HDIM * HDIM;
    unsigned short* Wt3 = (unsigned short*)p; p += sizeof(unsigned short) * HDIM * HDIM;
    int*   bsum    = (int*)p;              p += sizeof(int) * 128;
    int*   boff    = (int*)p;              p += sizeof(int) * 128;
    int*   flag    = (int*)p;

    const int TB = 256;
    const int egrid = (N_EDGES + TB - 1) / TB;
    const int ngrid = (N_NODES + TB - 1) / TB;
    const int ggrid = (N_NODES + 3) / 4;

    // --- graph preprocessing (identical every call) ---
    detect_mode_k<<<1, 256, 0, stream>>>(ei, flag);
    convert_idx_k<<<egrid, TB, 0, stream>>>(ei, flag, src32, dst32, N_EDGES);
    hipMemsetAsync(pcnt, 0, N_NODES * sizeof(unsigned long long), stream);
    wtrans_k<<<1, 256, 0, stream>>>(W1, Wt1);
    wtrans_k<<<1, 256, 0, stream>>>(W2, Wt2);
    wtrans_k<<<1, 256, 0, stream>>>(W3, Wt3);
    deghist_k<<<egrid, TB, 0, stream>>>(dst32, ew, pcnt, N_EDGES);
    unpack_k<<<ngrid, TB, 0, stream>>>(pcnt, dinv, cnt, N_NODES);
    scan1_k<<<SCAN_NB, SCAN_B, 0, stream>>>(cnt, incl, bsum, N_NODES);
    scan2_k<<<1, 128, 0, stream>>>(bsum, boff, rowptr, SCAN_NB, N_NODES);
    scan3_k<<<SCAN_NB, SCAN_B, 0, stream>>>(cnt, incl, boff, rowptr, cursor, N_NODES);
    reorder_k<<<egrid, TB, 0, stream>>>(src32, dst32, ew, dinv, cursor, csr, N_EDGES);

    // --- layer 1: h1 = elu(gcn(x, W1, b1)) -> B ---
    mfma_gemm_k<<<1024, TB, 0, stream>>>(x, Wt1, (unsigned short*)A, N_NODES);
    gather_k<<<ggrid, TB, 0, stream>>>(rowptr, csr, A, dinv, b1, nullptr, B, N_NODES);

    // --- layer 2: h2 = elu(gcn(h1, W2, b2)) + h1 -> C ---
    mfma_gemm_k<<<1024, TB, 0, stream>>>(B, Wt2, (unsigned short*)A, N_NODES);
    gather_k<<<ggrid, TB, 0, stream>>>(rowptr, csr, A, dinv, b2, B, C, N_NODES);

    // --- layer 3: h3 = elu(gcn(h2, W3, b3)) + h2 -> B ---
    mfma_gemm_k<<<1024, TB, 0, stream>>>(C, Wt3, (unsigned short*)A, N_NODES);
    gather_k<<<ggrid, TB, 0, stream>>>(rowptr, csr, A, dinv, b3, C, B, N_NODES);

    // --- head: out = sigmoid(h3 @ Wl + bl) ---
    head_k<<<(N_NODES + 3) / 4, TB, 0, stream>>>(B, Wl, bl, out, N_NODES);
}

// Round 14
// 255.685 us; speedup vs baseline: 16.7457x; 1.1860x over previous
//
#include <hip/hip_runtime.h>
#include <math.h>

#define N_NODES 50000
#define N_EDGES 800000
#define HDIM 128
#define SCAN_B 512
#define SCAN_NB ((N_NODES + SCAN_B - 1) / SCAN_B)   // 98

typedef __attribute__((ext_vector_type(8))) short short8;
typedef __attribute__((ext_vector_type(4))) float f32x4;

// bf16 helpers (manual RNE; bf16->f32 is a 16-bit shift)
__device__ __forceinline__ unsigned int f2bf(float f) {
    unsigned int u = __float_as_uint(f);
    return (u + 0x7fffu + ((u >> 16) & 1u)) >> 16;
}
__device__ __forceinline__ float bf_lo(unsigned int u) { return __uint_as_float(u << 16); }
__device__ __forceinline__ float bf_hi(unsigned int u) { return __uint_as_float(u & 0xffff0000u); }

// ---------------------------------------------------------------------------
// Edge-index layout probe (int64 vs int32 buffer layout). Deterministic.
// ---------------------------------------------------------------------------
__global__ void detect_mode_k(const int* __restrict__ ei, int* __restrict__ flag) {
    __shared__ int nz;
    if (threadIdx.x == 0) nz = 0;
    __syncthreads();
    for (int i = threadIdx.x; i < 4096; i += blockDim.x) {
        if (ei[2 * i + 1] != 0) atomicOr(&nz, 1);
    }
    __syncthreads();
    if (threadIdx.x == 0) *flag = (nz == 0) ? 1 : 0;  // 1 => int64 layout
}

// ---------------------------------------------------------------------------
// Fused convert + packed degree/count. ONE edge pass, ONE 64-bit atomic/edge.
// pcnt: high 32 = count, low 32 = sum(ew * 2^24) fixed-point.
// ---------------------------------------------------------------------------
__global__ void edges_k(const int* __restrict__ ei, const int* __restrict__ flag,
                        const float* __restrict__ ew,
                        int* __restrict__ src32, int* __restrict__ dst32,
                        unsigned long long* __restrict__ pcnt, int ne) {
    int e = blockIdx.x * blockDim.x + threadIdx.x;
    if (e >= ne) return;
    int s, d;
    if (*flag) {
        s = ei[2 * e];
        d = ei[2 * (ne + e)];
    } else {
        s = ei[e];
        d = ei[ne + e];
    }
    src32[e] = s;
    dst32[e] = d;
    unsigned int q = __float2uint_rn(ew[e] * 16777216.0f);
    atomicAdd(&pcnt[d], (1ULL << 32) | (unsigned long long)q);
}

// ---------------------------------------------------------------------------
// Hierarchical exclusive scan of counts (high word of pcnt) -> rowptr/cursor.
// scan1 also emits dinv (fused unpack).
// ---------------------------------------------------------------------------
__global__ __launch_bounds__(SCAN_B) void scan1_k(const unsigned long long* __restrict__ pcnt,
                                                  int* __restrict__ incl,
                                                  int* __restrict__ bsum,
                                                  float* __restrict__ dinv, int n) {
    __shared__ int buf[SCAN_B];
    int i = blockIdx.x * SCAN_B + threadIdx.x;
    unsigned long long v64 = (i < n) ? pcnt[i] : 0ULL;
    int v = (int)(v64 >> 32);
    buf[threadIdx.x] = v;
    __syncthreads();
#pragma unroll
    for (int off = 1; off < SCAN_B; off <<= 1) {
        int t = (threadIdx.x >= off) ? buf[threadIdx.x - off] : 0;
        __syncthreads();
        buf[threadIdx.x] += t;
        __syncthreads();
    }
    if (i < n) {
        incl[i] = buf[threadIdx.x];
        float deg = (float)(unsigned int)(v64 & 0xffffffffULL) * (1.0f / 16777216.0f);
        dinv[i] = rsqrtf(deg + 1.0f);
    }
    if (threadIdx.x == SCAN_B - 1) bsum[blockIdx.x] = buf[threadIdx.x];
}

__global__ __launch_bounds__(128) void scan2_k(const int* __restrict__ bsum,
                                               int* __restrict__ boff,
                                               int* __restrict__ rowptr, int nb, int n) {
    __shared__ int buf[128];
    int t = threadIdx.x;
    int v = (t < nb) ? bsum[t] : 0;
    buf[t] = v;
    __syncthreads();
#pragma unroll
    for (int off = 1; off < 128; off <<= 1) {
        int s = (t >= off) ? buf[t - off] : 0;
        __syncthreads();
        buf[t] += s;
        __syncthreads();
    }
    if (t < nb) boff[t] = buf[t] - v;
    if (t == nb - 1) rowptr[n] = buf[t];
}

__global__ __launch_bounds__(SCAN_B) void scan3_k(const unsigned long long* __restrict__ pcnt,
                                                  const int* __restrict__ incl,
                                                  const int* __restrict__ boff,
                                                  int* __restrict__ rowptr,
                                                  int* __restrict__ cursor, int n) {
    int i = blockIdx.x * SCAN_B + threadIdx.x;
    if (i >= n) return;
    int c = (int)(pcnt[i] >> 32);
    int ex = boff[blockIdx.x] + incl[i] - c;
    rowptr[i] = ex;
    cursor[i] = ex;
}

// ---------------------------------------------------------------------------
// Reorder, fused norm, packed (src, norm) int2: one 8B scattered store/edge.
// ---------------------------------------------------------------------------
__global__ void reorder_k(const int* __restrict__ src, const int* __restrict__ dst,
                          const float* __restrict__ ew, const float* __restrict__ dinv,
                          int* __restrict__ cursor, int2* __restrict__ csr, int ne) {
    int e = blockIdx.x * blockDim.x + threadIdx.x;
    if (e >= ne) return;
    int s = src[e], d = dst[e];
    int slot = atomicAdd(&cursor[d], 1);
    csr[slot] = make_int2(s, __float_as_int(dinv[s] * ew[e] * dinv[d]));
}

// ---------------------------------------------------------------------------
// W (f32 [k][c] row-major) -> Wt (bf16 [c][k] row-major). 64 blocks.
// ---------------------------------------------------------------------------
__global__ __launch_bounds__(256) void wtrans_k(const float* __restrict__ W,
                                                unsigned short* __restrict__ Wt) {
    for (int idx = blockIdx.x * 256 + threadIdx.x; idx < HDIM * HDIM; idx += gridDim.x * 256) {
        int c = idx >> 7, k = idx & 127;
        Wt[idx] = (unsigned short)f2bf(W[k * HDIM + c]);
    }
}

// ---------------------------------------------------------------------------
// MFMA GEMM: Yb(bf16) = X(f32) @ W via Wt(bf16, transposed).
// Block: 256 thr = 4 waves; tile 16 rows x 128 cols; wave w -> cols 32w..32w+31.
// v_mfma_f32_16x16x32_bf16: A/B frag lane l elem i -> [l&15][(l>>4)*8+i];
// D: col=l&15, row=(l>>4)*4+reg  [m89-verified layout].
// ---------------------------------------------------------------------------
__global__ __launch_bounds__(256) void mfma_gemm_k(const float* __restrict__ X,
                                                   const unsigned short* __restrict__ Wt,
                                                   unsigned short* __restrict__ Y16,
                                                   int nrows) {
    __shared__ unsigned short WtL[HDIM][136];  // 34.8 KB (+8 pad: 2-way banks only)
    __shared__ unsigned short At[16][136];     // 4.4 KB

    for (int idx = threadIdx.x; idx < HDIM * 16; idx += 256) {
        int row = idx >> 4, q = idx & 15;
        *(uint4*)&WtL[row][q * 8] = *(const uint4*)&Wt[row * HDIM + q * 8];
    }
    __syncthreads();

    const int lane = threadIdx.x & 63;
    const int wave = threadIdx.x >> 6;
    const int col0 = wave * 32 + (lane & 15);
    const int koff = (lane >> 4) * 8;
    const int rsub = (lane >> 4) * 4;

    for (int row0 = blockIdx.x * 16; row0 < nrows; row0 += gridDim.x * 16) {
        {
            int r = threadIdx.x >> 4;
            int c8 = (threadIdx.x & 15) * 8;
            float4 v0 = make_float4(0.f, 0.f, 0.f, 0.f), v1 = v0;
            if (row0 + r < nrows) {
                const float4* xp = (const float4*)(X + (size_t)(row0 + r) * HDIM + c8);
                v0 = xp[0]; v1 = xp[1];
            }
            unsigned short tmp[8];
            tmp[0] = f2bf(v0.x); tmp[1] = f2bf(v0.y); tmp[2] = f2bf(v0.z); tmp[3] = f2bf(v0.w);
            tmp[4] = f2bf(v1.x); tmp[5] = f2bf(v1.y); tmp[6] = f2bf(v1.z); tmp[7] = f2bf(v1.w);
            *(short8*)&At[r][c8] = *(short8*)tmp;
        }
        __syncthreads();

        f32x4 acc0 = {0.f, 0.f, 0.f, 0.f};
        f32x4 acc1 = {0.f, 0.f, 0.f, 0.f};
#pragma unroll
        for (int kb = 0; kb < 4; ++kb) {
            short8 a  = *(const short8*)&At[lane & 15][kb * 32 + koff];
            short8 b0 = *(const short8*)&WtL[col0][kb * 32 + koff];
            short8 b1 = *(const short8*)&WtL[col0 + 16][kb * 32 + koff];
            acc0 = __builtin_amdgcn_mfma_f32_16x16x32_bf16(a, b0, acc0, 0, 0, 0);
            acc1 = __builtin_amdgcn_mfma_f32_16x16x32_bf16(a, b1, acc1, 0, 0, 0);
        }
#pragma unroll
        for (int r = 0; r < 4; ++r) {
            int row = row0 + rsub + r;
            if (row < nrows) {
                Y16[(size_t)row * HDIM + col0]      = (unsigned short)f2bf(acc0[r]);
                Y16[(size_t)row * HDIM + col0 + 16] = (unsigned short)f2bf(acc1[r]);
            }
        }
        __syncthreads();
    }
}

// ---------------------------------------------------------------------------
// Fused CSR gather + finalize; XW rows bf16 (256B/row), 8-edge unroll,
// 4 accumulator chains. Plain loads (nt loads caused replay divergence, r13).
// OUT(f32) = elu(sum_e XW[src_e]*norm_e + XW[node]*dinv^2 + b) [+ RES]
// ---------------------------------------------------------------------------
__device__ __forceinline__ float eluf(float v) { return v > 0.f ? v : expf(v) - 1.f; }

__device__ __forceinline__ void gat_edge(const unsigned long long c,
                                         const unsigned int* __restrict__ XWb,
                                         int lane, float2* acc) {
    int sidx = (int)(c & 0xffffffffULL);
    float nm = __uint_as_float((unsigned int)(c >> 32));
    unsigned int u = (XWb + (size_t)sidx * 64)[lane];
    acc->x += bf_lo(u) * nm;
    acc->y += bf_hi(u) * nm;
}

__global__ __launch_bounds__(256) void gather_k(const int* __restrict__ rowptr,
                                                const unsigned long long* __restrict__ csr,
                                                const unsigned int* __restrict__ XWb,
                                                const float* __restrict__ dinv,
                                                const float* __restrict__ bias,
                                                const float* RES, float* __restrict__ OUT,
                                                int n) {
    int wid = threadIdx.x >> 6;
    int lane = threadIdx.x & 63;
    int node = blockIdx.x * 4 + wid;
    if (node >= n) return;
    int s = rowptr[node];
    const int end = rowptr[node + 1];

    float2 a0 = make_float2(0.f, 0.f), a1 = a0, a2 = a0, a3 = a0;

    for (; s + 7 < end; s += 8) {
        unsigned long long c0 = csr[s];
        unsigned long long c1 = csr[s + 1];
        unsigned long long c2 = csr[s + 2];
        unsigned long long c3 = csr[s + 3];
        unsigned long long c4 = csr[s + 4];
        unsigned long long c5 = csr[s + 5];
        unsigned long long c6 = csr[s + 6];
        unsigned long long c7 = csr[s + 7];
        gat_edge(c0, XWb, lane, &a0);
        gat_edge(c1, XWb, lane, &a1);
        gat_edge(c2, XWb, lane, &a2);
        gat_edge(c3, XWb, lane, &a3);
        gat_edge(c4, XWb, lane, &a0);
        gat_edge(c5, XWb, lane, &a1);
        gat_edge(c6, XWb, lane, &a2);
        gat_edge(c7, XWb, lane, &a3);
    }
    for (; s + 1 < end; s += 2) {
        unsigned long long c0 = csr[s];
        unsigned long long c1 = csr[s + 1];
        gat_edge(c0, XWb, lane, &a0);
        gat_edge(c1, XWb, lane, &a1);
    }
    if (s < end) {
        gat_edge(csr[s], XWb, lane, &a0);
    }

    float di = dinv[node];
    di = di * di;
    unsigned int us = (XWb + (size_t)node * 64)[lane];
    float2 bv = ((const float2*)bias)[lane];
    float2 o;
    o.x = eluf(a0.x + a1.x + a2.x + a3.x + bf_lo(us) * di + bv.x);
    o.y = eluf(a0.y + a1.y + a2.y + a3.y + bf_hi(us) * di + bv.y);
    if (RES) {
        float2 rv = ((const float2*)(RES + (size_t)node * HDIM))[lane];
        o.x += rv.x; o.y += rv.y;
    }
    ((float2*)(OUT + (size_t)node * HDIM))[lane] = o;
}

// ---------------------------------------------------------------------------
// Layer-3 gather fused with head: out[n]=sigmoid(dot(h3[n],Wl)+bl).
// h3 never hits memory.
// ---------------------------------------------------------------------------
__global__ __launch_bounds__(256) void gather_head_k(const int* __restrict__ rowptr,
                                                     const unsigned long long* __restrict__ csr,
                                                     const unsigned int* __restrict__ XWb,
                                                     const float* __restrict__ dinv,
                                                     const float* __restrict__ bias,
                                                     const float* __restrict__ RES,
                                                     const float* __restrict__ Wl,
                                                     const float* __restrict__ bl,
                                                     float* __restrict__ out, int n) {
    int wid = threadIdx.x >> 6;
    int lane = threadIdx.x & 63;
    int node = blockIdx.x * 4 + wid;
    if (node >= n) return;
    int s = rowptr[node];
    const int end = rowptr[node + 1];

    float2 a0 = make_float2(0.f, 0.f), a1 = a0, a2 = a0, a3 = a0;

    for (; s + 7 < end; s += 8) {
        unsigned long long c0 = csr[s];
        unsigned long long c1 = csr[s + 1];
        unsigned long long c2 = csr[s + 2];
        unsigned long long c3 = csr[s + 3];
        unsigned long long c4 = csr[s + 4];
        unsigned long long c5 = csr[s + 5];
        unsigned long long c6 = csr[s + 6];
        unsigned long long c7 = csr[s + 7];
        gat_edge(c0, XWb, lane, &a0);
        gat_edge(c1, XWb, lane, &a1);
        gat_edge(c2, XWb, lane, &a2);
        gat_edge(c3, XWb, lane, &a3);
        gat_edge(c4, XWb, lane, &a0);
        gat_edge(c5, XWb, lane, &a1);
        gat_edge(c6, XWb, lane, &a2);
        gat_edge(c7, XWb, lane, &a3);
    }
    for (; s + 1 < end; s += 2) {
        unsigned long long c0 = csr[s];
        unsigned long long c1 = csr[s + 1];
        gat_edge(c0, XWb, lane, &a0);
        gat_edge(c1, XWb, lane, &a1);
    }
    if (s < end) {
        gat_edge(csr[s], XWb, lane, &a0);
    }

    float di = dinv[node];
    di = di * di;
    unsigned int us = (XWb + (size_t)node * 64)[lane];
    float2 bv = ((const float2*)bias)[lane];
    float2 rv = ((const float2*)(RES + (size_t)node * HDIM))[lane];
    float2 o;
    o.x = eluf(a0.x + a1.x + a2.x + a3.x + bf_lo(us) * di + bv.x) + rv.x;
    o.y = eluf(a0.y + a1.y + a2.y + a3.y + bf_hi(us) * di + bv.y) + rv.y;

    float2 wv = ((const float2*)Wl)[lane];
    float acc = o.x * wv.x + o.y * wv.y;
#pragma unroll
    for (int off = 32; off > 0; off >>= 1) acc += __shfl_down(acc, off);
    if (lane == 0) out[node] = 1.f / (1.f + expf(-(acc + bl[0])));
}

// ---------------------------------------------------------------------------
extern "C" void kernel_launch(void* const* d_in, const int* in_sizes, int n_in,
                              void* d_out, int out_size, void* d_ws, size_t ws_size,
                              hipStream_t stream) {
    const float* x  = (const float*)d_in[0];
    const int*   ei = (const int*)d_in[1];
    const float* ew = (const float*)d_in[2];
    const float* W1 = (const float*)d_in[3];
    const float* b1 = (const float*)d_in[4];
    const float* W2 = (const float*)d_in[5];
    const float* b2 = (const float*)d_in[6];
    const float* W3 = (const float*)d_in[7];
    const float* b3 = (const float*)d_in[8];
    const float* Wl = (const float*)d_in[9];
    const float* bl = (const float*)d_in[10];
    float* out = (float*)d_out;

    char* ws = (char*)d_ws;
    const size_t NHB = (size_t)N_NODES * HDIM * sizeof(float);  // 25.6 MB
    unsigned int* A = (unsigned int*)(ws);            // XW in bf16 (12.8 MB used)
    float* B    = (float*)(ws + NHB);                 // h1
    float* C    = (float*)(ws + 2 * NHB);             // h2
    char*  p    = ws + 3 * NHB;
    unsigned long long* pcnt = (unsigned long long*)p; p += sizeof(unsigned long long) * N_NODES;
    float* dinv    = (float*)p;            p += sizeof(float) * N_NODES;
    int*   src32   = (int*)p;              p += sizeof(int) * N_EDGES;
    int*   dst32   = (int*)p;              p += sizeof(int) * N_EDGES;
    int*   incl    = (int*)p;              p += sizeof(int) * N_NODES;
    int*   rowptr  = (int*)p;              p += sizeof(int) * (N_NODES + 2);  // +2 keeps 8B align
    int*   cursor  = (int*)p;              p += sizeof(int) * N_NODES;
    int2*  csr     = (int2*)p;             p += sizeof(int2) * N_EDGES;
    unsigned short* Wt1 = (unsigned short*)p; p += sizeof(unsigned short) * HDIM * HDIM;
    unsigned short* Wt2 = (unsigned short*)p; p += sizeof(unsigned short) * HDIM * HDIM;
    unsigned short* Wt3 = (unsigned short*)p; p += sizeof(unsigned short) * HDIM * HDIM;
    int*   bsum    = (int*)p;              p += sizeof(int) * 128;
    int*   boff    = (int*)p;              p += sizeof(int) * 128;
    int*   flag    = (int*)p;

    const int TB = 256;
    const int egrid = (N_EDGES + TB - 1) / TB;
    const int ggrid = (N_NODES + 3) / 4;

    // --- graph preprocessing (identical every call) ---
    hipMemsetAsync(pcnt, 0, N_NODES * sizeof(unsigned long long), stream);
    detect_mode_k<<<1, 256, 0, stream>>>(ei, flag);
    edges_k<<<egrid, TB, 0, stream>>>(ei, flag, ew, src32, dst32, pcnt, N_EDGES);
    wtrans_k<<<64, 256, 0, stream>>>(W1, Wt1);
    wtrans_k<<<64, 256, 0, stream>>>(W2, Wt2);
    wtrans_k<<<64, 256, 0, stream>>>(W3, Wt3);
    scan1_k<<<SCAN_NB, SCAN_B, 0, stream>>>(pcnt, incl, bsum, dinv, N_NODES);
    scan2_k<<<1, 128, 0, stream>>>(bsum, boff, rowptr, SCAN_NB, N_NODES);
    scan3_k<<<SCAN_NB, SCAN_B, 0, stream>>>(pcnt, incl, boff, rowptr, cursor, N_NODES);
    reorder_k<<<egrid, TB, 0, stream>>>(src32, dst32, ew, dinv, cursor, csr, N_EDGES);

    // --- layer 1: h1 = elu(gcn(x, W1, b1)) -> B ---
    mfma_gemm_k<<<1024, TB, 0, stream>>>(x, Wt1, (unsigned short*)A, N_NODES);
    gather_k<<<ggrid, TB, 0, stream>>>(rowptr, (const unsigned long long*)csr, A, dinv, b1, nullptr, B, N_NODES);

    // --- layer 2: h2 = elu(gcn(h1, W2, b2)) + h1 -> C ---
    mfma_gemm_k<<<1024, TB, 0, stream>>>(B, Wt2, (unsigned short*)A, N_NODES);
    gather_k<<<ggrid, TB, 0, stream>>>(rowptr, (const unsigned long long*)csr, A, dinv, b2, B, C, N_NODES);

    // --- layer 3 + head fused: out = sigmoid((elu(gcn(h2,W3,b3))+h2) @ Wl + bl) ---
    mfma_gemm_k<<<1024, TB, 0, stream>>>(C, Wt3, (unsigned short*)A, N_NODES);
    gather_head_k<<<ggrid, TB, 0, stream>>>(rowptr, (const unsigned long long*)csr, A, dinv, b3, C, Wl, bl, out, N_NODES);
}

// Round 15
// 237.726 us; speedup vs baseline: 18.0109x; 1.0755x over previous
//
#include <hip/hip_runtime.h>
#include <hip/hip_fp16.h>
#include <math.h>

#define N_NODES 50000
#define N_EDGES 800000
#define HDIM 128
#define SCAN_B 512
#define SCAN_NB ((N_NODES + SCAN_B - 1) / SCAN_B)   // 98

typedef __attribute__((ext_vector_type(8))) short short8;
typedef __attribute__((ext_vector_type(4))) float f32x4;

// bf16 helpers (manual RNE; bf16->f32 is a 16-bit shift)
__device__ __forceinline__ unsigned int f2bf(float f) {
    unsigned int u = __float_as_uint(f);
    return (u + 0x7fffu + ((u >> 16) & 1u)) >> 16;
}
__device__ __forceinline__ float bf_lo(unsigned int u) { return __uint_as_float(u << 16); }
__device__ __forceinline__ float bf_hi(unsigned int u) { return __uint_as_float(u & 0xffff0000u); }

// ---------------------------------------------------------------------------
// Fused convert + packed degree/count, with per-block int64/int32 layout
// self-detection (drops the separate detect kernel). 256 odd-word samples per
// block: all-zero <=> int64 layout (P(false positive) ~ (2e-5)^256 ~ 0).
// pcnt: high 32 = count, low 32 = sum(ew * 2^24) fixed-point.
// ---------------------------------------------------------------------------
__global__ __launch_bounds__(256) void edges_k(const int* __restrict__ ei,
                                               const float* __restrict__ ew,
                                               int* __restrict__ src32, int* __restrict__ dst32,
                                               unsigned long long* __restrict__ pcnt, int ne) {
    __shared__ int nz;
    if (threadIdx.x == 0) nz = 0;
    __syncthreads();
    int e = blockIdx.x * 256 + threadIdx.x;
    int odd = (e < ne) ? ei[2 * e + 1] : 0;
    if (odd) atomicOr(&nz, 1);
    __syncthreads();
    if (e >= ne) return;
    int s, d;
    if (nz == 0) {  // int64 layout: low words at even offsets
        s = ei[2 * e];
        d = ei[2 * (ne + e)];
    } else {        // int32 layout
        s = ei[e];
        d = ei[ne + e];
    }
    src32[e] = s;
    dst32[e] = d;
    unsigned int q = __float2uint_rn(ew[e] * 16777216.0f);
    atomicAdd(&pcnt[d], (1ULL << 32) | (unsigned long long)q);
}

// ---------------------------------------------------------------------------
// Hierarchical exclusive scan of counts (high word of pcnt) -> rowptr/cursor.
// scan1 also emits dinv (fused unpack). scan3 re-derives block offsets from
// bsum locally (drops scan2).
// ---------------------------------------------------------------------------
__global__ __launch_bounds__(SCAN_B) void scan1_k(const unsigned long long* __restrict__ pcnt,
                                                  int* __restrict__ incl,
                                                  int* __restrict__ bsum,
                                                  float* __restrict__ dinv, int n) {
    __shared__ int buf[SCAN_B];
    int i = blockIdx.x * SCAN_B + threadIdx.x;
    unsigned long long v64 = (i < n) ? pcnt[i] : 0ULL;
    int v = (int)(v64 >> 32);
    buf[threadIdx.x] = v;
    __syncthreads();
#pragma unroll
    for (int off = 1; off < SCAN_B; off <<= 1) {
        int t = (threadIdx.x >= off) ? buf[threadIdx.x - off] : 0;
        __syncthreads();
        buf[threadIdx.x] += t;
        __syncthreads();
    }
    if (i < n) {
        incl[i] = buf[threadIdx.x];
        float deg = (float)(unsigned int)(v64 & 0xffffffffULL) * (1.0f / 16777216.0f);
        dinv[i] = rsqrtf(deg + 1.0f);
    }
    if (threadIdx.x == SCAN_B - 1) bsum[blockIdx.x] = buf[threadIdx.x];
}

__global__ __launch_bounds__(SCAN_B) void scan3_k(const unsigned long long* __restrict__ pcnt,
                                                  const int* __restrict__ incl,
                                                  const int* __restrict__ bsum,
                                                  int* __restrict__ rowptr,
                                                  int* __restrict__ cursor, int n, int nb) {
    __shared__ int bs[128];
    if (threadIdx.x < 128) bs[threadIdx.x] = (threadIdx.x < nb) ? bsum[threadIdx.x] : 0;
    __syncthreads();
#pragma unroll
    for (int off = 1; off < 128; off <<= 1) {
        int t = 0;
        if (threadIdx.x < 128 && threadIdx.x >= off) t = bs[threadIdx.x - off];
        __syncthreads();
        if (threadIdx.x < 128) bs[threadIdx.x] += t;
        __syncthreads();
    }
    // bs now inclusive scan of bsum
    int i = blockIdx.x * SCAN_B + threadIdx.x;
    if (i < n) {
        int boff = (blockIdx.x == 0) ? 0 : bs[blockIdx.x - 1];
        int c = (int)(pcnt[i] >> 32);
        int ex = boff + incl[i] - c;
        rowptr[i] = ex;
        cursor[i] = ex;
    }
    if (blockIdx.x == 0 && threadIdx.x == 0) rowptr[n] = bs[nb - 1];
}

// ---------------------------------------------------------------------------
// Reorder, fused norm, packed (src:16 | norm fp16:16): one 4B store/edge.
// N_NODES < 65536 so src fits 16 bits.
// ---------------------------------------------------------------------------
__global__ void reorder_k(const int* __restrict__ src, const int* __restrict__ dst,
                          const float* __restrict__ ew, const float* __restrict__ dinv,
                          int* __restrict__ cursor, unsigned int* __restrict__ csr, int ne) {
    int e = blockIdx.x * blockDim.x + threadIdx.x;
    if (e >= ne) return;
    int s = src[e], d = dst[e];
    int slot = atomicAdd(&cursor[d], 1);
    float nm = dinv[s] * ew[e] * dinv[d];
    unsigned int h = (unsigned int)__half_as_ushort(__float2half(nm));
    csr[slot] = (unsigned int)s | (h << 16);
}

// ---------------------------------------------------------------------------
// All three W (f32 [k][c]) -> Wt (bf16 [c][k]). 192 blocks, 1 elem/thread.
// ---------------------------------------------------------------------------
__global__ __launch_bounds__(256) void wtrans3_k(const float* __restrict__ W1,
                                                 const float* __restrict__ W2,
                                                 const float* __restrict__ W3,
                                                 unsigned short* __restrict__ Wt1,
                                                 unsigned short* __restrict__ Wt2,
                                                 unsigned short* __restrict__ Wt3) {
    int which = blockIdx.x >> 6;          // 64 blocks per weight
    const float* W = (which == 0) ? W1 : (which == 1) ? W2 : W3;
    unsigned short* Wt = (which == 0) ? Wt1 : (which == 1) ? Wt2 : Wt3;
    int idx = (blockIdx.x & 63) * 256 + threadIdx.x;   // 0..16383
    int c = idx >> 7, k = idx & 127;
    Wt[idx] = (unsigned short)f2bf(W[k * HDIM + c]);
}

// ---------------------------------------------------------------------------
// MFMA GEMM: Yb(bf16) = X(f32) @ W via Wt(bf16, transposed).
// Block: 256 thr = 4 waves; tile 16 rows x 128 cols; wave w -> cols 32w..32w+31.
// v_mfma_f32_16x16x32_bf16: A/B frag lane l elem i -> [l&15][(l>>4)*8+i];
// D: col=l&15, row=(l>>4)*4+reg  [m89-verified layout].
// ---------------------------------------------------------------------------
__global__ __launch_bounds__(256) void mfma_gemm_k(const float* __restrict__ X,
                                                   const unsigned short* __restrict__ Wt,
                                                   unsigned short* __restrict__ Y16,
                                                   int nrows) {
    __shared__ unsigned short WtL[HDIM][136];  // 34.8 KB (+8 pad: 2-way banks only)
    __shared__ unsigned short At[16][136];     // 4.4 KB

    for (int idx = threadIdx.x; idx < HDIM * 16; idx += 256) {
        int row = idx >> 4, q = idx & 15;
        *(uint4*)&WtL[row][q * 8] = *(const uint4*)&Wt[row * HDIM + q * 8];
    }
    __syncthreads();

    const int lane = threadIdx.x & 63;
    const int wave = threadIdx.x >> 6;
    const int col0 = wave * 32 + (lane & 15);
    const int koff = (lane >> 4) * 8;
    const int rsub = (lane >> 4) * 4;

    for (int row0 = blockIdx.x * 16; row0 < nrows; row0 += gridDim.x * 16) {
        {
            int r = threadIdx.x >> 4;
            int c8 = (threadIdx.x & 15) * 8;
            float4 v0 = make_float4(0.f, 0.f, 0.f, 0.f), v1 = v0;
            if (row0 + r < nrows) {
                const float4* xp = (const float4*)(X + (size_t)(row0 + r) * HDIM + c8);
                v0 = xp[0]; v1 = xp[1];
            }
            unsigned short tmp[8];
            tmp[0] = f2bf(v0.x); tmp[1] = f2bf(v0.y); tmp[2] = f2bf(v0.z); tmp[3] = f2bf(v0.w);
            tmp[4] = f2bf(v1.x); tmp[5] = f2bf(v1.y); tmp[6] = f2bf(v1.z); tmp[7] = f2bf(v1.w);
            *(short8*)&At[r][c8] = *(short8*)tmp;
        }
        __syncthreads();

        f32x4 acc0 = {0.f, 0.f, 0.f, 0.f};
        f32x4 acc1 = {0.f, 0.f, 0.f, 0.f};
#pragma unroll
        for (int kb = 0; kb < 4; ++kb) {
            short8 a  = *(const short8*)&At[lane & 15][kb * 32 + koff];
            short8 b0 = *(const short8*)&WtL[col0][kb * 32 + koff];
            short8 b1 = *(const short8*)&WtL[col0 + 16][kb * 32 + koff];
            acc0 = __builtin_amdgcn_mfma_f32_16x16x32_bf16(a, b0, acc0, 0, 0, 0);
            acc1 = __builtin_amdgcn_mfma_f32_16x16x32_bf16(a, b1, acc1, 0, 0, 0);
        }
#pragma unroll
        for (int r = 0; r < 4; ++r) {
            int row = row0 + rsub + r;
            if (row < nrows) {
                Y16[(size_t)row * HDIM + col0]      = (unsigned short)f2bf(acc0[r]);
                Y16[(size_t)row * HDIM + col0 + 16] = (unsigned short)f2bf(acc1[r]);
            }
        }
        __syncthreads();
    }
}

// ---------------------------------------------------------------------------
// Fused CSR gather + finalize; XW rows bf16 (256B/row), 8-edge unroll,
// 4 accumulator chains. Plain loads (nt loads caused replay divergence, r13).
// csr entry: (src:16 | norm fp16:16), 4B/edge.
// OUT(f32) = elu(sum_e XW[src_e]*norm_e + XW[node]*dinv^2 + b) [+ RES]
// ---------------------------------------------------------------------------
__device__ __forceinline__ float eluf(float v) { return v > 0.f ? v : expf(v) - 1.f; }

__device__ __forceinline__ void gat_edge(const unsigned int c,
                                         const unsigned int* __restrict__ XWb,
                                         int lane, float2* acc) {
    int sidx = (int)(c & 0xffffu);
    float nm = __half2float(__ushort_as_half((unsigned short)(c >> 16)));
    unsigned int u = (XWb + (size_t)sidx * 64)[lane];
    acc->x += bf_lo(u) * nm;
    acc->y += bf_hi(u) * nm;
}

__global__ __launch_bounds__(256) void gather_k(const int* __restrict__ rowptr,
                                                const unsigned int* __restrict__ csr,
                                                const unsigned int* __restrict__ XWb,
                                                const float* __restrict__ dinv,
                                                const float* __restrict__ bias,
                                                const float* RES, float* __restrict__ OUT,
                                                int n) {
    int wid = threadIdx.x >> 6;
    int lane = threadIdx.x & 63;
    int node = blockIdx.x * 4 + wid;
    if (node >= n) return;
    int s = rowptr[node];
    const int end = rowptr[node + 1];

    float2 a0 = make_float2(0.f, 0.f), a1 = a0, a2 = a0, a3 = a0;

    for (; s + 7 < end; s += 8) {
        unsigned int c0 = csr[s];
        unsigned int c1 = csr[s + 1];
        unsigned int c2 = csr[s + 2];
        unsigned int c3 = csr[s + 3];
        unsigned int c4 = csr[s + 4];
        unsigned int c5 = csr[s + 5];
        unsigned int c6 = csr[s + 6];
        unsigned int c7 = csr[s + 7];
        gat_edge(c0, XWb, lane, &a0);
        gat_edge(c1, XWb, lane, &a1);
        gat_edge(c2, XWb, lane, &a2);
        gat_edge(c3, XWb, lane, &a3);
        gat_edge(c4, XWb, lane, &a0);
        gat_edge(c5, XWb, lane, &a1);
        gat_edge(c6, XWb, lane, &a2);
        gat_edge(c7, XWb, lane, &a3);
    }
    for (; s + 1 < end; s += 2) {
        unsigned int c0 = csr[s];
        unsigned int c1 = csr[s + 1];
        gat_edge(c0, XWb, lane, &a0);
        gat_edge(c1, XWb, lane, &a1);
    }
    if (s < end) {
        gat_edge(csr[s], XWb, lane, &a0);
    }

    float di = dinv[node];
    di = di * di;
    unsigned int us = (XWb + (size_t)node * 64)[lane];
    float2 bv = ((const float2*)bias)[lane];
    float2 o;
    o.x = eluf(a0.x + a1.x + a2.x + a3.x + bf_lo(us) * di + bv.x);
    o.y = eluf(a0.y + a1.y + a2.y + a3.y + bf_hi(us) * di + bv.y);
    if (RES) {
        float2 rv = ((const float2*)(RES + (size_t)node * HDIM))[lane];
        o.x += rv.x; o.y += rv.y;
    }
    ((float2*)(OUT + (size_t)node * HDIM))[lane] = o;
}

// ---------------------------------------------------------------------------
// Layer-3 gather fused with head: out[n]=sigmoid(dot(h3[n],Wl)+bl).
// h3 never hits memory.
// ---------------------------------------------------------------------------
__global__ __launch_bounds__(256) void gather_head_k(const int* __restrict__ rowptr,
                                                     const unsigned int* __restrict__ csr,
                                                     const unsigned int* __restrict__ XWb,
                                                     const float* __restrict__ dinv,
                                                     const float* __restrict__ bias,
                                                     const float* __restrict__ RES,
                                                     const float* __restrict__ Wl,
                                                     const float* __restrict__ bl,
                                                     float* __restrict__ out, int n) {
    int wid = threadIdx.x >> 6;
    int lane = threadIdx.x & 63;
    int node = blockIdx.x * 4 + wid;
    if (node >= n) return;
    int s = rowptr[node];
    const int end = rowptr[node + 1];

    float2 a0 = make_float2(0.f, 0.f), a1 = a0, a2 = a0, a3 = a0;

    for (; s + 7 < end; s += 8) {
        unsigned int c0 = csr[s];
        unsigned int c1 = csr[s + 1];
        unsigned int c2 = csr[s + 2];
        unsigned int c3 = csr[s + 3];
        unsigned int c4 = csr[s + 4];
        unsigned int c5 = csr[s + 5];
        unsigned int c6 = csr[s + 6];
        unsigned int c7 = csr[s + 7];
        gat_edge(c0, XWb, lane, &a0);
        gat_edge(c1, XWb, lane, &a1);
        gat_edge(c2, XWb, lane, &a2);
        gat_edge(c3, XWb, lane, &a3);
        gat_edge(c4, XWb, lane, &a0);
        gat_edge(c5, XWb, lane, &a1);
        gat_edge(c6, XWb, lane, &a2);
        gat_edge(c7, XWb, lane, &a3);
    }
    for (; s + 1 < end; s += 2) {
        unsigned int c0 = csr[s];
        unsigned int c1 = csr[s + 1];
        gat_edge(c0, XWb, lane, &a0);
        gat_edge(c1, XWb, lane, &a1);
    }
    if (s < end) {
        gat_edge(csr[s], XWb, lane, &a0);
    }

    float di = dinv[node];
    di = di * di;
    unsigned int us = (XWb + (size_t)node * 64)[lane];
    float2 bv = ((const float2*)bias)[lane];
    float2 rv = ((const float2*)(RES + (size_t)node * HDIM))[lane];
    float2 o;
    o.x = eluf(a0.x + a1.x + a2.x + a3.x + bf_lo(us) * di + bv.x) + rv.x;
    o.y = eluf(a0.y + a1.y + a2.y + a3.y + bf_hi(us) * di + bv.y) + rv.y;

    float2 wv = ((const float2*)Wl)[lane];
    float acc = o.x * wv.x + o.y * wv.y;
#pragma unroll
    for (int off = 32; off > 0; off >>= 1) acc += __shfl_down(acc, off);
    if (lane == 0) out[node] = 1.f / (1.f + expf(-(acc + bl[0])));
}

// ---------------------------------------------------------------------------
extern "C" void kernel_launch(void* const* d_in, const int* in_sizes, int n_in,
                              void* d_out, int out_size, void* d_ws, size_t ws_size,
                              hipStream_t stream) {
    const float* x  = (const float*)d_in[0];
    const int*   ei = (const int*)d_in[1];
    const float* ew = (const float*)d_in[2];
    const float* W1 = (const float*)d_in[3];
    const float* b1 = (const float*)d_in[4];
    const float* W2 = (const float*)d_in[5];
    const float* b2 = (const float*)d_in[6];
    const float* W3 = (const float*)d_in[7];
    const float* b3 = (const float*)d_in[8];
    const float* Wl = (const float*)d_in[9];
    const float* bl = (const float*)d_in[10];
    float* out = (float*)d_out;

    char* ws = (char*)d_ws;
    const size_t NHB = (size_t)N_NODES * HDIM * sizeof(float);  // 25.6 MB
    unsigned int* A = (unsigned int*)(ws);            // XW in bf16 (12.8 MB used)
    float* B    = (float*)(ws + NHB);                 // h1
    float* C    = (float*)(ws + 2 * NHB);             // h2
    char*  p    = ws + 3 * NHB;
    unsigned long long* pcnt = (unsigned long long*)p; p += sizeof(unsigned long long) * N_NODES;
    float* dinv    = (float*)p;            p += sizeof(float) * N_NODES;
    int*   src32   = (int*)p;              p += sizeof(int) * N_EDGES;
    int*   dst32   = (int*)p;              p += sizeof(int) * N_EDGES;
    int*   incl    = (int*)p;              p += sizeof(int) * N_NODES;
    int*   rowptr  = (int*)p;              p += sizeof(int) * (N_NODES + 2);
    int*   cursor  = (int*)p;              p += sizeof(int) * N_NODES;
    unsigned int* csr = (unsigned int*)p;  p += sizeof(unsigned int) * N_EDGES;
    unsigned short* Wt1 = (unsigned short*)p; p += sizeof(unsigned short) * HDIM * HDIM;
    unsigned short* Wt2 = (unsigned short*)p; p += sizeof(unsigned short) * HDIM * HDIM;
    unsigned short* Wt3 = (unsigned short*)p; p += sizeof(unsigned short) * HDIM * HDIM;
    int*   bsum    = (int*)p;              p += sizeof(int) * 128;

    const int TB = 256;
    const int egrid = (N_EDGES + TB - 1) / TB;
    const int ggrid = (N_NODES + 3) / 4;

    // --- graph preprocessing (identical every call) ---
    hipMemsetAsync(pcnt, 0, N_NODES * sizeof(unsigned long long), stream);
    edges_k<<<egrid, TB, 0, stream>>>(ei, ew, src32, dst32, pcnt, N_EDGES);
    wtrans3_k<<<192, TB, 0, stream>>>(W1, W2, W3, Wt1, Wt2, Wt3);
    scan1_k<<<SCAN_NB, SCAN_B, 0, stream>>>(pcnt, incl, bsum, dinv, N_NODES);
    scan3_k<<<SCAN_NB, SCAN_B, 0, stream>>>(pcnt, incl, bsum, rowptr, cursor, N_NODES, SCAN_NB);
    reorder_k<<<egrid, TB, 0, stream>>>(src32, dst32, ew, dinv, cursor, csr, N_EDGES);

    // --- layer 1: h1 = elu(gcn(x, W1, b1)) -> B ---
    mfma_gemm_k<<<1024, TB, 0, stream>>>(x, Wt1, (unsigned short*)A, N_NODES);
    gather_k<<<ggrid, TB, 0, stream>>>(rowptr, csr, A, dinv, b1, nullptr, B, N_NODES);

    // --- layer 2: h2 = elu(gcn(h1, W2, b2)) + h1 -> C ---
    mfma_gemm_k<<<1024, TB, 0, stream>>>(B, Wt2, (unsigned short*)A, N_NODES);
    gather_k<<<ggrid, TB, 0, stream>>>(rowptr, csr, A, dinv, b2, B, C, N_NODES);

    // --- layer 3 + head fused: out = sigmoid((elu(gcn(h2,W3,b3))+h2) @ Wl + bl) ---
    mfma_gemm_k<<<1024, TB, 0, stream>>>(C, Wt3, (unsigned short*)A, N_NODES);
    gather_head_k<<<ggrid, TB, 0, stream>>>(rowptr, csr, A, dinv, b3, C, Wl, bl, out, N_NODES);
}

// Round 16
// 212.900 us; speedup vs baseline: 20.1111x; 1.1166x over previous
//
#include <hip/hip_runtime.h>
#include <hip/hip_fp16.h>
#include <math.h>

#define N_NODES 50000
#define N_EDGES 800000
#define HDIM 128
#define SCAN_B 512
#define SCAN_NB ((N_NODES + SCAN_B - 1) / SCAN_B)   // 98

typedef __attribute__((ext_vector_type(8))) short short8;
typedef __attribute__((ext_vector_type(4))) float f32x4;

// bf16 helpers (manual RNE; bf16->f32 is a 16-bit shift)
__device__ __forceinline__ unsigned int f2bf(float f) {
    unsigned int u = __float_as_uint(f);
    return (u + 0x7fffu + ((u >> 16) & 1u)) >> 16;
}
__device__ __forceinline__ float bf_lo(unsigned int u) { return __uint_as_float(u << 16); }
__device__ __forceinline__ float bf_hi(unsigned int u) { return __uint_as_float(u & 0xffff0000u); }

// ---------------------------------------------------------------------------
// Fused convert + packed degree/count + RANK CAPTURE.
// The 64-bit atomicAdd's returned old value's high word = this edge's rank
// within its dst group -> drank[e] = d:16 | rank:16 (replaces dst32; no
// cursor atomics needed later). Per-block int64/int32 layout self-detection.
// pcnt: high 32 = count, low 32 = sum(ew * 2^24) fixed-point.
// ---------------------------------------------------------------------------
__global__ __launch_bounds__(256) void edges_k(const int* __restrict__ ei,
                                               const float* __restrict__ ew,
                                               int* __restrict__ src32,
                                               unsigned int* __restrict__ drank,
                                               unsigned long long* __restrict__ pcnt, int ne) {
    __shared__ int nz;
    if (threadIdx.x == 0) nz = 0;
    __syncthreads();
    int e = blockIdx.x * 256 + threadIdx.x;
    int odd = (e < ne) ? ei[2 * e + 1] : 0;
    if (odd) atomicOr(&nz, 1);
    __syncthreads();
    if (e >= ne) return;
    int s, d;
    if (nz == 0) {  // int64 layout: low words at even offsets
        s = ei[2 * e];
        d = ei[2 * (ne + e)];
    } else {        // int32 layout
        s = ei[e];
        d = ei[ne + e];
    }
    src32[e] = s;
    unsigned int q = __float2uint_rn(ew[e] * 16777216.0f);
    unsigned long long old = atomicAdd(&pcnt[d], (1ULL << 32) | (unsigned long long)q);
    unsigned int rank = (unsigned int)(old >> 32);
    drank[e] = (unsigned int)d | (rank << 16);
}

// ---------------------------------------------------------------------------
// Hierarchical exclusive scan of counts (high word of pcnt) -> rowptr.
// scan1 also emits dinv (fused unpack). scan3 re-derives block offsets from
// bsum locally (no scan2, no cursor).
// ---------------------------------------------------------------------------
__global__ __launch_bounds__(SCAN_B) void scan1_k(const unsigned long long* __restrict__ pcnt,
                                                  int* __restrict__ incl,
                                                  int* __restrict__ bsum,
                                                  float* __restrict__ dinv, int n) {
    __shared__ int buf[SCAN_B];
    int i = blockIdx.x * SCAN_B + threadIdx.x;
    unsigned long long v64 = (i < n) ? pcnt[i] : 0ULL;
    int v = (int)(v64 >> 32);
    buf[threadIdx.x] = v;
    __syncthreads();
#pragma unroll
    for (int off = 1; off < SCAN_B; off <<= 1) {
        int t = (threadIdx.x >= off) ? buf[threadIdx.x - off] : 0;
        __syncthreads();
        buf[threadIdx.x] += t;
        __syncthreads();
    }
    if (i < n) {
        incl[i] = buf[threadIdx.x];
        float deg = (float)(unsigned int)(v64 & 0xffffffffULL) * (1.0f / 16777216.0f);
        dinv[i] = rsqrtf(deg + 1.0f);
    }
    if (threadIdx.x == SCAN_B - 1) bsum[blockIdx.x] = buf[threadIdx.x];
}

__global__ __launch_bounds__(SCAN_B) void scan3_k(const unsigned long long* __restrict__ pcnt,
                                                  const int* __restrict__ incl,
                                                  const int* __restrict__ bsum,
                                                  int* __restrict__ rowptr, int n, int nb) {
    __shared__ int bs[128];
    if (threadIdx.x < 128) bs[threadIdx.x] = (threadIdx.x < nb) ? bsum[threadIdx.x] : 0;
    __syncthreads();
#pragma unroll
    for (int off = 1; off < 128; off <<= 1) {
        int t = 0;
        if (threadIdx.x < 128 && threadIdx.x >= off) t = bs[threadIdx.x - off];
        __syncthreads();
        if (threadIdx.x < 128) bs[threadIdx.x] += t;
        __syncthreads();
    }
    int i = blockIdx.x * SCAN_B + threadIdx.x;
    if (i < n) {
        int boff = (blockIdx.x == 0) ? 0 : bs[blockIdx.x - 1];
        int c = (int)(pcnt[i] >> 32);
        rowptr[i] = boff + incl[i] - c;
    }
    if (blockIdx.x == 0 && threadIdx.x == 0) rowptr[n] = bs[nb - 1];
}

// ---------------------------------------------------------------------------
// Reorder, ATOMIC-FREE: slot = rowptr[d] + rank (rank captured in edges_k).
// csr entry: (src:16 | norm fp16:16), one 4B scattered store/edge.
// ---------------------------------------------------------------------------
__global__ void reorder_k(const int* __restrict__ src,
                          const unsigned int* __restrict__ drank,
                          const float* __restrict__ ew, const float* __restrict__ dinv,
                          const int* __restrict__ rowptr,
                          unsigned int* __restrict__ csr, int ne) {
    int e = blockIdx.x * blockDim.x + threadIdx.x;
    if (e >= ne) return;
    int s = src[e];
    unsigned int dr = drank[e];
    int d = (int)(dr & 0xffffu);
    int rank = (int)(dr >> 16);
    int slot = rowptr[d] + rank;
    float nm = dinv[s] * ew[e] * dinv[d];
    unsigned int h = (unsigned int)__half_as_ushort(__float2half(nm));
    csr[slot] = (unsigned int)s | (h << 16);
}

// ---------------------------------------------------------------------------
// All three W (f32 [k][c]) -> Wt (bf16 [c][k]). 192 blocks, 1 elem/thread.
// ---------------------------------------------------------------------------
__global__ __launch_bounds__(256) void wtrans3_k(const float* __restrict__ W1,
                                                 const float* __restrict__ W2,
                                                 const float* __restrict__ W3,
                                                 unsigned short* __restrict__ Wt1,
                                                 unsigned short* __restrict__ Wt2,
                                                 unsigned short* __restrict__ Wt3) {
    int which = blockIdx.x >> 6;          // 64 blocks per weight
    const float* W = (which == 0) ? W1 : (which == 1) ? W2 : W3;
    unsigned short* Wt = (which == 0) ? Wt1 : (which == 1) ? Wt2 : Wt3;
    int idx = (blockIdx.x & 63) * 256 + threadIdx.x;   // 0..16383
    int c = idx >> 7, k = idx & 127;
    Wt[idx] = (unsigned short)f2bf(W[k * HDIM + c]);
}

// ---------------------------------------------------------------------------
// MFMA GEMM: Yb(bf16) = X(f32) @ W via Wt(bf16, transposed).
// Block: 256 thr = 4 waves; tile 16 rows x 128 cols; wave w -> cols 32w..32w+31.
// v_mfma_f32_16x16x32_bf16: A/B frag lane l elem i -> [l&15][(l>>4)*8+i];
// D: col=l&15, row=(l>>4)*4+reg  [m89-verified layout].
// ---------------------------------------------------------------------------
__global__ __launch_bounds__(256) void mfma_gemm_k(const float* __restrict__ X,
                                                   const unsigned short* __restrict__ Wt,
                                                   unsigned short* __restrict__ Y16,
                                                   int nrows) {
    __shared__ unsigned short WtL[HDIM][136];  // 34.8 KB (+8 pad: 2-way banks only)
    __shared__ unsigned short At[16][136];     // 4.4 KB

    for (int idx = threadIdx.x; idx < HDIM * 16; idx += 256) {
        int row = idx >> 4, q = idx & 15;
        *(uint4*)&WtL[row][q * 8] = *(const uint4*)&Wt[row * HDIM + q * 8];
    }
    __syncthreads();

    const int lane = threadIdx.x & 63;
    const int wave = threadIdx.x >> 6;
    const int col0 = wave * 32 + (lane & 15);
    const int koff = (lane >> 4) * 8;
    const int rsub = (lane >> 4) * 4;

    for (int row0 = blockIdx.x * 16; row0 < nrows; row0 += gridDim.x * 16) {
        {
            int r = threadIdx.x >> 4;
            int c8 = (threadIdx.x & 15) * 8;
            float4 v0 = make_float4(0.f, 0.f, 0.f, 0.f), v1 = v0;
            if (row0 + r < nrows) {
                const float4* xp = (const float4*)(X + (size_t)(row0 + r) * HDIM + c8);
                v0 = xp[0]; v1 = xp[1];
            }
            unsigned short tmp[8];
            tmp[0] = f2bf(v0.x); tmp[1] = f2bf(v0.y); tmp[2] = f2bf(v0.z); tmp[3] = f2bf(v0.w);
            tmp[4] = f2bf(v1.x); tmp[5] = f2bf(v1.y); tmp[6] = f2bf(v1.z); tmp[7] = f2bf(v1.w);
            *(short8*)&At[r][c8] = *(short8*)tmp;
        }
        __syncthreads();

        f32x4 acc0 = {0.f, 0.f, 0.f, 0.f};
        f32x4 acc1 = {0.f, 0.f, 0.f, 0.f};
#pragma unroll
        for (int kb = 0; kb < 4; ++kb) {
            short8 a  = *(const short8*)&At[lane & 15][kb * 32 + koff];
            short8 b0 = *(const short8*)&WtL[col0][kb * 32 + koff];
            short8 b1 = *(const short8*)&WtL[col0 + 16][kb * 32 + koff];
            acc0 = __builtin_amdgcn_mfma_f32_16x16x32_bf16(a, b0, acc0, 0, 0, 0);
            acc1 = __builtin_amdgcn_mfma_f32_16x16x32_bf16(a, b1, acc1, 0, 0, 0);
        }
#pragma unroll
        for (int r = 0; r < 4; ++r) {
            int row = row0 + rsub + r;
            if (row < nrows) {
                Y16[(size_t)row * HDIM + col0]      = (unsigned short)f2bf(acc0[r]);
                Y16[(size_t)row * HDIM + col0 + 16] = (unsigned short)f2bf(acc1[r]);
            }
        }
        __syncthreads();
    }
}

// ---------------------------------------------------------------------------
// Fused CSR gather + finalize; XW rows bf16 (256B/row), 8-edge unroll,
// 4 accumulator chains. Plain loads (nt loads caused replay divergence, r13).
// csr entry: (src:16 | norm fp16:16), 4B/edge.
// OUT(f32) = elu(sum_e XW[src_e]*norm_e + XW[node]*dinv^2 + b) [+ RES]
// ---------------------------------------------------------------------------
__device__ __forceinline__ float eluf(float v) { return v > 0.f ? v : expf(v) - 1.f; }

__device__ __forceinline__ void gat_edge(const unsigned int c,
                                         const unsigned int* __restrict__ XWb,
                                         int lane, float2* acc) {
    int sidx = (int)(c & 0xffffu);
    float nm = __half2float(__ushort_as_half((unsigned short)(c >> 16)));
    unsigned int u = (XWb + (size_t)sidx * 64)[lane];
    acc->x += bf_lo(u) * nm;
    acc->y += bf_hi(u) * nm;
}

__global__ __launch_bounds__(256) void gather_k(const int* __restrict__ rowptr,
                                                const unsigned int* __restrict__ csr,
                                                const unsigned int* __restrict__ XWb,
                                                const float* __restrict__ dinv,
                                                const float* __restrict__ bias,
                                                const float* RES, float* __restrict__ OUT,
                                                int n) {
    int wid = threadIdx.x >> 6;
    int lane = threadIdx.x & 63;
    int node = blockIdx.x * 4 + wid;
    if (node >= n) return;
    int s = rowptr[node];
    const int end = rowptr[node + 1];

    float2 a0 = make_float2(0.f, 0.f), a1 = a0, a2 = a0, a3 = a0;

    for (; s + 7 < end; s += 8) {
        unsigned int c0 = csr[s];
        unsigned int c1 = csr[s + 1];
        unsigned int c2 = csr[s + 2];
        unsigned int c3 = csr[s + 3];
        unsigned int c4 = csr[s + 4];
        unsigned int c5 = csr[s + 5];
        unsigned int c6 = csr[s + 6];
        unsigned int c7 = csr[s + 7];
        gat_edge(c0, XWb, lane, &a0);
        gat_edge(c1, XWb, lane, &a1);
        gat_edge(c2, XWb, lane, &a2);
        gat_edge(c3, XWb, lane, &a3);
        gat_edge(c4, XWb, lane, &a0);
        gat_edge(c5, XWb, lane, &a1);
        gat_edge(c6, XWb, lane, &a2);
        gat_edge(c7, XWb, lane, &a3);
    }
    for (; s + 1 < end; s += 2) {
        unsigned int c0 = csr[s];
        unsigned int c1 = csr[s + 1];
        gat_edge(c0, XWb, lane, &a0);
        gat_edge(c1, XWb, lane, &a1);
    }
    if (s < end) {
        gat_edge(csr[s], XWb, lane, &a0);
    }

    float di = dinv[node];
    di = di * di;
    unsigned int us = (XWb + (size_t)node * 64)[lane];
    float2 bv = ((const float2*)bias)[lane];
    float2 o;
    o.x = eluf(a0.x + a1.x + a2.x + a3.x + bf_lo(us) * di + bv.x);
    o.y = eluf(a0.y + a1.y + a2.y + a3.y + bf_hi(us) * di + bv.y);
    if (RES) {
        float2 rv = ((const float2*)(RES + (size_t)node * HDIM))[lane];
        o.x += rv.x; o.y += rv.y;
    }
    ((float2*)(OUT + (size_t)node * HDIM))[lane] = o;
}

// ---------------------------------------------------------------------------
// Layer-3 gather fused with head: out[n]=sigmoid(dot(h3[n],Wl)+bl).
// h3 never hits memory.
// ---------------------------------------------------------------------------
__global__ __launch_bounds__(256) void gather_head_k(const int* __restrict__ rowptr,
                                                     const unsigned int* __restrict__ csr,
                                                     const unsigned int* __restrict__ XWb,
                                                     const float* __restrict__ dinv,
                                                     const float* __restrict__ bias,
                                                     const float* __restrict__ RES,
                                                     const float* __restrict__ Wl,
                                                     const float* __restrict__ bl,
                                                     float* __restrict__ out, int n) {
    int wid = threadIdx.x >> 6;
    int lane = threadIdx.x & 63;
    int node = blockIdx.x * 4 + wid;
    if (node >= n) return;
    int s = rowptr[node];
    const int end = rowptr[node + 1];

    float2 a0 = make_float2(0.f, 0.f), a1 = a0, a2 = a0, a3 = a0;

    for (; s + 7 < end; s += 8) {
        unsigned int c0 = csr[s];
        unsigned int c1 = csr[s + 1];
        unsigned int c2 = csr[s + 2];
        unsigned int c3 = csr[s + 3];
        unsigned int c4 = csr[s + 4];
        unsigned int c5 = csr[s + 5];
        unsigned int c6 = csr[s + 6];
        unsigned int c7 = csr[s + 7];
        gat_edge(c0, XWb, lane, &a0);
        gat_edge(c1, XWb, lane, &a1);
        gat_edge(c2, XWb, lane, &a2);
        gat_edge(c3, XWb, lane, &a3);
        gat_edge(c4, XWb, lane, &a0);
        gat_edge(c5, XWb, lane, &a1);
        gat_edge(c6, XWb, lane, &a2);
        gat_edge(c7, XWb, lane, &a3);
    }
    for (; s + 1 < end; s += 2) {
        unsigned int c0 = csr[s];
        unsigned int c1 = csr[s + 1];
        gat_edge(c0, XWb, lane, &a0);
        gat_edge(c1, XWb, lane, &a1);
    }
    if (s < end) {
        gat_edge(csr[s], XWb, lane, &a0);
    }

    float di = dinv[node];
    di = di * di;
    unsigned int us = (XWb + (size_t)node * 64)[lane];
    float2 bv = ((const float2*)bias)[lane];
    float2 rv = ((const float2*)(RES + (size_t)node * HDIM))[lane];
    float2 o;
    o.x = eluf(a0.x + a1.x + a2.x + a3.x + bf_lo(us) * di + bv.x) + rv.x;
    o.y = eluf(a0.y + a1.y + a2.y + a3.y + bf_hi(us) * di + bv.y) + rv.y;

    float2 wv = ((const float2*)Wl)[lane];
    float acc = o.x * wv.x + o.y * wv.y;
#pragma unroll
    for (int off = 32; off > 0; off >>= 1) acc += __shfl_down(acc, off);
    if (lane == 0) out[node] = 1.f / (1.f + expf(-(acc + bl[0])));
}

// ---------------------------------------------------------------------------
extern "C" void kernel_launch(void* const* d_in, const int* in_sizes, int n_in,
                              void* d_out, int out_size, void* d_ws, size_t ws_size,
                              hipStream_t stream) {
    const float* x  = (const float*)d_in[0];
    const int*   ei = (const int*)d_in[1];
    const float* ew = (const float*)d_in[2];
    const float* W1 = (const float*)d_in[3];
    const float* b1 = (const float*)d_in[4];
    const float* W2 = (const float*)d_in[5];
    const float* b2 = (const float*)d_in[6];
    const float* W3 = (const float*)d_in[7];
    const float* b3 = (const float*)d_in[8];
    const float* Wl = (const float*)d_in[9];
    const float* bl = (const float*)d_in[10];
    float* out = (float*)d_out;

    char* ws = (char*)d_ws;
    const size_t NHB = (size_t)N_NODES * HDIM * sizeof(float);  // 25.6 MB
    unsigned int* A = (unsigned int*)(ws);            // XW in bf16 (12.8 MB used)
    float* B    = (float*)(ws + NHB);                 // h1
    float* C    = (float*)(ws + 2 * NHB);             // h2
    char*  p    = ws + 3 * NHB;
    unsigned long long* pcnt = (unsigned long long*)p; p += sizeof(unsigned long long) * N_NODES;
    float* dinv    = (float*)p;            p += sizeof(float) * N_NODES;
    int*   src32   = (int*)p;              p += sizeof(int) * N_EDGES;
    unsigned int* drank = (unsigned int*)p; p += sizeof(unsigned int) * N_EDGES;
    int*   incl    = (int*)p;              p += sizeof(int) * N_NODES;
    int*   rowptr  = (int*)p;              p += sizeof(int) * (N_NODES + 2);
    unsigned int* csr = (unsigned int*)p;  p += sizeof(unsigned int) * N_EDGES;
    unsigned short* Wt1 = (unsigned short*)p; p += sizeof(unsigned short) * HDIM * HDIM;
    unsigned short* Wt2 = (unsigned short*)p; p += sizeof(unsigned short) * HDIM * HDIM;
    unsigned short* Wt3 = (unsigned short*)p; p += sizeof(unsigned short) * HDIM * HDIM;
    int*   bsum    = (int*)p;              p += sizeof(int) * 128;

    const int TB = 256;
    const int egrid = (N_EDGES + TB - 1) / TB;
    const int ggrid = (N_NODES + 3) / 4;

    // --- graph preprocessing (identical every call) ---
    hipMemsetAsync(pcnt, 0, N_NODES * sizeof(unsigned long long), stream);
    edges_k<<<egrid, TB, 0, stream>>>(ei, ew, src32, drank, pcnt, N_EDGES);
    wtrans3_k<<<192, TB, 0, stream>>>(W1, W2, W3, Wt1, Wt2, Wt3);
    scan1_k<<<SCAN_NB, SCAN_B, 0, stream>>>(pcnt, incl, bsum, dinv, N_NODES);
    scan3_k<<<SCAN_NB, SCAN_B, 0, stream>>>(pcnt, incl, bsum, rowptr, N_NODES, SCAN_NB);
    reorder_k<<<egrid, TB, 0, stream>>>(src32, drank, ew, dinv, rowptr, csr, N_EDGES);

    // --- layer 1: h1 = elu(gcn(x, W1, b1)) -> B ---
    mfma_gemm_k<<<1024, TB, 0, stream>>>(x, Wt1, (unsigned short*)A, N_NODES);
    gather_k<<<ggrid, TB, 0, stream>>>(rowptr, csr, A, dinv, b1, nullptr, B, N_NODES);

    // --- layer 2: h2 = elu(gcn(h1, W2, b2)) + h1 -> C ---
    mfma_gemm_k<<<1024, TB, 0, stream>>>(B, Wt2, (unsigned short*)A, N_NODES);
    gather_k<<<ggrid, TB, 0, stream>>>(rowptr, csr, A, dinv, b2, B, C, N_NODES);

    // --- layer 3 + head fused: out = sigmoid((elu(gcn(h2,W3,b3))+h2) @ Wl + bl) ---
    mfma_gemm_k<<<1024, TB, 0, stream>>>(C, Wt3, (unsigned short*)A, N_NODES);
    gather_head_k<<<ggrid, TB, 0, stream>>>(rowptr, csr, A, dinv, b3, C, Wl, bl, out, N_NODES);
}

// Round 18
// 202.924 us; speedup vs baseline: 21.0997x; 1.0492x over previous
//
#include <hip/hip_runtime.h>
#include <hip/hip_fp16.h>
#include <math.h>

#define N_NODES 50000
#define N_EDGES 800000
#define HDIM 128
#define SCAN_B 512
#define SCAN_NB ((N_NODES + SCAN_B - 1) / SCAN_B)   // 98

typedef __attribute__((ext_vector_type(8))) short short8;
typedef __attribute__((ext_vector_type(4))) float f32x4;

// bf16 helpers (manual RNE; bf16->f32 is a 16-bit shift)
__device__ __forceinline__ unsigned int f2bf(float f) {
    unsigned int u = __float_as_uint(f);
    return (u + 0x7fffu + ((u >> 16) & 1u)) >> 16;
}
__device__ __forceinline__ float bf_lo(unsigned int u) { return __uint_as_float(u << 16); }
__device__ __forceinline__ float bf_hi(unsigned int u) { return __uint_as_float(u & 0xffff0000u); }

// ---------------------------------------------------------------------------
// Fused convert + packed degree/count + RANK CAPTURE (see r16).
// pcnt: high 32 = count, low 32 = sum(ew * 2^24) fixed-point.
// ---------------------------------------------------------------------------
__global__ __launch_bounds__(256) void edges_k(const int* __restrict__ ei,
                                               const float* __restrict__ ew,
                                               int* __restrict__ src32,
                                               unsigned int* __restrict__ drank,
                                               unsigned long long* __restrict__ pcnt, int ne) {
    __shared__ int nz;
    if (threadIdx.x == 0) nz = 0;
    __syncthreads();
    int e = blockIdx.x * 256 + threadIdx.x;
    int odd = (e < ne) ? ei[2 * e + 1] : 0;
    if (odd) atomicOr(&nz, 1);
    __syncthreads();
    if (e >= ne) return;
    int s, d;
    if (nz == 0) {  // int64 layout: low words at even offsets
        s = ei[2 * e];
        d = ei[2 * (ne + e)];
    } else {        // int32 layout
        s = ei[e];
        d = ei[ne + e];
    }
    src32[e] = s;
    unsigned int q = __float2uint_rn(ew[e] * 16777216.0f);
    unsigned long long old = atomicAdd(&pcnt[d], (1ULL << 32) | (unsigned long long)q);
    unsigned int rank = (unsigned int)(old >> 32);
    drank[e] = (unsigned int)d | (rank << 16);
}

// ---------------------------------------------------------------------------
// Hierarchical exclusive scan (see r16). scan1 fuses dinv emit.
// ---------------------------------------------------------------------------
__global__ __launch_bounds__(SCAN_B) void scan1_k(const unsigned long long* __restrict__ pcnt,
                                                  int* __restrict__ incl,
                                                  int* __restrict__ bsum,
                                                  float* __restrict__ dinv, int n) {
    __shared__ int buf[SCAN_B];
    int i = blockIdx.x * SCAN_B + threadIdx.x;
    unsigned long long v64 = (i < n) ? pcnt[i] : 0ULL;
    int v = (int)(v64 >> 32);
    buf[threadIdx.x] = v;
    __syncthreads();
#pragma unroll
    for (int off = 1; off < SCAN_B; off <<= 1) {
        int t = (threadIdx.x >= off) ? buf[threadIdx.x - off] : 0;
        __syncthreads();
        buf[threadIdx.x] += t;
        __syncthreads();
    }
    if (i < n) {
        incl[i] = buf[threadIdx.x];
        float deg = (float)(unsigned int)(v64 & 0xffffffffULL) * (1.0f / 16777216.0f);
        dinv[i] = rsqrtf(deg + 1.0f);
    }
    if (threadIdx.x == SCAN_B - 1) bsum[blockIdx.x] = buf[threadIdx.x];
}

__global__ __launch_bounds__(SCAN_B) void scan3_k(const unsigned long long* __restrict__ pcnt,
                                                  const int* __restrict__ incl,
                                                  const int* __restrict__ bsum,
                                                  int* __restrict__ rowptr, int n, int nb) {
    __shared__ int bs[128];
    if (threadIdx.x < 128) bs[threadIdx.x] = (threadIdx.x < nb) ? bsum[threadIdx.x] : 0;
    __syncthreads();
#pragma unroll
    for (int off = 1; off < 128; off <<= 1) {
        int t = 0;
        if (threadIdx.x < 128 && threadIdx.x >= off) t = bs[threadIdx.x - off];
        __syncthreads();
        if (threadIdx.x < 128) bs[threadIdx.x] += t;
        __syncthreads();
    }
    int i = blockIdx.x * SCAN_B + threadIdx.x;
    if (i < n) {
        int boff = (blockIdx.x == 0) ? 0 : bs[blockIdx.x - 1];
        int c = (int)(pcnt[i] >> 32);
        rowptr[i] = boff + incl[i] - c;
    }
    if (blockIdx.x == 0 && threadIdx.x == 0) rowptr[n] = bs[nb - 1];
}

// ---------------------------------------------------------------------------
// Reorder, ATOMIC-FREE: slot = rowptr[d] + rank.
// csr entry: (src:16 | norm fp16:16), one 4B scattered store/edge.
// ---------------------------------------------------------------------------
__global__ void reorder_k(const int* __restrict__ src,
                          const unsigned int* __restrict__ drank,
                          const float* __restrict__ ew, const float* __restrict__ dinv,
                          const int* __restrict__ rowptr,
                          unsigned int* __restrict__ csr, int ne) {
    int e = blockIdx.x * blockDim.x + threadIdx.x;
    if (e >= ne) return;
    int s = src[e];
    unsigned int dr = drank[e];
    int d = (int)(dr & 0xffffu);
    int rank = (int)(dr >> 16);
    int slot = rowptr[d] + rank;
    float nm = dinv[s] * ew[e] * dinv[d];
    unsigned int h = (unsigned int)__half_as_ushort(__float2half(nm));
    csr[slot] = (unsigned int)s | (h << 16);
}

// ---------------------------------------------------------------------------
// All three W (f32 [k][c]) -> Wt (bf16 [c][k]). 192 blocks, 1 elem/thread.
// ---------------------------------------------------------------------------
__global__ __launch_bounds__(256) void wtrans3_k(const float* __restrict__ W1,
                                                 const float* __restrict__ W2,
                                                 const float* __restrict__ W3,
                                                 unsigned short* __restrict__ Wt1,
                                                 unsigned short* __restrict__ Wt2,
                                                 unsigned short* __restrict__ Wt3) {
    int which = blockIdx.x >> 6;          // 64 blocks per weight
    const float* W = (which == 0) ? W1 : (which == 1) ? W2 : W3;
    unsigned short* Wt = (which == 0) ? Wt1 : (which == 1) ? Wt2 : Wt3;
    int idx = (blockIdx.x & 63) * 256 + threadIdx.x;   // 0..16383
    int c = idx >> 7, k = idx & 127;
    Wt[idx] = (unsigned short)f2bf(W[k * HDIM + c]);
}

// ---------------------------------------------------------------------------
// MFMA GEMM (unchanged, m89-verified layout).
// ---------------------------------------------------------------------------
__global__ __launch_bounds__(256) void mfma_gemm_k(const float* __restrict__ X,
                                                   const unsigned short* __restrict__ Wt,
                                                   unsigned short* __restrict__ Y16,
                                                   int nrows) {
    __shared__ unsigned short WtL[HDIM][136];  // 34.8 KB (+8 pad: 2-way banks only)
    __shared__ unsigned short At[16][136];     // 4.4 KB

    for (int idx = threadIdx.x; idx < HDIM * 16; idx += 256) {
        int row = idx >> 4, q = idx & 15;
        *(uint4*)&WtL[row][q * 8] = *(const uint4*)&Wt[row * HDIM + q * 8];
    }
    __syncthreads();

    const int lane = threadIdx.x & 63;
    const int wave = threadIdx.x >> 6;
    const int col0 = wave * 32 + (lane & 15);
    const int koff = (lane >> 4) * 8;
    const int rsub = (lane >> 4) * 4;

    for (int row0 = blockIdx.x * 16; row0 < nrows; row0 += gridDim.x * 16) {
        {
            int r = threadIdx.x >> 4;
            int c8 = (threadIdx.x & 15) * 8;
            float4 v0 = make_float4(0.f, 0.f, 0.f, 0.f), v1 = v0;
            if (row0 + r < nrows) {
                const float4* xp = (const float4*)(X + (size_t)(row0 + r) * HDIM + c8);
                v0 = xp[0]; v1 = xp[1];
            }
            unsigned short tmp[8];
            tmp[0] = f2bf(v0.x); tmp[1] = f2bf(v0.y); tmp[2] = f2bf(v0.z); tmp[3] = f2bf(v0.w);
            tmp[4] = f2bf(v1.x); tmp[5] = f2bf(v1.y); tmp[6] = f2bf(v1.z); tmp[7] = f2bf(v1.w);
            *(short8*)&At[r][c8] = *(short8*)tmp;
        }
        __syncthreads();

        f32x4 acc0 = {0.f, 0.f, 0.f, 0.f};
        f32x4 acc1 = {0.f, 0.f, 0.f, 0.f};
#pragma unroll
        for (int kb = 0; kb < 4; ++kb) {
            short8 a  = *(const short8*)&At[lane & 15][kb * 32 + koff];
            short8 b0 = *(const short8*)&WtL[col0][kb * 32 + koff];
            short8 b1 = *(const short8*)&WtL[col0 + 16][kb * 32 + koff];
            acc0 = __builtin_amdgcn_mfma_f32_16x16x32_bf16(a, b0, acc0, 0, 0, 0);
            acc1 = __builtin_amdgcn_mfma_f32_16x16x32_bf16(a, b1, acc1, 0, 0, 0);
        }
#pragma unroll
        for (int r = 0; r < 4; ++r) {
            int row = row0 + rsub + r;
            if (row < nrows) {
                Y16[(size_t)row * HDIM + col0]      = (unsigned short)f2bf(acc0[r]);
                Y16[(size_t)row * HDIM + col0 + 16] = (unsigned short)f2bf(acc1[r]);
            }
        }
        __syncthreads();
    }
}

// ---------------------------------------------------------------------------
// Fused CSR gather + finalize, HALF-WAVE PER NODE (2 nodes/wave, 8/block):
// each 32-lane half reads its row as uint2 (32 x 8B = 256B) -> 2 independent
// edge streams per wave = 2x memory-level parallelism. 8-edge unroll,
// 4 acc chains (float4 each). Plain loads (nt caused replay divergence, r13).
// csr entry: (src:16 | norm fp16:16), 4B/edge.
// ---------------------------------------------------------------------------
__device__ __forceinline__ float eluf(float v) { return v > 0.f ? v : expf(v) - 1.f; }

__device__ __forceinline__ void gat_edge2(const unsigned int c,
                                          const uint2* __restrict__ XW2,
                                          int lane32, float4* acc) {
    int sidx = (int)(c & 0xffffu);
    float nm = __half2float(__ushort_as_half((unsigned short)(c >> 16)));
    uint2 u = XW2[(size_t)sidx * 32 + lane32];
    acc->x += bf_lo(u.x) * nm;
    acc->y += bf_hi(u.x) * nm;
    acc->z += bf_lo(u.y) * nm;
    acc->w += bf_hi(u.y) * nm;
}

__global__ __launch_bounds__(256) void gather_k(const int* __restrict__ rowptr,
                                                const unsigned int* __restrict__ csr,
                                                const uint2* __restrict__ XW2,
                                                const float* __restrict__ dinv,
                                                const float* __restrict__ bias,
                                                const float* RES, float* __restrict__ OUT,
                                                int n) {
    int half = threadIdx.x >> 5;       // 0..7
    int lane32 = threadIdx.x & 31;
    int node = blockIdx.x * 8 + half;
    if (node >= n) return;
    int s = rowptr[node];
    const int end = rowptr[node + 1];

    float4 a0 = make_float4(0.f, 0.f, 0.f, 0.f), a1 = a0, a2 = a0, a3 = a0;

    for (; s + 7 < end; s += 8) {
        unsigned int c0 = csr[s];
        unsigned int c1 = csr[s + 1];
        unsigned int c2 = csr[s + 2];
        unsigned int c3 = csr[s + 3];
        unsigned int c4 = csr[s + 4];
        unsigned int c5 = csr[s + 5];
        unsigned int c6 = csr[s + 6];
        unsigned int c7 = csr[s + 7];
        gat_edge2(c0, XW2, lane32, &a0);
        gat_edge2(c1, XW2, lane32, &a1);
        gat_edge2(c2, XW2, lane32, &a2);
        gat_edge2(c3, XW2, lane32, &a3);
        gat_edge2(c4, XW2, lane32, &a0);
        gat_edge2(c5, XW2, lane32, &a1);
        gat_edge2(c6, XW2, lane32, &a2);
        gat_edge2(c7, XW2, lane32, &a3);
    }
    for (; s + 1 < end; s += 2) {
        unsigned int c0 = csr[s];
        unsigned int c1 = csr[s + 1];
        gat_edge2(c0, XW2, lane32, &a0);
        gat_edge2(c1, XW2, lane32, &a1);
    }
    if (s < end) {
        gat_edge2(csr[s], XW2, lane32, &a0);
    }

    float di = dinv[node];
    di = di * di;
    uint2 us = XW2[(size_t)node * 32 + lane32];
    float4 bv = ((const float4*)bias)[lane32];
    float4 o;
    o.x = eluf(a0.x + a1.x + a2.x + a3.x + bf_lo(us.x) * di + bv.x);
    o.y = eluf(a0.y + a1.y + a2.y + a3.y + bf_hi(us.x) * di + bv.y);
    o.z = eluf(a0.z + a1.z + a2.z + a3.z + bf_lo(us.y) * di + bv.z);
    o.w = eluf(a0.w + a1.w + a2.w + a3.w + bf_hi(us.y) * di + bv.w);
    if (RES) {
        float4 rv = ((const float4*)(RES + (size_t)node * HDIM))[lane32];
        o.x += rv.x; o.y += rv.y; o.z += rv.z; o.w += rv.w;
    }
    ((float4*)(OUT + (size_t)node * HDIM))[lane32] = o;
}

// ---------------------------------------------------------------------------
// Layer-3 gather fused with head (half-wave per node; width-32 reduce).
// ---------------------------------------------------------------------------
__global__ __launch_bounds__(256) void gather_head_k(const int* __restrict__ rowptr,
                                                     const unsigned int* __restrict__ csr,
                                                     const uint2* __restrict__ XW2,
                                                     const float* __restrict__ dinv,
                                                     const float* __restrict__ bias,
                                                     const float* __restrict__ RES,
                                                     const float* __restrict__ Wl,
                                                     const float* __restrict__ bl,
                                                     float* __restrict__ out, int n) {
    int half = threadIdx.x >> 5;
    int lane32 = threadIdx.x & 31;
    int node = blockIdx.x * 8 + half;
    if (node >= n) return;
    int s = rowptr[node];
    const int end = rowptr[node + 1];

    float4 a0 = make_float4(0.f, 0.f, 0.f, 0.f), a1 = a0, a2 = a0, a3 = a0;

    for (; s + 7 < end; s += 8) {
        unsigned int c0 = csr[s];
        unsigned int c1 = csr[s + 1];
        unsigned int c2 = csr[s + 2];
        unsigned int c3 = csr[s + 3];
        unsigned int c4 = csr[s + 4];
        unsigned int c5 = csr[s + 5];
        unsigned int c6 = csr[s + 6];
        unsigned int c7 = csr[s + 7];
        gat_edge2(c0, XW2, lane32, &a0);
        gat_edge2(c1, XW2, lane32, &a1);
        gat_edge2(c2, XW2, lane32, &a2);
        gat_edge2(c3, XW2, lane32, &a3);
        gat_edge2(c4, XW2, lane32, &a0);
        gat_edge2(c5, XW2, lane32, &a1);
        gat_edge2(c6, XW2, lane32, &a2);
        gat_edge2(c7, XW2, lane32, &a3);
    }
    for (; s + 1 < end; s += 2) {
        unsigned int c0 = csr[s];
        unsigned int c1 = csr[s + 1];
        gat_edge2(c0, XW2, lane32, &a0);
        gat_edge2(c1, XW2, lane32, &a1);
    }
    if (s < end) {
        gat_edge2(csr[s], XW2, lane32, &a0);
    }

    float di = dinv[node];
    di = di * di;
    uint2 us = XW2[(size_t)node * 32 + lane32];
    float4 bv = ((const float4*)bias)[lane32];
    float4 rv = ((const float4*)(RES + (size_t)node * HDIM))[lane32];
    float4 o;
    o.x = eluf(a0.x + a1.x + a2.x + a3.x + bf_lo(us.x) * di + bv.x) + rv.x;
    o.y = eluf(a0.y + a1.y + a2.y + a3.y + bf_hi(us.x) * di + bv.y) + rv.y;
    o.z = eluf(a0.z + a1.z + a2.z + a3.z + bf_lo(us.y) * di + bv.z) + rv.z;
    o.w = eluf(a0.w + a1.w + a2.w + a3.w + bf_hi(us.y) * di + bv.w) + rv.w;

    float4 wv = ((const float4*)Wl)[lane32];
    float acc = o.x * wv.x + o.y * wv.y + o.z * wv.z + o.w * wv.w;
#pragma unroll
    for (int off = 16; off > 0; off >>= 1) acc += __shfl_down(acc, off, 32);
    if (lane32 == 0) out[node] = 1.f / (1.f + expf(-(acc + bl[0])));
}

// ---------------------------------------------------------------------------
extern "C" void kernel_launch(void* const* d_in, const int* in_sizes, int n_in,
                              void* d_out, int out_size, void* d_ws, size_t ws_size,
                              hipStream_t stream) {
    const float* x  = (const float*)d_in[0];
    const int*   ei = (const int*)d_in[1];
    const float* ew = (const float*)d_in[2];
    const float* W1 = (const float*)d_in[3];
    const float* b1 = (const float*)d_in[4];
    const float* W2 = (const float*)d_in[5];
    const float* b2 = (const float*)d_in[6];
    const float* W3 = (const float*)d_in[7];
    const float* b3 = (const float*)d_in[8];
    const float* Wl = (const float*)d_in[9];
    const float* bl = (const float*)d_in[10];
    float* out = (float*)d_out;

    char* ws = (char*)d_ws;
    const size_t NHB = (size_t)N_NODES * HDIM * sizeof(float);  // 25.6 MB
    unsigned int* A = (unsigned int*)(ws);            // XW in bf16 (12.8 MB used)
    float* B    = (float*)(ws + NHB);                 // h1
    float* C    = (float*)(ws + 2 * NHB);             // h2
    char*  p    = ws + 3 * NHB;
    unsigned long long* pcnt = (unsigned long long*)p; p += sizeof(unsigned long long) * N_NODES;
    float* dinv    = (float*)p;            p += sizeof(float) * N_NODES;
    int*   src32   = (int*)p;              p += sizeof(int) * N_EDGES;
    unsigned int* drank = (unsigned int*)p; p += sizeof(unsigned int) * N_EDGES;
    int*   incl    = (int*)p;              p += sizeof(int) * N_NODES;
    int*   rowptr  = (int*)p;              p += sizeof(int) * (N_NODES + 2);
    unsigned int* csr = (unsigned int*)p;  p += sizeof(unsigned int) * N_EDGES;
    unsigned short* Wt1 = (unsigned short*)p; p += sizeof(unsigned short) * HDIM * HDIM;
    unsigned short* Wt2 = (unsigned short*)p; p += sizeof(unsigned short) * HDIM * HDIM;
    unsigned short* Wt3 = (unsigned short*)p; p += sizeof(unsigned short) * HDIM * HDIM;
    int*   bsum    = (int*)p;              p += sizeof(int) * 128;

    const int TB = 256;
    const int egrid = (N_EDGES + TB - 1) / TB;
    const int ggrid = (N_NODES + 7) / 8;   // 8 nodes per block (half-wave each)

    // --- graph preprocessing (identical every call) ---
    hipMemsetAsync(pcnt, 0, N_NODES * sizeof(unsigned long long), stream);
    edges_k<<<egrid, TB, 0, stream>>>(ei, ew, src32, drank, pcnt, N_EDGES);
    wtrans3_k<<<192, TB, 0, stream>>>(W1, W2, W3, Wt1, Wt2, Wt3);
    scan1_k<<<SCAN_NB, SCAN_B, 0, stream>>>(pcnt, incl, bsum, dinv, N_NODES);
    scan3_k<<<SCAN_NB, SCAN_B, 0, stream>>>(pcnt, incl, bsum, rowptr, N_NODES, SCAN_NB);
    reorder_k<<<egrid, TB, 0, stream>>>(src32, drank, ew, dinv, rowptr, csr, N_EDGES);

    // --- layer 1: h1 = elu(gcn(x, W1, b1)) -> B ---
    mfma_gemm_k<<<1024, TB, 0, stream>>>(x, Wt1, (unsigned short*)A, N_NODES);
    gather_k<<<ggrid, TB, 0, stream>>>(rowptr, csr, (const uint2*)A, dinv, b1, nullptr, B, N_NODES);

    // --- layer 2: h2 = elu(gcn(h1, W2, b2)) + h1 -> C ---
    mfma_gemm_k<<<1024, TB, 0, stream>>>(B, Wt2, (unsigned short*)A, N_NODES);
    gather_k<<<ggrid, TB, 0, stream>>>(rowptr, csr, (const uint2*)A, dinv, b2, B, C, N_NODES);

    // --- layer 3 + head fused: out = sigmoid((elu(gcn(h2,W3,b3))+h2) @ Wl + bl) ---
    mfma_gemm_k<<<1024, TB, 0, stream>>>(C, Wt3, (unsigned short*)A, N_NODES);
    gather_head_k<<<ggrid, TB, 0, stream>>>(rowptr, csr, (const uint2*)A, dinv, b3, C, Wl, bl, out, N_NODES);
}

// Round 19
// 202.612 us; speedup vs baseline: 21.1322x; 1.0015x over previous
//
#include <hip/hip_runtime.h>
#include <hip/hip_fp16.h>
#include <math.h>

#define N_NODES 50000
#define N_EDGES 800000
#define HDIM 128
#define SCAN_B 512
#define SCAN_NB ((N_NODES + SCAN_B - 1) / SCAN_B)   // 98

typedef __attribute__((ext_vector_type(8))) short short8;
typedef __attribute__((ext_vector_type(4))) float f32x4;

// bf16 helpers (manual RNE; bf16->f32 is a 16-bit shift)
__device__ __forceinline__ unsigned int f2bf(float f) {
    unsigned int u = __float_as_uint(f);
    return (u + 0x7fffu + ((u >> 16) & 1u)) >> 16;
}
__device__ __forceinline__ float bf_lo(unsigned int u) { return __uint_as_float(u << 16); }
__device__ __forceinline__ float bf_hi(unsigned int u) { return __uint_as_float(u & 0xffff0000u); }
// fp16 helpers
__device__ __forceinline__ float h2f(unsigned short u) { return __half2float(__ushort_as_half(u)); }
__device__ __forceinline__ unsigned short f2h(float f) { return __half_as_ushort(__float2half_rn(f)); }

// ---------------------------------------------------------------------------
// Fused convert + packed degree/count + RANK CAPTURE (r16).
// pcnt: high 32 = count, low 32 = sum(ew * 2^24) fixed-point.
// ---------------------------------------------------------------------------
__global__ __launch_bounds__(256) void edges_k(const int* __restrict__ ei,
                                               const float* __restrict__ ew,
                                               int* __restrict__ src32,
                                               unsigned int* __restrict__ drank,
                                               unsigned long long* __restrict__ pcnt, int ne) {
    __shared__ int nz;
    if (threadIdx.x == 0) nz = 0;
    __syncthreads();
    int e = blockIdx.x * 256 + threadIdx.x;
    int odd = (e < ne) ? ei[2 * e + 1] : 0;
    if (odd) atomicOr(&nz, 1);
    __syncthreads();
    if (e >= ne) return;
    int s, d;
    if (nz == 0) {  // int64 layout: low words at even offsets
        s = ei[2 * e];
        d = ei[2 * (ne + e)];
    } else {        // int32 layout
        s = ei[e];
        d = ei[ne + e];
    }
    src32[e] = s;
    unsigned int q = __float2uint_rn(ew[e] * 16777216.0f);
    unsigned long long old = atomicAdd(&pcnt[d], (1ULL << 32) | (unsigned long long)q);
    unsigned int rank = (unsigned int)(old >> 32);
    drank[e] = (unsigned int)d | (rank << 16);
}

// ---------------------------------------------------------------------------
// Hierarchical exclusive scan (r16). scan1 fuses dinv emit.
// ---------------------------------------------------------------------------
__global__ __launch_bounds__(SCAN_B) void scan1_k(const unsigned long long* __restrict__ pcnt,
                                                  int* __restrict__ incl,
                                                  int* __restrict__ bsum,
                                                  float* __restrict__ dinv, int n) {
    __shared__ int buf[SCAN_B];
    int i = blockIdx.x * SCAN_B + threadIdx.x;
    unsigned long long v64 = (i < n) ? pcnt[i] : 0ULL;
    int v = (int)(v64 >> 32);
    buf[threadIdx.x] = v;
    __syncthreads();
#pragma unroll
    for (int off = 1; off < SCAN_B; off <<= 1) {
        int t = (threadIdx.x >= off) ? buf[threadIdx.x - off] : 0;
        __syncthreads();
        buf[threadIdx.x] += t;
        __syncthreads();
    }
    if (i < n) {
        incl[i] = buf[threadIdx.x];
        float deg = (float)(unsigned int)(v64 & 0xffffffffULL) * (1.0f / 16777216.0f);
        dinv[i] = rsqrtf(deg + 1.0f);
    }
    if (threadIdx.x == SCAN_B - 1) bsum[blockIdx.x] = buf[threadIdx.x];
}

__global__ __launch_bounds__(SCAN_B) void scan3_k(const unsigned long long* __restrict__ pcnt,
                                                  const int* __restrict__ incl,
                                                  const int* __restrict__ bsum,
                                                  int* __restrict__ rowptr, int n, int nb) {
    __shared__ int bs[128];
    if (threadIdx.x < 128) bs[threadIdx.x] = (threadIdx.x < nb) ? bsum[threadIdx.x] : 0;
    __syncthreads();
#pragma unroll
    for (int off = 1; off < 128; off <<= 1) {
        int t = 0;
        if (threadIdx.x < 128 && threadIdx.x >= off) t = bs[threadIdx.x - off];
        __syncthreads();
        if (threadIdx.x < 128) bs[threadIdx.x] += t;
        __syncthreads();
    }
    int i = blockIdx.x * SCAN_B + threadIdx.x;
    if (i < n) {
        int boff = (blockIdx.x == 0) ? 0 : bs[blockIdx.x - 1];
        int c = (int)(pcnt[i] >> 32);
        rowptr[i] = boff + incl[i] - c;
    }
    if (blockIdx.x == 0 && threadIdx.x == 0) rowptr[n] = bs[nb - 1];
}

// ---------------------------------------------------------------------------
// Reorder, ATOMIC-FREE: slot = rowptr[d] + rank.
// csr entry: (src:16 | norm fp16:16), one 4B scattered store/edge.
// ---------------------------------------------------------------------------
__global__ void reorder_k(const int* __restrict__ src,
                          const unsigned int* __restrict__ drank,
                          const float* __restrict__ ew, const float* __restrict__ dinv,
                          const int* __restrict__ rowptr,
                          unsigned int* __restrict__ csr, int ne) {
    int e = blockIdx.x * blockDim.x + threadIdx.x;
    if (e >= ne) return;
    int s = src[e];
    unsigned int dr = drank[e];
    int d = (int)(dr & 0xffffu);
    int rank = (int)(dr >> 16);
    int slot = rowptr[d] + rank;
    float nm = dinv[s] * ew[e] * dinv[d];
    csr[slot] = (unsigned int)s | ((unsigned int)f2h(nm) << 16);
}

// ---------------------------------------------------------------------------
// All three W (f32 [k][c]) -> Wt (bf16 [c][k]). 192 blocks, 1 elem/thread.
// ---------------------------------------------------------------------------
__global__ __launch_bounds__(256) void wtrans3_k(const float* __restrict__ W1,
                                                 const float* __restrict__ W2,
                                                 const float* __restrict__ W3,
                                                 unsigned short* __restrict__ Wt1,
                                                 unsigned short* __restrict__ Wt2,
                                                 unsigned short* __restrict__ Wt3) {
    int which = blockIdx.x >> 6;          // 64 blocks per weight
    const float* W = (which == 0) ? W1 : (which == 1) ? W2 : W3;
    unsigned short* Wt = (which == 0) ? Wt1 : (which == 1) ? Wt2 : Wt3;
    int idx = (blockIdx.x & 63) * 256 + threadIdx.x;   // 0..16383
    int c = idx >> 7, k = idx & 127;
    Wt[idx] = (unsigned short)f2bf(W[k * HDIM + c]);
}

// ---------------------------------------------------------------------------
// MFMA GEMM: Yb(bf16) = X @ W via Wt(bf16, transposed). INF16 selects the
// input dtype (f32 for layer 1, fp16 for layers 2/3); both cast to bf16 in
// LDS staging. m89-verified fragment layout (see r12).
// ---------------------------------------------------------------------------
template <bool INF16>
__global__ __launch_bounds__(256) void mfma_gemm_k(const void* __restrict__ Xv,
                                                   const unsigned short* __restrict__ Wt,
                                                   unsigned short* __restrict__ Y16,
                                                   int nrows) {
    __shared__ unsigned short WtL[HDIM][136];  // 34.8 KB (+8 pad: 2-way banks only)
    __shared__ unsigned short At[16][136];     // 4.4 KB

    for (int idx = threadIdx.x; idx < HDIM * 16; idx += 256) {
        int row = idx >> 4, q = idx & 15;
        *(uint4*)&WtL[row][q * 8] = *(const uint4*)&Wt[row * HDIM + q * 8];
    }
    __syncthreads();

    const int lane = threadIdx.x & 63;
    const int wave = threadIdx.x >> 6;
    const int col0 = wave * 32 + (lane & 15);
    const int koff = (lane >> 4) * 8;
    const int rsub = (lane >> 4) * 4;

    for (int row0 = blockIdx.x * 16; row0 < nrows; row0 += gridDim.x * 16) {
        {
            int r = threadIdx.x >> 4;
            int c8 = (threadIdx.x & 15) * 8;
            unsigned short tmp[8];
#pragma unroll
            for (int j = 0; j < 8; ++j) tmp[j] = 0;
            if (row0 + r < nrows) {
                if constexpr (INF16) {
                    const unsigned short* Xh = (const unsigned short*)Xv;
                    uint4 v = *(const uint4*)(Xh + (size_t)(row0 + r) * HDIM + c8);
                    unsigned int w[4] = {v.x, v.y, v.z, v.w};
#pragma unroll
                    for (int j = 0; j < 4; ++j) {
                        tmp[2 * j]     = (unsigned short)f2bf(h2f((unsigned short)(w[j] & 0xffffu)));
                        tmp[2 * j + 1] = (unsigned short)f2bf(h2f((unsigned short)(w[j] >> 16)));
                    }
                } else {
                    const float* Xf = (const float*)Xv;
                    const float4* xp = (const float4*)(Xf + (size_t)(row0 + r) * HDIM + c8);
                    float4 v0 = xp[0], v1 = xp[1];
                    tmp[0] = (unsigned short)f2bf(v0.x); tmp[1] = (unsigned short)f2bf(v0.y);
                    tmp[2] = (unsigned short)f2bf(v0.z); tmp[3] = (unsigned short)f2bf(v0.w);
                    tmp[4] = (unsigned short)f2bf(v1.x); tmp[5] = (unsigned short)f2bf(v1.y);
                    tmp[6] = (unsigned short)f2bf(v1.z); tmp[7] = (unsigned short)f2bf(v1.w);
                }
            }
            *(short8*)&At[r][c8] = *(short8*)tmp;
        }
        __syncthreads();

        f32x4 acc0 = {0.f, 0.f, 0.f, 0.f};
        f32x4 acc1 = {0.f, 0.f, 0.f, 0.f};
#pragma unroll
        for (int kb = 0; kb < 4; ++kb) {
            short8 a  = *(const short8*)&At[lane & 15][kb * 32 + koff];
            short8 b0 = *(const short8*)&WtL[col0][kb * 32 + koff];
            short8 b1 = *(const short8*)&WtL[col0 + 16][kb * 32 + koff];
            acc0 = __builtin_amdgcn_mfma_f32_16x16x32_bf16(a, b0, acc0, 0, 0, 0);
            acc1 = __builtin_amdgcn_mfma_f32_16x16x32_bf16(a, b1, acc1, 0, 0, 0);
        }
#pragma unroll
        for (int r = 0; r < 4; ++r) {
            int row = row0 + rsub + r;
            if (row < nrows) {
                Y16[(size_t)row * HDIM + col0]      = (unsigned short)f2bf(acc0[r]);
                Y16[(size_t)row * HDIM + col0 + 16] = (unsigned short)f2bf(acc1[r]);
            }
        }
        __syncthreads();
    }
}

// ---------------------------------------------------------------------------
// Fused CSR gather + finalize, half-wave per node (r18). XW rows bf16
// (256B/row), 8-edge unroll, 4 acc chains. OUT/RES now fp16 (halved traffic).
// Plain loads (nt caused replay divergence, r13).
// ---------------------------------------------------------------------------
__device__ __forceinline__ float eluf(float v) { return v > 0.f ? v : expf(v) - 1.f; }

__device__ __forceinline__ void gat_edge2(const unsigned int c,
                                          const uint2* __restrict__ XW2,
                                          int lane32, float4* acc) {
    int sidx = (int)(c & 0xffffu);
    float nm = h2f((unsigned short)(c >> 16));
    uint2 u = XW2[(size_t)sidx * 32 + lane32];
    acc->x += bf_lo(u.x) * nm;
    acc->y += bf_hi(u.x) * nm;
    acc->z += bf_lo(u.y) * nm;
    acc->w += bf_hi(u.y) * nm;
}

__global__ __launch_bounds__(256) void gather_k(const int* __restrict__ rowptr,
                                                const unsigned int* __restrict__ csr,
                                                const uint2* __restrict__ XW2,
                                                const float* __restrict__ dinv,
                                                const float* __restrict__ bias,
                                                const unsigned short* RES,
                                                unsigned short* __restrict__ OUT,
                                                int n) {
    int half = threadIdx.x >> 5;       // 0..7
    int lane32 = threadIdx.x & 31;
    int node = blockIdx.x * 8 + half;
    if (node >= n) return;
    int s = rowptr[node];
    const int end = rowptr[node + 1];

    float4 a0 = make_float4(0.f, 0.f, 0.f, 0.f), a1 = a0, a2 = a0, a3 = a0;

    for (; s + 7 < end; s += 8) {
        unsigned int c0 = csr[s];
        unsigned int c1 = csr[s + 1];
        unsigned int c2 = csr[s + 2];
        unsigned int c3 = csr[s + 3];
        unsigned int c4 = csr[s + 4];
        unsigned int c5 = csr[s + 5];
        unsigned int c6 = csr[s + 6];
        unsigned int c7 = csr[s + 7];
        gat_edge2(c0, XW2, lane32, &a0);
        gat_edge2(c1, XW2, lane32, &a1);
        gat_edge2(c2, XW2, lane32, &a2);
        gat_edge2(c3, XW2, lane32, &a3);
        gat_edge2(c4, XW2, lane32, &a0);
        gat_edge2(c5, XW2, lane32, &a1);
        gat_edge2(c6, XW2, lane32, &a2);
        gat_edge2(c7, XW2, lane32, &a3);
    }
    for (; s + 1 < end; s += 2) {
        unsigned int c0 = csr[s];
        unsigned int c1 = csr[s + 1];
        gat_edge2(c0, XW2, lane32, &a0);
        gat_edge2(c1, XW2, lane32, &a1);
    }
    if (s < end) {
        gat_edge2(csr[s], XW2, lane32, &a0);
    }

    float di = dinv[node];
    di = di * di;
    uint2 us = XW2[(size_t)node * 32 + lane32];
    float4 bv = ((const float4*)bias)[lane32];
    float4 o;
    o.x = eluf(a0.x + a1.x + a2.x + a3.x + bf_lo(us.x) * di + bv.x);
    o.y = eluf(a0.y + a1.y + a2.y + a3.y + bf_hi(us.x) * di + bv.y);
    o.z = eluf(a0.z + a1.z + a2.z + a3.z + bf_lo(us.y) * di + bv.z);
    o.w = eluf(a0.w + a1.w + a2.w + a3.w + bf_hi(us.y) * di + bv.w);
    if (RES) {
        uint2 rv = ((const uint2*)RES)[(size_t)node * 32 + lane32];
        o.x += h2f((unsigned short)(rv.x & 0xffffu));
        o.y += h2f((unsigned short)(rv.x >> 16));
        o.z += h2f((unsigned short)(rv.y & 0xffffu));
        o.w += h2f((unsigned short)(rv.y >> 16));
    }
    uint2 ov;
    ov.x = (unsigned int)f2h(o.x) | ((unsigned int)f2h(o.y) << 16);
    ov.y = (unsigned int)f2h(o.z) | ((unsigned int)f2h(o.w) << 16);
    ((uint2*)OUT)[(size_t)node * 32 + lane32] = ov;
}

// ---------------------------------------------------------------------------
// Layer-3 gather fused with head (half-wave per node; width-32 reduce).
// h3 never hits memory. RES (h2) is fp16.
// ---------------------------------------------------------------------------
__global__ __launch_bounds__(256) void gather_head_k(const int* __restrict__ rowptr,
                                                     const unsigned int* __restrict__ csr,
                                                     const uint2* __restrict__ XW2,
                                                     const float* __restrict__ dinv,
                                                     const float* __restrict__ bias,
                                                     const unsigned short* __restrict__ RES,
                                                     const float* __restrict__ Wl,
                                                     const float* __restrict__ bl,
                                                     float* __restrict__ out, int n) {
    int half = threadIdx.x >> 5;
    int lane32 = threadIdx.x & 31;
    int node = blockIdx.x * 8 + half;
    if (node >= n) return;
    int s = rowptr[node];
    const int end = rowptr[node + 1];

    float4 a0 = make_float4(0.f, 0.f, 0.f, 0.f), a1 = a0, a2 = a0, a3 = a0;

    for (; s + 7 < end; s += 8) {
        unsigned int c0 = csr[s];
        unsigned int c1 = csr[s + 1];
        unsigned int c2 = csr[s + 2];
        unsigned int c3 = csr[s + 3];
        unsigned int c4 = csr[s + 4];
        unsigned int c5 = csr[s + 5];
        unsigned int c6 = csr[s + 6];
        unsigned int c7 = csr[s + 7];
        gat_edge2(c0, XW2, lane32, &a0);
        gat_edge2(c1, XW2, lane32, &a1);
        gat_edge2(c2, XW2, lane32, &a2);
        gat_edge2(c3, XW2, lane32, &a3);
        gat_edge2(c4, XW2, lane32, &a0);
        gat_edge2(c5, XW2, lane32, &a1);
        gat_edge2(c6, XW2, lane32, &a2);
        gat_edge2(c7, XW2, lane32, &a3);
    }
    for (; s + 1 < end; s += 2) {
        unsigned int c0 = csr[s];
        unsigned int c1 = csr[s + 1];
        gat_edge2(c0, XW2, lane32, &a0);
        gat_edge2(c1, XW2, lane32, &a1);
    }
    if (s < end) {
        gat_edge2(csr[s], XW2, lane32, &a0);
    }

    float di = dinv[node];
    di = di * di;
    uint2 us = XW2[(size_t)node * 32 + lane32];
    float4 bv = ((const float4*)bias)[lane32];
    uint2 rv = ((const uint2*)RES)[(size_t)node * 32 + lane32];
    float4 o;
    o.x = eluf(a0.x + a1.x + a2.x + a3.x + bf_lo(us.x) * di + bv.x) + h2f((unsigned short)(rv.x & 0xffffu));
    o.y = eluf(a0.y + a1.y + a2.y + a3.y + bf_hi(us.x) * di + bv.y) + h2f((unsigned short)(rv.x >> 16));
    o.z = eluf(a0.z + a1.z + a2.z + a3.z + bf_lo(us.y) * di + bv.z) + h2f((unsigned short)(rv.y & 0xffffu));
    o.w = eluf(a0.w + a1.w + a2.w + a3.w + bf_hi(us.y) * di + bv.w) + h2f((unsigned short)(rv.y >> 16));

    float4 wv = ((const float4*)Wl)[lane32];
    float acc = o.x * wv.x + o.y * wv.y + o.z * wv.z + o.w * wv.w;
#pragma unroll
    for (int off = 16; off > 0; off >>= 1) acc += __shfl_down(acc, off, 32);
    if (lane32 == 0) out[node] = 1.f / (1.f + expf(-(acc + bl[0])));
}

// ---------------------------------------------------------------------------
extern "C" void kernel_launch(void* const* d_in, const int* in_sizes, int n_in,
                              void* d_out, int out_size, void* d_ws, size_t ws_size,
                              hipStream_t stream) {
    const float* x  = (const float*)d_in[0];
    const int*   ei = (const int*)d_in[1];
    const float* ew = (const float*)d_in[2];
    const float* W1 = (const float*)d_in[3];
    const float* b1 = (const float*)d_in[4];
    const float* W2 = (const float*)d_in[5];
    const float* b2 = (const float*)d_in[6];
    const float* W3 = (const float*)d_in[7];
    const float* b3 = (const float*)d_in[8];
    const float* Wl = (const float*)d_in[9];
    const float* bl = (const float*)d_in[10];
    float* out = (float*)d_out;

    char* ws = (char*)d_ws;
    const size_t NHB = (size_t)N_NODES * HDIM * sizeof(float);  // 25.6 MB slots
    unsigned int*   A = (unsigned int*)(ws);          // XW in bf16 (12.8 MB used)
    unsigned short* B = (unsigned short*)(ws + NHB);  // h1 (fp16, 12.8 MB used)
    unsigned short* C = (unsigned short*)(ws + 2 * NHB);  // h2 (fp16)
    char*  p    = ws + 3 * NHB;
    unsigned long long* pcnt = (unsigned long long*)p; p += sizeof(unsigned long long) * N_NODES;
    float* dinv    = (float*)p;            p += sizeof(float) * N_NODES;
    int*   src32   = (int*)p;              p += sizeof(int) * N_EDGES;
    unsigned int* drank = (unsigned int*)p; p += sizeof(unsigned int) * N_EDGES;
    int*   incl    = (int*)p;              p += sizeof(int) * N_NODES;
    int*   rowptr  = (int*)p;              p += sizeof(int) * (N_NODES + 2);
    unsigned int* csr = (unsigned int*)p;  p += sizeof(unsigned int) * N_EDGES;
    unsigned short* Wt1 = (unsigned short*)p; p += sizeof(unsigned short) * HDIM * HDIM;
    unsigned short* Wt2 = (unsigned short*)p; p += sizeof(unsigned short) * HDIM * HDIM;
    unsigned short* Wt3 = (unsigned short*)p; p += sizeof(unsigned short) * HDIM * HDIM;
    int*   bsum    = (int*)p;              p += sizeof(int) * 128;

    const int TB = 256;
    const int egrid = (N_EDGES + TB - 1) / TB;
    const int ggrid = (N_NODES + 7) / 8;   // 8 nodes per block (half-wave each)

    // --- graph preprocessing (identical every call) ---
    hipMemsetAsync(pcnt, 0, N_NODES * sizeof(unsigned long long), stream);
    edges_k<<<egrid, TB, 0, stream>>>(ei, ew, src32, drank, pcnt, N_EDGES);
    wtrans3_k<<<192, TB, 0, stream>>>(W1, W2, W3, Wt1, Wt2, Wt3);
    scan1_k<<<SCAN_NB, SCAN_B, 0, stream>>>(pcnt, incl, bsum, dinv, N_NODES);
    scan3_k<<<SCAN_NB, SCAN_B, 0, stream>>>(pcnt, incl, bsum, rowptr, N_NODES, SCAN_NB);
    reorder_k<<<egrid, TB, 0, stream>>>(src32, drank, ew, dinv, rowptr, csr, N_EDGES);

    // --- layer 1: h1 = elu(gcn(x, W1, b1)) -> B (fp16) ---
    mfma_gemm_k<false><<<1024, TB, 0, stream>>>(x, Wt1, (unsigned short*)A, N_NODES);
    gather_k<<<ggrid, TB, 0, stream>>>(rowptr, csr, (const uint2*)A, dinv, b1, nullptr, B, N_NODES);

    // --- layer 2: h2 = elu(gcn(h1, W2, b2)) + h1 -> C (fp16) ---
    mfma_gemm_k<true><<<1024, TB, 0, stream>>>(B, Wt2, (unsigned short*)A, N_NODES);
    gather_k<<<ggrid, TB, 0, stream>>>(rowptr, csr, (const uint2*)A, dinv, b2, B, C, N_NODES);

    // --- layer 3 + head fused: out = sigmoid((elu(gcn(h2,W3,b3))+h2) @ Wl + bl) ---
    mfma_gemm_k<true><<<1024, TB, 0, stream>>>(C, Wt3, (unsigned short*)A, N_NODES);
    gather_head_k<<<ggrid, TB, 0, stream>>>(rowptr, csr, (const uint2*)A, dinv, b3, C, Wl, bl, out, N_NODES);
}

// Round 20
// 198.048 us; speedup vs baseline: 21.6192x; 1.0230x over previous
//
#include <hip/hip_runtime.h>
#include <hip/hip_fp16.h>
#include <math.h>

#define N_NODES 50000
#define N_EDGES 800000
#define HDIM 128
#define SCAN_B 512
#define SCAN_NB ((N_NODES + SCAN_B - 1) / SCAN_B)   // 98
#define EGRID ((N_EDGES + 255) / 256)               // 3125
#define WT_NB 192
#define GEMM_NB 1024

typedef __attribute__((ext_vector_type(8))) short short8;
typedef __attribute__((ext_vector_type(4))) float f32x4;

// bf16 helpers (manual RNE; bf16->f32 is a 16-bit shift)
__device__ __forceinline__ unsigned int f2bf(float f) {
    unsigned int u = __float_as_uint(f);
    return (u + 0x7fffu + ((u >> 16) & 1u)) >> 16;
}
__device__ __forceinline__ float bf_lo(unsigned int u) { return __uint_as_float(u << 16); }
__device__ __forceinline__ float bf_hi(unsigned int u) { return __uint_as_float(u & 0xffff0000u); }
// fp16 helpers
__device__ __forceinline__ float h2f(unsigned short u) { return __half2float(__ushort_as_half(u)); }
__device__ __forceinline__ unsigned short f2h(float f) { return __half_as_ushort(__float2half_rn(f)); }

// ---------------------------------------------------------------------------
// FUSED dispatch 1: edges (3125 blocks) || wtrans x3 (192 blocks).
// edges: convert + packed degree/count + rank capture (r16); fabric-bound,
// CUs ~idle -> wtrans rides along free.
// ---------------------------------------------------------------------------
__global__ __launch_bounds__(256) void edges_wtrans_k(const int* __restrict__ ei,
                                                      const float* __restrict__ ew,
                                                      int* __restrict__ src32,
                                                      unsigned int* __restrict__ drank,
                                                      unsigned long long* __restrict__ pcnt, int ne,
                                                      const float* __restrict__ W1,
                                                      const float* __restrict__ W2,
                                                      const float* __restrict__ W3,
                                                      unsigned short* __restrict__ Wt1,
                                                      unsigned short* __restrict__ Wt2,
                                                      unsigned short* __restrict__ Wt3) {
    if (blockIdx.x < EGRID) {
        __shared__ int nz;
        if (threadIdx.x == 0) nz = 0;
        __syncthreads();
        int e = blockIdx.x * 256 + threadIdx.x;
        int odd = (e < ne) ? ei[2 * e + 1] : 0;
        if (odd) atomicOr(&nz, 1);
        __syncthreads();
        if (e >= ne) return;
        int s, d;
        if (nz == 0) {  // int64 layout: low words at even offsets
            s = ei[2 * e];
            d = ei[2 * (ne + e)];
        } else {        // int32 layout
            s = ei[e];
            d = ei[ne + e];
        }
        src32[e] = s;
        unsigned int q = __float2uint_rn(ew[e] * 16777216.0f);
        unsigned long long old = atomicAdd(&pcnt[d], (1ULL << 32) | (unsigned long long)q);
        drank[e] = (unsigned int)d | ((unsigned int)(old >> 32) << 16);
    } else {
        int wb = blockIdx.x - EGRID;           // 0..191, 64 blocks per weight
        int which = wb >> 6;
        const float* W = (which == 0) ? W1 : (which == 1) ? W2 : W3;
        unsigned short* Wt = (which == 0) ? Wt1 : (which == 1) ? Wt2 : Wt3;
        int idx = (wb & 63) * 256 + threadIdx.x;   // 0..16383
        int c = idx >> 7, k = idx & 127;
        Wt[idx] = (unsigned short)f2bf(W[k * HDIM + c]);
    }
}

// ---------------------------------------------------------------------------
// Hierarchical exclusive scan (r16). scan1 fuses dinv emit.
// ---------------------------------------------------------------------------
__global__ __launch_bounds__(SCAN_B) void scan1_k(const unsigned long long* __restrict__ pcnt,
                                                  int* __restrict__ incl,
                                                  int* __restrict__ bsum,
                                                  float* __restrict__ dinv, int n) {
    __shared__ int buf[SCAN_B];
    int i = blockIdx.x * SCAN_B + threadIdx.x;
    unsigned long long v64 = (i < n) ? pcnt[i] : 0ULL;
    int v = (int)(v64 >> 32);
    buf[threadIdx.x] = v;
    __syncthreads();
#pragma unroll
    for (int off = 1; off < SCAN_B; off <<= 1) {
        int t = (threadIdx.x >= off) ? buf[threadIdx.x - off] : 0;
        __syncthreads();
        buf[threadIdx.x] += t;
        __syncthreads();
    }
    if (i < n) {
        incl[i] = buf[threadIdx.x];
        float deg = (float)(unsigned int)(v64 & 0xffffffffULL) * (1.0f / 16777216.0f);
        dinv[i] = rsqrtf(deg + 1.0f);
    }
    if (threadIdx.x == SCAN_B - 1) bsum[blockIdx.x] = buf[threadIdx.x];
}

__global__ __launch_bounds__(SCAN_B) void scan3_k(const unsigned long long* __restrict__ pcnt,
                                                  const int* __restrict__ incl,
                                                  const int* __restrict__ bsum,
                                                  int* __restrict__ rowptr, int n, int nb) {
    __shared__ int bs[128];
    if (threadIdx.x < 128) bs[threadIdx.x] = (threadIdx.x < nb) ? bsum[threadIdx.x] : 0;
    __syncthreads();
#pragma unroll
    for (int off = 1; off < 128; off <<= 1) {
        int t = 0;
        if (threadIdx.x < 128 && threadIdx.x >= off) t = bs[threadIdx.x - off];
        __syncthreads();
        if (threadIdx.x < 128) bs[threadIdx.x] += t;
        __syncthreads();
    }
    int i = blockIdx.x * SCAN_B + threadIdx.x;
    if (i < n) {
        int boff = (blockIdx.x == 0) ? 0 : bs[blockIdx.x - 1];
        int c = (int)(pcnt[i] >> 32);
        rowptr[i] = boff + incl[i] - c;
    }
    if (blockIdx.x == 0 && threadIdx.x == 0) rowptr[n] = bs[nb - 1];
}

// ---------------------------------------------------------------------------
// MFMA GEMM body (shared by fused dispatch 2 and standalone layers 2/3).
// Yb(bf16) = X @ W via Wt(bf16, transposed). INF16 selects input dtype.
// m89-verified fragment layout (r12).
// ---------------------------------------------------------------------------
template <bool INF16>
__device__ __forceinline__ void gemm_body(const void* __restrict__ Xv,
                                          const unsigned short* __restrict__ Wt,
                                          unsigned short* __restrict__ Y16,
                                          int nrows, int bid, int nb) {
    __shared__ unsigned short WtL[HDIM][136];  // 34.8 KB (+8 pad: 2-way banks only)
    __shared__ unsigned short At[16][136];     // 4.4 KB

    for (int idx = threadIdx.x; idx < HDIM * 16; idx += 256) {
        int row = idx >> 4, q = idx & 15;
        *(uint4*)&WtL[row][q * 8] = *(const uint4*)&Wt[row * HDIM + q * 8];
    }
    __syncthreads();

    const int lane = threadIdx.x & 63;
    const int wave = threadIdx.x >> 6;
    const int col0 = wave * 32 + (lane & 15);
    const int koff = (lane >> 4) * 8;
    const int rsub = (lane >> 4) * 4;

    for (int row0 = bid * 16; row0 < nrows; row0 += nb * 16) {
        {
            int r = threadIdx.x >> 4;
            int c8 = (threadIdx.x & 15) * 8;
            unsigned short tmp[8];
#pragma unroll
            for (int j = 0; j < 8; ++j) tmp[j] = 0;
            if (row0 + r < nrows) {
                if constexpr (INF16) {
                    const unsigned short* Xh = (const unsigned short*)Xv;
                    uint4 v = *(const uint4*)(Xh + (size_t)(row0 + r) * HDIM + c8);
                    unsigned int w[4] = {v.x, v.y, v.z, v.w};
#pragma unroll
                    for (int j = 0; j < 4; ++j) {
                        tmp[2 * j]     = (unsigned short)f2bf(h2f((unsigned short)(w[j] & 0xffffu)));
                        tmp[2 * j + 1] = (unsigned short)f2bf(h2f((unsigned short)(w[j] >> 16)));
                    }
                } else {
                    const float* Xf = (const float*)Xv;
                    const float4* xp = (const float4*)(Xf + (size_t)(row0 + r) * HDIM + c8);
                    float4 v0 = xp[0], v1 = xp[1];
                    tmp[0] = (unsigned short)f2bf(v0.x); tmp[1] = (unsigned short)f2bf(v0.y);
                    tmp[2] = (unsigned short)f2bf(v0.z); tmp[3] = (unsigned short)f2bf(v0.w);
                    tmp[4] = (unsigned short)f2bf(v1.x); tmp[5] = (unsigned short)f2bf(v1.y);
                    tmp[6] = (unsigned short)f2bf(v1.z); tmp[7] = (unsigned short)f2bf(v1.w);
                }
            }
            *(short8*)&At[r][c8] = *(short8*)tmp;
        }
        __syncthreads();

        f32x4 acc0 = {0.f, 0.f, 0.f, 0.f};
        f32x4 acc1 = {0.f, 0.f, 0.f, 0.f};
#pragma unroll
        for (int kb = 0; kb < 4; ++kb) {
            short8 a  = *(const short8*)&At[lane & 15][kb * 32 + koff];
            short8 b0 = *(const short8*)&WtL[col0][kb * 32 + koff];
            short8 b1 = *(const short8*)&WtL[col0 + 16][kb * 32 + koff];
            acc0 = __builtin_amdgcn_mfma_f32_16x16x32_bf16(a, b0, acc0, 0, 0, 0);
            acc1 = __builtin_amdgcn_mfma_f32_16x16x32_bf16(a, b1, acc1, 0, 0, 0);
        }
#pragma unroll
        for (int r = 0; r < 4; ++r) {
            int row = row0 + rsub + r;
            if (row < nrows) {
                Y16[(size_t)row * HDIM + col0]      = (unsigned short)f2bf(acc0[r]);
                Y16[(size_t)row * HDIM + col0 + 16] = (unsigned short)f2bf(acc1[r]);
            }
        }
        __syncthreads();
    }
}

template <bool INF16>
__global__ __launch_bounds__(256) void mfma_gemm_k(const void* __restrict__ Xv,
                                                   const unsigned short* __restrict__ Wt,
                                                   unsigned short* __restrict__ Y16,
                                                   int nrows) {
    gemm_body<INF16>(Xv, Wt, Y16, nrows, blockIdx.x, gridDim.x);
}

// ---------------------------------------------------------------------------
// FUSED dispatch 2: reorder (3125 blocks, scatter-bound, CUs ~idle) ||
// gemm1 (1024 blocks, f32 input). Wt1 ready (fused dispatch 1 completed).
// reorder: ATOMIC-FREE slot = rowptr[d] + rank; csr = (src:16 | norm fp16:16).
// ---------------------------------------------------------------------------
__global__ __launch_bounds__(256) void reorder_gemm_k(const int* __restrict__ src,
                                                      const unsigned int* __restrict__ drank,
                                                      const float* __restrict__ ew,
                                                      const float* __restrict__ dinv,
                                                      const int* __restrict__ rowptr,
                                                      unsigned int* __restrict__ csr, int ne,
                                                      const float* __restrict__ x,
                                                      const unsigned short* __restrict__ Wt1,
                                                      unsigned short* __restrict__ Y16, int nrows) {
    if (blockIdx.x < EGRID) {
        int e = blockIdx.x * 256 + threadIdx.x;
        if (e >= ne) return;
        int s = src[e];
        unsigned int dr = drank[e];
        int d = (int)(dr & 0xffffu);
        int rank = (int)(dr >> 16);
        int slot = rowptr[d] + rank;
        float nm = dinv[s] * ew[e] * dinv[d];
        csr[slot] = (unsigned int)s | ((unsigned int)f2h(nm) << 16);
    } else {
        gemm_body<false>(x, Wt1, Y16, nrows, blockIdx.x - EGRID, GEMM_NB);
    }
}

// ---------------------------------------------------------------------------
// Fused CSR gather + finalize, half-wave per node (r18). XW rows bf16
// (256B/row), 8-edge unroll, 4 acc chains. OUT/RES fp16. Plain loads
// (nt caused replay divergence, r13).
// ---------------------------------------------------------------------------
__device__ __forceinline__ float eluf(float v) { return v > 0.f ? v : expf(v) - 1.f; }

__device__ __forceinline__ void gat_edge2(const unsigned int c,
                                          const uint2* __restrict__ XW2,
                                          int lane32, float4* acc) {
    int sidx = (int)(c & 0xffffu);
    float nm = h2f((unsigned short)(c >> 16));
    uint2 u = XW2[(size_t)sidx * 32 + lane32];
    acc->x += bf_lo(u.x) * nm;
    acc->y += bf_hi(u.x) * nm;
    acc->z += bf_lo(u.y) * nm;
    acc->w += bf_hi(u.y) * nm;
}

__global__ __launch_bounds__(256) void gather_k(const int* __restrict__ rowptr,
                                                const unsigned int* __restrict__ csr,
                                                const uint2* __restrict__ XW2,
                                                const float* __restrict__ dinv,
                                                const float* __restrict__ bias,
                                                const unsigned short* RES,
                                                unsigned short* __restrict__ OUT,
                                                int n) {
    int half = threadIdx.x >> 5;       // 0..7
    int lane32 = threadIdx.x & 31;
    int node = blockIdx.x * 8 + half;
    if (node >= n) return;
    int s = rowptr[node];
    const int end = rowptr[node + 1];

    float4 a0 = make_float4(0.f, 0.f, 0.f, 0.f), a1 = a0, a2 = a0, a3 = a0;

    for (; s + 7 < end; s += 8) {
        unsigned int c0 = csr[s];
        unsigned int c1 = csr[s + 1];
        unsigned int c2 = csr[s + 2];
        unsigned int c3 = csr[s + 3];
        unsigned int c4 = csr[s + 4];
        unsigned int c5 = csr[s + 5];
        unsigned int c6 = csr[s + 6];
        unsigned int c7 = csr[s + 7];
        gat_edge2(c0, XW2, lane32, &a0);
        gat_edge2(c1, XW2, lane32, &a1);
        gat_edge2(c2, XW2, lane32, &a2);
        gat_edge2(c3, XW2, lane32, &a3);
        gat_edge2(c4, XW2, lane32, &a0);
        gat_edge2(c5, XW2, lane32, &a1);
        gat_edge2(c6, XW2, lane32, &a2);
        gat_edge2(c7, XW2, lane32, &a3);
    }
    for (; s + 1 < end; s += 2) {
        unsigned int c0 = csr[s];
        unsigned int c1 = csr[s + 1];
        gat_edge2(c0, XW2, lane32, &a0);
        gat_edge2(c1, XW2, lane32, &a1);
    }
    if (s < end) {
        gat_edge2(csr[s], XW2, lane32, &a0);
    }

    float di = dinv[node];
    di = di * di;
    uint2 us = XW2[(size_t)node * 32 + lane32];
    float4 bv = ((const float4*)bias)[lane32];
    float4 o;
    o.x = eluf(a0.x + a1.x + a2.x + a3.x + bf_lo(us.x) * di + bv.x);
    o.y = eluf(a0.y + a1.y + a2.y + a3.y + bf_hi(us.x) * di + bv.y);
    o.z = eluf(a0.z + a1.z + a2.z + a3.z + bf_lo(us.y) * di + bv.z);
    o.w = eluf(a0.w + a1.w + a2.w + a3.w + bf_hi(us.y) * di + bv.w);
    if (RES) {
        uint2 rv = ((const uint2*)RES)[(size_t)node * 32 + lane32];
        o.x += h2f((unsigned short)(rv.x & 0xffffu));
        o.y += h2f((unsigned short)(rv.x >> 16));
        o.z += h2f((unsigned short)(rv.y & 0xffffu));
        o.w += h2f((unsigned short)(rv.y >> 16));
    }
    uint2 ov;
    ov.x = (unsigned int)f2h(o.x) | ((unsigned int)f2h(o.y) << 16);
    ov.y = (unsigned int)f2h(o.z) | ((unsigned int)f2h(o.w) << 16);
    ((uint2*)OUT)[(size_t)node * 32 + lane32] = ov;
}

// ---------------------------------------------------------------------------
// Layer-3 gather fused with head (half-wave per node; width-32 reduce).
// h3 never hits memory. RES (h2) fp16.
// ---------------------------------------------------------------------------
__global__ __launch_bounds__(256) void gather_head_k(const int* __restrict__ rowptr,
                                                     const unsigned int* __restrict__ csr,
                                                     const uint2* __restrict__ XW2,
                                                     const float* __restrict__ dinv,
                                                     const float* __restrict__ bias,
                                                     const unsigned short* __restrict__ RES,
                                                     const float* __restrict__ Wl,
                                                     const float* __restrict__ bl,
                                                     float* __restrict__ out, int n) {
    int half = threadIdx.x >> 5;
    int lane32 = threadIdx.x & 31;
    int node = blockIdx.x * 8 + half;
    if (node >= n) return;
    int s = rowptr[node];
    const int end = rowptr[node + 1];

    float4 a0 = make_float4(0.f, 0.f, 0.f, 0.f), a1 = a0, a2 = a0, a3 = a0;

    for (; s + 7 < end; s += 8) {
        unsigned int c0 = csr[s];
        unsigned int c1 = csr[s + 1];
        unsigned int c2 = csr[s + 2];
        unsigned int c3 = csr[s + 3];
        unsigned int c4 = csr[s + 4];
        unsigned int c5 = csr[s + 5];
        unsigned int c6 = csr[s + 6];
        unsigned int c7 = csr[s + 7];
        gat_edge2(c0, XW2, lane32, &a0);
        gat_edge2(c1, XW2, lane32, &a1);
        gat_edge2(c2, XW2, lane32, &a2);
        gat_edge2(c3, XW2, lane32, &a3);
        gat_edge2(c4, XW2, lane32, &a0);
        gat_edge2(c5, XW2, lane32, &a1);
        gat_edge2(c6, XW2, lane32, &a2);
        gat_edge2(c7, XW2, lane32, &a3);
    }
    for (; s + 1 < end; s += 2) {
        unsigned int c0 = csr[s];
        unsigned int c1 = csr[s + 1];
        gat_edge2(c0, XW2, lane32, &a0);
        gat_edge2(c1, XW2, lane32, &a1);
    }
    if (s < end) {
        gat_edge2(csr[s], XW2, lane32, &a0);
    }

    float di = dinv[node];
    di = di * di;
    uint2 us = XW2[(size_t)node * 32 + lane32];
    float4 bv = ((const float4*)bias)[lane32];
    uint2 rv = ((const uint2*)RES)[(size_t)node * 32 + lane32];
    float4 o;
    o.x = eluf(a0.x + a1.x + a2.x + a3.x + bf_lo(us.x) * di + bv.x) + h2f((unsigned short)(rv.x & 0xffffu));
    o.y = eluf(a0.y + a1.y + a2.y + a3.y + bf_hi(us.x) * di + bv.y) + h2f((unsigned short)(rv.x >> 16));
    o.z = eluf(a0.z + a1.z + a2.z + a3.z + bf_lo(us.y) * di + bv.z) + h2f((unsigned short)(rv.y & 0xffffu));
    o.w = eluf(a0.w + a1.w + a2.w + a3.w + bf_hi(us.y) * di + bv.w) + h2f((unsigned short)(rv.y >> 16));

    float4 wv = ((const float4*)Wl)[lane32];
    float acc = o.x * wv.x + o.y * wv.y + o.z * wv.z + o.w * wv.w;
#pragma unroll
    for (int off = 16; off > 0; off >>= 1) acc += __shfl_down(acc, off, 32);
    if (lane32 == 0) out[node] = 1.f / (1.f + expf(-(acc + bl[0])));
}

// ---------------------------------------------------------------------------
extern "C" void kernel_launch(void* const* d_in, const int* in_sizes, int n_in,
                              void* d_out, int out_size, void* d_ws, size_t ws_size,
                              hipStream_t stream) {
    const float* x  = (const float*)d_in[0];
    const int*   ei = (const int*)d_in[1];
    const float* ew = (const float*)d_in[2];
    const float* W1 = (const float*)d_in[3];
    const float* b1 = (const float*)d_in[4];
    const float* W2 = (const float*)d_in[5];
    const float* b2 = (const float*)d_in[6];
    const float* W3 = (const float*)d_in[7];
    const float* b3 = (const float*)d_in[8];
    const float* Wl = (const float*)d_in[9];
    const float* bl = (const float*)d_in[10];
    float* out = (float*)d_out;

    char* ws = (char*)d_ws;
    const size_t NHB = (size_t)N_NODES * HDIM * sizeof(float);  // 25.6 MB slots
    unsigned int*   A = (unsigned int*)(ws);          // XW in bf16 (12.8 MB used)
    unsigned short* B = (unsigned short*)(ws + NHB);  // h1 (fp16)
    unsigned short* C = (unsigned short*)(ws + 2 * NHB);  // h2 (fp16)
    char*  p    = ws + 3 * NHB;
    unsigned long long* pcnt = (unsigned long long*)p; p += sizeof(unsigned long long) * N_NODES;
    float* dinv    = (float*)p;            p += sizeof(float) * N_NODES;
    int*   src32   = (int*)p;              p += sizeof(int) * N_EDGES;
    unsigned int* drank = (unsigned int*)p; p += sizeof(unsigned int) * N_EDGES;
    int*   incl    = (int*)p;              p += sizeof(int) * N_NODES;
    int*   rowptr  = (int*)p;              p += sizeof(int) * (N_NODES + 2);
    unsigned int* csr = (unsigned int*)p;  p += sizeof(unsigned int) * N_EDGES;
    unsigned short* Wt1 = (unsigned short*)p; p += sizeof(unsigned short) * HDIM * HDIM;
    unsigned short* Wt2 = (unsigned short*)p; p += sizeof(unsigned short) * HDIM * HDIM;
    unsigned short* Wt3 = (unsigned short*)p; p += sizeof(unsigned short) * HDIM * HDIM;
    int*   bsum    = (int*)p;              p += sizeof(int) * 128;

    const int TB = 256;
    const int ggrid = (N_NODES + 7) / 8;   // 8 nodes per block (half-wave each)

    // --- preprocessing: [edges || wtrans] -> scan -> [reorder || gemm1] ---
    hipMemsetAsync(pcnt, 0, N_NODES * sizeof(unsigned long long), stream);
    edges_wtrans_k<<<EGRID + WT_NB, TB, 0, stream>>>(ei, ew, src32, drank, pcnt, N_EDGES,
                                                     W1, W2, W3, Wt1, Wt2, Wt3);
    scan1_k<<<SCAN_NB, SCAN_B, 0, stream>>>(pcnt, incl, bsum, dinv, N_NODES);
    scan3_k<<<SCAN_NB, SCAN_B, 0, stream>>>(pcnt, incl, bsum, rowptr, N_NODES, SCAN_NB);
    reorder_gemm_k<<<EGRID + GEMM_NB, TB, 0, stream>>>(src32, drank, ew, dinv, rowptr, csr, N_EDGES,
                                                       x, Wt1, (unsigned short*)A, N_NODES);

    // --- layer 1: h1 = elu(gcn(x, W1, b1)) -> B (fp16)  [gemm1 already done] ---
    gather_k<<<ggrid, TB, 0, stream>>>(rowptr, csr, (const uint2*)A, dinv, b1, nullptr, B, N_NODES);

    // --- layer 2: h2 = elu(gcn(h1, W2, b2)) + h1 -> C (fp16) ---
    mfma_gemm_k<true><<<GEMM_NB, TB, 0, stream>>>(B, Wt2, (unsigned short*)A, N_NODES);
    gather_k<<<ggrid, TB, 0, stream>>>(rowptr, csr, (const uint2*)A, dinv, b2, B, C, N_NODES);

    // --- layer 3 + head fused: out = sigmoid((elu(gcn(h2,W3,b3))+h2) @ Wl + bl) ---
    mfma_gemm_k<true><<<GEMM_NB, TB, 0, stream>>>(C, Wt3, (unsigned short*)A, N_NODES);
    gather_head_k<<<ggrid, TB, 0, stream>>>(rowptr, csr, (const uint2*)A, dinv, b3, C, Wl, bl, out, N_NODES);
}